// Round 4
// baseline (806.419 us; speedup 1.0000x reference)
//
#include <hip/hip_runtime.h>
#include <stdint.h>

// ResonanceLayer: routed einsum -> resonance irfft (x-pair packed, frames to
// scratch) -> OLA+transpose+norm -> upsample*threefry-noise -> 65536-pt FFT
// convolution with complex-packed res spectra -> softmax-deformation mix ->
// tanh(gain*x) summed over resonators.
//
// FFT: radix-2 DIF forward (natural->bitrev), DIT inverse (bitrev->natural);
// spectra stay in bitrev order (products are order-consistent).
// Round-4 change: k_fwdB(ru)+product+invB fused into k_conv -- the ru block
// stage was pure traffic (134MB w + 3x134MB r); now the block-stage spectrum
// lives only in LDS + a 16-reg/thread snapshot reused for both p values.

#define PI_F     3.14159265358979323846f
#define TWOPI_F  6.28318530717958647692f
#define UNIT64K  (TWOPI_F/65536.0f)
#define UNIT2K   (TWOPI_F/2048.0f)
#define SK(i)    ((i) + ((i) >> 5))      // LDS skew: kills 4-way bank conflicts

__device__ __forceinline__ float2 cmul(float2 a, float2 b){
  return make_float2(a.x*b.x - a.y*b.y, a.x*b.y + a.y*b.x);
}

__device__ __forceinline__ float2 twid(uint32_t e, float unit, float sign){
  float ang = (float)e * unit;
  float sn, cn;
  __sincosf(ang, &sn, &cn);
  return make_float2(cn, sign*sn);
}

__device__ __forceinline__ uint32_t rotl32(uint32_t v, int r){
  return (v << r) | (v >> (32 - r));
}

// Threefry-2x32, key = (0, 123)
__device__ __forceinline__ void threefry2x32(uint32_t c0, uint32_t c1,
                                             uint32_t& o0, uint32_t& o1){
  const uint32_t k0 = 0u, k1 = 123u;
  const uint32_t k2 = 0x1BD11BDAu ^ k0 ^ k1;
  const uint32_t ks[3] = {k0, k1, k2};
  uint32_t x0 = c0 + k0, x1 = c1 + k1;
#pragma unroll
  for (int i = 0; i < 5; i++){
    if ((i & 1) == 0){
      x0 += x1; x1 = rotl32(x1,13); x1 ^= x0;
      x0 += x1; x1 = rotl32(x1,15); x1 ^= x0;
      x0 += x1; x1 = rotl32(x1,26); x1 ^= x0;
      x0 += x1; x1 = rotl32(x1, 6); x1 ^= x0;
    } else {
      x0 += x1; x1 = rotl32(x1,17); x1 ^= x0;
      x0 += x1; x1 = rotl32(x1,29); x1 ^= x0;
      x0 += x1; x1 = rotl32(x1,16); x1 ^= x0;
      x0 += x1; x1 = rotl32(x1,24); x1 ^= x0;
    }
    x0 += ks[(i+1)%3];
    x1 += ks[(i+2)%3] + (uint32_t)(i+1);
  }
  o0 = x0; o1 = x1;
}

__device__ __forceinline__ float jax_noise(uint32_t p){
  uint32_t b0, b1;
  threefry2x32(0u, p, b0, b1);
  uint32_t bits = b0 ^ b1;
  float u = __uint_as_float((bits >> 9) | 0x3f800000u) - 1.0f;
  return fmaxf(-1.0f, u*2.0f - 1.0f);
}

__device__ __forceinline__ void interp128(int t, int& lo, int& hi, float& w){
  float posf = ((float)t + 0.5f) * (1.0f/256.0f) - 0.5f;
  posf = fminf(fmaxf(posf, 0.0f), 127.0f);
  lo = (int)posf;
  hi = lo + 1; if (hi > 127) hi = 127;
  w = posf - (float)lo;
}

// ---------------- routed einsum + output1 + softmax(deformations) ----------
__global__ void k_routed(const float* __restrict__ ctrl, const float* __restrict__ defm,
                         const float* __restrict__ router,
                         float* __restrict__ w_routed, float* __restrict__ w_sm,
                         float* __restrict__ out1){
  int idx = blockIdx.x*blockDim.x + threadIdx.x;
  if (idx < 32768){
    int f = idx & 127, r = (idx >> 7) & 31, be = idx >> 12;
    float acc = 0.0f;
#pragma unroll
    for (int c = 0; c < 16; c++)
      acc += ctrl[(be*16 + c)*128 + f] * router[c*32 + r];
    w_routed[idx] = acc;
    out1[idx] = acc;
  } else if (idx < 32768 + 1024){
    int j = idx - 32768;
    int f = j & 127, be = j >> 7;
    float v[4];
#pragma unroll
    for (int x = 0; x < 4; x++)
      v[x] = defm[(be*4 + x)*128 + f] + (x == 0 ? 1.0f : 0.0f);
    float mx = fmaxf(fmaxf(v[0], v[1]), fmaxf(v[2], v[3]));
    float s = 0.0f;
#pragma unroll
    for (int x = 0; x < 4; x++){ v[x] = expf(v[x] - mx); s += v[x]; }
#pragma unroll
    for (int x = 0; x < 4; x++) w_sm[(be*4 + x)*128 + f] = v[x]/s;
  }
}

// ---- resonance frames: packed complex irfft(2048) of x-pairs + hann -------
// output: w_fr[(rp*32+f)*2048 + u]  (contiguous float2 per frame, no atomics)
__global__ void k_frames(const float* __restrict__ amp, const float* __restrict__ phase,
                         const float* __restrict__ decay, float2* __restrict__ w_fr){
  const int wg = blockIdx.x;          // (r,p,f)
  const int f = wg & 31;
  const int rp = wg >> 5;             // r*2 + p
  const int p = rp & 1;
  const int r = rp >> 1;
  const int t = threadIdx.x;
  __shared__ float2 buf[2048];

  for (int k = t; k <= 1024; k += 256){
    float2 S[2];
#pragma unroll
    for (int d = 0; d < 2; d++){
      const int x = 2*p + d;
      const int base = (r*1025 + k)*4 + x;
      float a  = fabsf(amp[base]);
      float ph = tanhf(phase[base]) * PI_F;
      float sg = 1.0f / (1.0f + expf(-decay[base]));
      float dc = 0.5f + 0.45f * sg;
      float mag = expf(logf(dc + 1e-12f) * (float)(f+1)) * a;
      float snv, csv;
      sincosf(ph, &snv, &csv);
      float re = mag * csv, im = mag * snv;
      if (k == 0 || k == 1024) im = 0.0f;
      S[d] = make_float2(re, im);
    }
    buf[__brev((uint32_t)k) >> 21] =
        make_float2(S[0].x - S[1].y, S[0].y + S[1].x);
    if (k >= 1 && k <= 1023)
      buf[__brev((uint32_t)(2048 - k)) >> 21] =
          make_float2(S[0].x + S[1].y, -S[0].y + S[1].x);
  }
  __syncthreads();
  for (int s = 10; s >= 0; s--){
    const int ls = 10 - s;
    const int hl = 1 << ls;
    for (int bi = t; bi < 1024; bi += 256){
      const int g = bi >> ls, j = bi & (hl - 1);
      const int i0 = g*2*hl + j, i1 = i0 + hl;
      float2 pp = buf[i0], qq = buf[i1];
      float2 w = twid((uint32_t)(j << s), UNIT2K, +1.0f);
      float2 v = cmul(qq, w);
      buf[i0] = make_float2(pp.x+v.x, pp.y+v.y);
      buf[i1] = make_float2(pp.x-v.x, pp.y-v.y);
    }
    __syncthreads();
  }
  float2* O = w_fr + (size_t)wg*2048;
  for (int u = t; u < 2048; u += 256){
    float hann = 0.5f - 0.5f*cosf(TWOPI_F * (float)u / 2048.0f);
    float sc = (1.0f/2048.0f) * hann;
    O[u] = make_float2(buf[u].x*sc, buf[u].y*sc);
  }
}

// ---- OLA + transpose + sum-of-squares ------------------------------------
__global__ void k_ola(const float2* __restrict__ w_fr, float* __restrict__ w_resT,
                      float* __restrict__ w_sumsq){
  const int wg = blockIdx.x;           // rp*8 + cq
  const int cq = wg & 7;
  const int rp = wg >> 3;
  const int c0 = cq*32;
  const int r = rp >> 1, p = rp & 1;
  const int ch0 = r*4 + p*2;
  const int t = threadIdx.x;
  __shared__ float tx[32][129], ty[32][129];
  __shared__ float red[2][256];
  const float2* F = w_fr + (size_t)rp*32*2048;
  float acc0 = 0.0f, acc1 = 0.0f;
#pragma unroll
  for (int it = 0; it < 16; it++){
    const int idx = it*256 + t;        // m*32 + c'  (time-ordered reads)
    const int cp = idx & 31, m = idx >> 5;
    const int n = c0 + cp + 256*m;
    const int f = n >> 10, u = n & 1023;
    float2 a = F[(size_t)f*2048 + u];
    float vx = a.x, vy = a.y;
    if (f > 0){
      float2 b = F[(size_t)(f-1)*2048 + u + 1024];
      vx += b.x; vy += b.y;
    }
    tx[cp][m] = vx; ty[cp][m] = vy;
    acc0 += vx*vx; acc1 += vy*vy;
  }
  red[0][t] = acc0; red[1][t] = acc1;
  __syncthreads();
#pragma unroll
  for (int it = 0; it < 16; it++){
    const int idx = it*256 + t;        // c'*128 + m  (contiguous writes)
    const int m = idx & 127, cp = idx >> 7;
    w_resT[(size_t)ch0*32768 + (size_t)(c0+cp)*128 + m]     = tx[cp][m];
    w_resT[(size_t)(ch0+1)*32768 + (size_t)(c0+cp)*128 + m] = ty[cp][m];
  }
  for (int off = 128; off > 0; off >>= 1){
    __syncthreads();
    if (t < off){ red[0][t] += red[0][t+off]; red[1][t] += red[1][t+off]; }
  }
  if (t == 0){
    atomicAdd(&w_sumsq[ch0],     red[0][0]);
    atomicAdd(&w_sumsq[ch0 + 1], red[1][0]);
  }
}

// ---------------- invnorm from sumsq (1 tiny block) ------------------------
__global__ void k_norm(const float* __restrict__ w_sumsq, float* __restrict__ w_invnorm){
  const int s = threadIdx.x;
  if (s < 128) w_invnorm[s] = 1.0f/(sqrtf(w_sumsq[s]) + 1e-8f);
}

// --------- forward comb stages (s=0..7): 256-pt DIF over m per comb --------
// mode 0 (sig=r*2+p <64): packed res pair; mode 1 (sig<256): ru real
// output c-major: spec[sig][c*256 + m]
__global__ void k_fwdA(const int mode, const float* __restrict__ w_resT,
                       const float* __restrict__ w_invnorm,
                       const float* __restrict__ w_routed,
                       float2* __restrict__ spec){
  const int wg = blockIdx.x;
  const int cpair = wg & 127;
  const int sig = wg >> 7;
  const int c0 = cpair*2;
  const int t = threadIdx.x;
  __shared__ float re[2][264], im[2][264];
#pragma unroll
  for (int i = 0; i < 2; i++){
    const int li = t + i*256;
    const int cc = li >> 8, m = li & 255;
    const int c = c0 + cc;
    float vx = 0.0f, vy = 0.0f;
    if (m < 128){                       // n = c + 256*m < 32768
      if (mode == 0){
        const int rr = sig >> 1, pq = sig & 1;
        const int ch0 = rr*4 + pq*2;
        vx = w_resT[(size_t)ch0*32768 + c*128 + m] * w_invnorm[ch0];
        vy = w_resT[(size_t)(ch0+1)*32768 + c*128 + m] * w_invnorm[ch0+1];
      } else {
        const int n = c + 256*m;
        int lo, hi; float w;
        interp128(n, lo, hi, w);
        const float* rp = w_routed + sig*128;
        float rv = rp[lo]*(1.0f - w) + rp[hi]*w;
        vx = rv * jax_noise((uint32_t)sig*32768u + (uint32_t)n);
      }
    }
    re[cc][SK(m)] = vx; im[cc][SK(m)] = vy;
  }
  __syncthreads();
  const int arr = t >> 7, b = t & 127;
  for (int s = 0; s < 8; s++){
    const int ls = 7 - s;
    const int hl = 1 << ls;
    const int g = b >> ls, j = b & (hl - 1);
    const int i0 = g*2*hl + j, i1 = i0 + hl;
    float2 u = make_float2(re[arr][SK(i0)], im[arr][SK(i0)]);
    float2 v = make_float2(re[arr][SK(i1)], im[arr][SK(i1)]);
    uint32_t e = (((uint32_t)(c0 + arr) + 256u*(uint32_t)j) << s) & 0xFFFFu;
    float2 w = twid(e, UNIT64K, -1.0f);
    re[arr][SK(i0)] = u.x + v.x; im[arr][SK(i0)] = u.y + v.y;
    float2 d = make_float2(u.x - v.x, u.y - v.y);
    float2 dv = cmul(d, w);
    re[arr][SK(i1)] = dv.x; im[arr][SK(i1)] = dv.y;
    __syncthreads();
  }
#pragma unroll
  for (int i = 0; i < 2; i++){
    const int li = t + i*256;
    const int cc = li >> 8, m = li & 255;
    spec[(size_t)sig*65536 + (size_t)(c0+cc)*256 + m] =
        make_float2(re[cc][SK(m)], im[cc][SK(m)]);
  }
}

// ------- forward block stages (s=8..15) for res spectra, in place ----------
__global__ void k_fwdB(float2* __restrict__ spec){
  const int wg = blockIdx.x;
  const int mq = wg & 31;
  const int sig = wg >> 5;
  const int m8 = mq*8;
  const int t = threadIdx.x;
  __shared__ float re[8][264], im[8][264];
  float2* base = spec + (size_t)sig*65536;
#pragma unroll
  for (int i = 0; i < 8; i++){
    const int li = t + i*256;          // li = c*8 + mm
    const int mm = li & 7, c = li >> 3;
    float2 v = base[(size_t)c*256 + m8 + mm];
    re[mm][SK(c)] = v.x; im[mm][SK(c)] = v.y;
  }
  __syncthreads();
  for (int s = 8; s < 16; s++){
    const int ls = 15 - s;
    const int hl = 1 << ls;            // 128..1
#pragma unroll
    for (int it = 0; it < 4; it++){
      const int task = t + it*256;
      const int arr = task >> 7, b = task & 127;
      const int g = b >> ls, j = b & (hl - 1);
      const int i0 = g*2*hl + j, i1 = i0 + hl;
      float2 u = make_float2(re[arr][SK(i0)], im[arr][SK(i0)]);
      float2 v = make_float2(re[arr][SK(i1)], im[arr][SK(i1)]);
      float2 w = twid((uint32_t)(j << s), UNIT64K, -1.0f);
      re[arr][SK(i0)] = u.x + v.x; im[arr][SK(i0)] = u.y + v.y;
      float2 d = make_float2(u.x - v.x, u.y - v.y);
      float2 dv = cmul(d, w);
      re[arr][SK(i1)] = dv.x; im[arr][SK(i1)] = dv.y;
    }
    __syncthreads();
  }
#pragma unroll
  for (int i = 0; i < 8; i++){
    const int li = t + i*256;
    const int mm = li & 7, c = li >> 3;
    base[(size_t)c*256 + m8 + mm] = make_float2(re[mm][SK(c)], im[mm][SK(c)]);
  }
}

// ---- FUSED: ru fwd block stages + product(p=0,1) + inverse block stages ----
// in: ruspec = comb-stage output [g][c*256+m]; respspec fully transformed.
// out: chunk n-major CH[gl*2+p][m*256 + c]
__global__ void k_conv(const float2* __restrict__ ruspec,
                       const float2* __restrict__ respspec,
                       float2* __restrict__ chunkbuf, const int gbase){
  const int wg = blockIdx.x;
  const int mq = wg & 31;
  const int gl = wg >> 5;
  const int g = gbase + gl;
  const int r = g & 31;
  const int m8 = mq*8;
  const int t = threadIdx.x;
  __shared__ float re[8][264], im[8][264];
  const float2* A = ruspec + (size_t)g*65536;
#pragma unroll
  for (int i = 0; i < 8; i++){
    const int li = t + i*256;          // li = c*8 + mm
    const int mm = li & 7, c = li >> 3;
    float2 v = A[(size_t)c*256 + m8 + mm];
    re[mm][SK(c)] = v.x; im[mm][SK(c)] = v.y;
  }
  __syncthreads();
  // forward block stages s=8..15
  for (int s = 8; s < 16; s++){
    const int ls = 15 - s;
    const int hl = 1 << ls;
#pragma unroll
    for (int it = 0; it < 4; it++){
      const int task = t + it*256;
      const int arr = task >> 7, b = task & 127;
      const int gg = b >> ls, j = b & (hl - 1);
      const int i0 = gg*2*hl + j, i1 = i0 + hl;
      float2 u = make_float2(re[arr][SK(i0)], im[arr][SK(i0)]);
      float2 v = make_float2(re[arr][SK(i1)], im[arr][SK(i1)]);
      float2 w = twid((uint32_t)(j << s), UNIT64K, -1.0f);
      re[arr][SK(i0)] = u.x + v.x; im[arr][SK(i0)] = u.y + v.y;
      float2 d = make_float2(u.x - v.x, u.y - v.y);
      float2 dv = cmul(d, w);
      re[arr][SK(i1)] = dv.x; im[arr][SK(i1)] = dv.y;
    }
    __syncthreads();
  }
  // snapshot forward spectrum slab to registers (ownership li = c*8+mm)
  float fr[8], fi[8];
#pragma unroll
  for (int i = 0; i < 8; i++){
    const int li = t + i*256;
    const int mm = li & 7, c = li >> 3;
    fr[i] = re[mm][SK(c)]; fi[i] = im[mm][SK(c)];
  }
#pragma unroll 1
  for (int p = 0; p < 2; p++){
    __syncthreads();                   // protect LDS vs prior O-reads
    const float2* B = respspec + (size_t)(r*2 + p)*65536;
#pragma unroll
    for (int i = 0; i < 8; i++){
      const int li = t + i*256;
      const int mm = li & 7, c = li >> 3;
      float2 b = B[(size_t)c*256 + m8 + mm];
      re[mm][SK(c)] = fr[i]*b.x - fi[i]*b.y;
      im[mm][SK(c)] = fr[i]*b.y + fi[i]*b.x;
    }
    __syncthreads();
    // inverse block stages s=15..8
    for (int s = 15; s >= 8; s--){
      const int ls = 15 - s;
      const int hl = 1 << ls;
#pragma unroll
      for (int it = 0; it < 4; it++){
        const int task = t + it*256;
        const int arr = task >> 7, b = task & 127;
        const int g2 = b >> ls, j = b & (hl - 1);
        const int i0 = g2*2*hl + j, i1 = i0 + hl;
        float2 pp = make_float2(re[arr][SK(i0)], im[arr][SK(i0)]);
        float2 qq = make_float2(re[arr][SK(i1)], im[arr][SK(i1)]);
        float2 w = twid((uint32_t)(j << s), UNIT64K, +1.0f);
        float2 v = cmul(qq, w);
        re[arr][SK(i0)] = pp.x + v.x; im[arr][SK(i0)] = pp.y + v.y;
        re[arr][SK(i1)] = pp.x - v.x; im[arr][SK(i1)] = pp.y - v.y;
      }
      __syncthreads();
    }
    float2* O = chunkbuf + (size_t)(gl*2 + p)*65536;
#pragma unroll
    for (int i = 0; i < 8; i++){
      const int li = t + i*256;        // li = mm*256 + c -> contiguous rows
      const int mm = li >> 8, c = li & 255;
      O[(size_t)(m8+mm)*256 + c] = make_float2(re[mm][SK(c)], im[mm][SK(c)]);
    }
  }
}

// -- inverse comb stages (s=7..0): 8 combs x 2 p per block, fused epilogue --
__global__ void k_invA_w(const float2* __restrict__ chunkbuf, const int gbase,
                         const float* __restrict__ w_sm, const float* __restrict__ gains,
                         float* __restrict__ out0){
  const int wg = blockIdx.x;
  const int c8 = wg & 31;
  const int gl = wg >> 5;
  const int g = gbase + gl;
  const int r = g & 31, be = g >> 5;
  const int c0 = c8*8;
  const int t = threadIdx.x;
  __shared__ float re[2][8][264], im[2][8][264];
#pragma unroll
  for (int p = 0; p < 2; p++){
    const float2* C = chunkbuf + (size_t)(gl*2 + p)*65536;
#pragma unroll
    for (int i = 0; i < 8; i++){
      const int li = t + i*256;        // li = m*8 + cc -> 64B clusters
      const int cc = li & 7, m = li >> 3;
      float2 v = C[(size_t)m*256 + c0 + cc];
      re[p][cc][SK(m)] = v.x; im[p][cc][SK(m)] = v.y;
    }
  }
  __syncthreads();
  for (int s = 7; s >= 0; s--){
    const int ls = 7 - s;
    const int hl = 1 << ls;            // 1..128
#pragma unroll
    for (int it = 0; it < 8; it++){
      const int task = t + it*256;     // p(1) cc(3) b(7)
      const int b = task & 127;
      const int cc = (task >> 7) & 7;
      const int p = task >> 10;
      const int g2 = b >> ls, j = b & (hl - 1);
      const int i0 = g2*2*hl + j, i1 = i0 + hl;
      float2 pp = make_float2(re[p][cc][SK(i0)], im[p][cc][SK(i0)]);
      float2 qq = make_float2(re[p][cc][SK(i1)], im[p][cc][SK(i1)]);
      uint32_t e = (((uint32_t)(c0 + cc) + 256u*(uint32_t)j) << s) & 0xFFFFu;
      float2 w = twid(e, UNIT64K, +1.0f);
      float2 v = cmul(qq, w);
      re[p][cc][SK(i0)] = pp.x + v.x; im[p][cc][SK(i0)] = pp.y + v.y;
      re[p][cc][SK(i1)] = pp.x - v.x; im[p][cc][SK(i1)] = pp.y - v.y;
    }
    __syncthreads();
  }
  const float gv = fabsf(gains[r]);
  const float* smb = w_sm + be*512;
#pragma unroll
  for (int it = 0; it < 4; it++){
    const int li = t + it*256;         // li = m*8 + cc, m < 128
    const int cc = li & 7, m = li >> 3;
    const int tt = c0 + cc + 256*m;
    int lo, hi; float w;
    interp128(tt, lo, hi, w);
    float val = 0.0f;
#pragma unroll
    for (int p = 0; p < 2; p++){
      float z_re = re[p][cc][SK(m)], z_im = im[p][cc][SK(m)];
      float dw0 = smb[(2*p  )*128 + lo]*(1.0f - w) + smb[(2*p  )*128 + hi]*w;
      float dw1 = smb[(2*p+1)*128 + lo]*(1.0f - w) + smb[(2*p+1)*128 + hi]*w;
      val += dw0*z_re + dw1*z_im;
    }
    val *= (1.0f/65536.0f);
    atomicAdd(&out0[(size_t)be*32768 + tt], tanhf(val*gv));
  }
}

extern "C" void kernel_launch(void* const* d_in, const int* in_sizes, int n_in,
                              void* d_out, int out_size, void* d_ws, size_t ws_size,
                              hipStream_t stream){
  const float* ctrl   = (const float*)d_in[0];
  const float* defm   = (const float*)d_in[1];
  const float* router = (const float*)d_in[2];
  const float* amp    = (const float*)d_in[3];
  const float* phase  = (const float*)d_in[4];
  const float* decay  = (const float*)d_in[5];
  const float* gains  = (const float*)d_in[6];
  float* out = (float*)d_out;
  float* ws  = (float*)d_ws;

  // ws layout (float offsets)
  float*  w_resT    = ws;                         // 128*32768      = 4,194,304
  float*  w_routed  = ws + 4194304;               // 32768
  float*  w_sm      = ws + 4227072;               // 4096
  float*  w_invnorm = ws + 4231168;               // 128
  float*  w_sumsq   = ws + 4231296;               // 128
  float2* w_ruspec  = (float2*)(ws + 4231424);    // 256*65536 c    = 33,554,432 f
  float2* w_resp    = (float2*)(ws + 37785856);   // 64*65536 c     = 8,388,608 f
  float2* w_chunk   = (float2*)(ws + 46174464);   // 2G*65536 c
  const size_t base_f = 46174464;
  // frames scratch aliases the ruspec region (ruspec written later by fwdA)
  float2* w_fr      = w_ruspec;                   // 2048*2048 c = 8,388,608 f

  int G = 0;
  for (int gg = 64; gg >= 1; gg >>= 1){
    size_t need = (base_f + (size_t)gg*262144) * sizeof(float);
    if (need <= ws_size){ G = gg; break; }
  }

  hipMemsetAsync(d_out, 0, 262144*sizeof(float), stream);  // out0 (atomicAdd)
  k_routed<<<132, 256, 0, stream>>>(ctrl, defm, router, w_routed, w_sm, out + 262144);
  if (G == 0) return;  // diagnostic: out1 ok, out0 stays 0 => ws too small

  hipMemsetAsync(w_sumsq, 0, 128*sizeof(float), stream);
  k_frames<<<2048, 256, 0, stream>>>(amp, phase, decay, w_fr);
  k_ola<<<512, 256, 0, stream>>>(w_fr, w_resT, w_sumsq);
  k_norm<<<1, 128, 0, stream>>>(w_sumsq, w_invnorm);
  k_fwdA<<<64*128, 256, 0, stream>>>(0, w_resT, w_invnorm, w_routed, w_resp);
  k_fwdB<<<64*32, 256, 0, stream>>>(w_resp);
  k_fwdA<<<256*128, 256, 0, stream>>>(1, w_resT, w_invnorm, w_routed, w_ruspec);
  for (int gb = 0; gb < 256; gb += G){
    k_conv<<<G*32, 256, 0, stream>>>(w_ruspec, w_resp, w_chunk, gb);
    k_invA_w<<<G*32, 256, 0, stream>>>(w_chunk, gb, w_sm, gains, out);
  }
}

// Round 5
// 740.843 us; speedup vs baseline: 1.0885x; 1.0885x over previous
//
#include <hip/hip_runtime.h>
#include <stdint.h>

// ResonanceLayer: routed einsum -> resonance irfft (x-pair packed, frames to
// scratch) -> OLA+transpose+norm -> upsample*threefry-noise -> 65536-pt FFT
// convolution with complex-packed res spectra -> softmax-deformation mix ->
// tanh(gain*x) summed over resonators.
//
// FFT: radix-2 DIF forward (natural->bitrev), DIT inverse (bitrev->natural);
// spectra stay in bitrev order (products are order-consistent).
// Round-5 change: k_conv's forward-spectrum snapshot moved from 16 VGPRs
// (round-4: compiler capped at 64 VGPRs -> ~256B/thread scratch spill, seen
// as +128MB write / +115MB read per dispatch) to a linear LDS buffer
// (per-thread-owned cells, stride-1, conflict-free) + __launch_bounds__(256,4)
// so the register allocator has 128 VGPRs headroom.

#define PI_F     3.14159265358979323846f
#define TWOPI_F  6.28318530717958647692f
#define UNIT64K  (TWOPI_F/65536.0f)
#define UNIT2K   (TWOPI_F/2048.0f)
#define SK(i)    ((i) + ((i) >> 5))      // LDS skew: kills 4-way bank conflicts

__device__ __forceinline__ float2 cmul(float2 a, float2 b){
  return make_float2(a.x*b.x - a.y*b.y, a.x*b.y + a.y*b.x);
}

__device__ __forceinline__ float2 twid(uint32_t e, float unit, float sign){
  float ang = (float)e * unit;
  float sn, cn;
  __sincosf(ang, &sn, &cn);
  return make_float2(cn, sign*sn);
}

__device__ __forceinline__ uint32_t rotl32(uint32_t v, int r){
  return (v << r) | (v >> (32 - r));
}

// Threefry-2x32, key = (0, 123)
__device__ __forceinline__ void threefry2x32(uint32_t c0, uint32_t c1,
                                             uint32_t& o0, uint32_t& o1){
  const uint32_t k0 = 0u, k1 = 123u;
  const uint32_t k2 = 0x1BD11BDAu ^ k0 ^ k1;
  const uint32_t ks[3] = {k0, k1, k2};
  uint32_t x0 = c0 + k0, x1 = c1 + k1;
#pragma unroll
  for (int i = 0; i < 5; i++){
    if ((i & 1) == 0){
      x0 += x1; x1 = rotl32(x1,13); x1 ^= x0;
      x0 += x1; x1 = rotl32(x1,15); x1 ^= x0;
      x0 += x1; x1 = rotl32(x1,26); x1 ^= x0;
      x0 += x1; x1 = rotl32(x1, 6); x1 ^= x0;
    } else {
      x0 += x1; x1 = rotl32(x1,17); x1 ^= x0;
      x0 += x1; x1 = rotl32(x1,29); x1 ^= x0;
      x0 += x1; x1 = rotl32(x1,16); x1 ^= x0;
      x0 += x1; x1 = rotl32(x1,24); x1 ^= x0;
    }
    x0 += ks[(i+1)%3];
    x1 += ks[(i+2)%3] + (uint32_t)(i+1);
  }
  o0 = x0; o1 = x1;
}

__device__ __forceinline__ float jax_noise(uint32_t p){
  uint32_t b0, b1;
  threefry2x32(0u, p, b0, b1);
  uint32_t bits = b0 ^ b1;
  float u = __uint_as_float((bits >> 9) | 0x3f800000u) - 1.0f;
  return fmaxf(-1.0f, u*2.0f - 1.0f);
}

__device__ __forceinline__ void interp128(int t, int& lo, int& hi, float& w){
  float posf = ((float)t + 0.5f) * (1.0f/256.0f) - 0.5f;
  posf = fminf(fmaxf(posf, 0.0f), 127.0f);
  lo = (int)posf;
  hi = lo + 1; if (hi > 127) hi = 127;
  w = posf - (float)lo;
}

// ---------------- routed einsum + output1 + softmax(deformations) ----------
__global__ void k_routed(const float* __restrict__ ctrl, const float* __restrict__ defm,
                         const float* __restrict__ router,
                         float* __restrict__ w_routed, float* __restrict__ w_sm,
                         float* __restrict__ out1){
  int idx = blockIdx.x*blockDim.x + threadIdx.x;
  if (idx < 32768){
    int f = idx & 127, r = (idx >> 7) & 31, be = idx >> 12;
    float acc = 0.0f;
#pragma unroll
    for (int c = 0; c < 16; c++)
      acc += ctrl[(be*16 + c)*128 + f] * router[c*32 + r];
    w_routed[idx] = acc;
    out1[idx] = acc;
  } else if (idx < 32768 + 1024){
    int j = idx - 32768;
    int f = j & 127, be = j >> 7;
    float v[4];
#pragma unroll
    for (int x = 0; x < 4; x++)
      v[x] = defm[(be*4 + x)*128 + f] + (x == 0 ? 1.0f : 0.0f);
    float mx = fmaxf(fmaxf(v[0], v[1]), fmaxf(v[2], v[3]));
    float s = 0.0f;
#pragma unroll
    for (int x = 0; x < 4; x++){ v[x] = expf(v[x] - mx); s += v[x]; }
#pragma unroll
    for (int x = 0; x < 4; x++) w_sm[(be*4 + x)*128 + f] = v[x]/s;
  }
}

// ---- resonance frames: packed complex irfft(2048) of x-pairs + hann -------
// output: w_fr[(rp*32+f)*2048 + u]  (contiguous float2 per frame, no atomics)
__global__ void k_frames(const float* __restrict__ amp, const float* __restrict__ phase,
                         const float* __restrict__ decay, float2* __restrict__ w_fr){
  const int wg = blockIdx.x;          // (r,p,f)
  const int f = wg & 31;
  const int rp = wg >> 5;             // r*2 + p
  const int p = rp & 1;
  const int r = rp >> 1;
  const int t = threadIdx.x;
  __shared__ float2 buf[2048];

  for (int k = t; k <= 1024; k += 256){
    float2 S[2];
#pragma unroll
    for (int d = 0; d < 2; d++){
      const int x = 2*p + d;
      const int base = (r*1025 + k)*4 + x;
      float a  = fabsf(amp[base]);
      float ph = tanhf(phase[base]) * PI_F;
      float sg = 1.0f / (1.0f + expf(-decay[base]));
      float dc = 0.5f + 0.45f * sg;
      float mag = expf(logf(dc + 1e-12f) * (float)(f+1)) * a;
      float snv, csv;
      sincosf(ph, &snv, &csv);
      float re = mag * csv, im = mag * snv;
      if (k == 0 || k == 1024) im = 0.0f;
      S[d] = make_float2(re, im);
    }
    buf[__brev((uint32_t)k) >> 21] =
        make_float2(S[0].x - S[1].y, S[0].y + S[1].x);
    if (k >= 1 && k <= 1023)
      buf[__brev((uint32_t)(2048 - k)) >> 21] =
          make_float2(S[0].x + S[1].y, -S[0].y + S[1].x);
  }
  __syncthreads();
  for (int s = 10; s >= 0; s--){
    const int ls = 10 - s;
    const int hl = 1 << ls;
    for (int bi = t; bi < 1024; bi += 256){
      const int g = bi >> ls, j = bi & (hl - 1);
      const int i0 = g*2*hl + j, i1 = i0 + hl;
      float2 pp = buf[i0], qq = buf[i1];
      float2 w = twid((uint32_t)(j << s), UNIT2K, +1.0f);
      float2 v = cmul(qq, w);
      buf[i0] = make_float2(pp.x+v.x, pp.y+v.y);
      buf[i1] = make_float2(pp.x-v.x, pp.y-v.y);
    }
    __syncthreads();
  }
  float2* O = w_fr + (size_t)wg*2048;
  for (int u = t; u < 2048; u += 256){
    float hann = 0.5f - 0.5f*cosf(TWOPI_F * (float)u / 2048.0f);
    float sc = (1.0f/2048.0f) * hann;
    O[u] = make_float2(buf[u].x*sc, buf[u].y*sc);
  }
}

// ---- OLA + transpose + sum-of-squares ------------------------------------
__global__ void k_ola(const float2* __restrict__ w_fr, float* __restrict__ w_resT,
                      float* __restrict__ w_sumsq){
  const int wg = blockIdx.x;           // rp*8 + cq
  const int cq = wg & 7;
  const int rp = wg >> 3;
  const int c0 = cq*32;
  const int r = rp >> 1, p = rp & 1;
  const int ch0 = r*4 + p*2;
  const int t = threadIdx.x;
  __shared__ float tx[32][129], ty[32][129];
  __shared__ float red[2][256];
  const float2* F = w_fr + (size_t)rp*32*2048;
  float acc0 = 0.0f, acc1 = 0.0f;
#pragma unroll
  for (int it = 0; it < 16; it++){
    const int idx = it*256 + t;        // m*32 + c'  (time-ordered reads)
    const int cp = idx & 31, m = idx >> 5;
    const int n = c0 + cp + 256*m;
    const int f = n >> 10, u = n & 1023;
    float2 a = F[(size_t)f*2048 + u];
    float vx = a.x, vy = a.y;
    if (f > 0){
      float2 b = F[(size_t)(f-1)*2048 + u + 1024];
      vx += b.x; vy += b.y;
    }
    tx[cp][m] = vx; ty[cp][m] = vy;
    acc0 += vx*vx; acc1 += vy*vy;
  }
  red[0][t] = acc0; red[1][t] = acc1;
  __syncthreads();
#pragma unroll
  for (int it = 0; it < 16; it++){
    const int idx = it*256 + t;        // c'*128 + m  (contiguous writes)
    const int m = idx & 127, cp = idx >> 7;
    w_resT[(size_t)ch0*32768 + (size_t)(c0+cp)*128 + m]     = tx[cp][m];
    w_resT[(size_t)(ch0+1)*32768 + (size_t)(c0+cp)*128 + m] = ty[cp][m];
  }
  for (int off = 128; off > 0; off >>= 1){
    __syncthreads();
    if (t < off){ red[0][t] += red[0][t+off]; red[1][t] += red[1][t+off]; }
  }
  if (t == 0){
    atomicAdd(&w_sumsq[ch0],     red[0][0]);
    atomicAdd(&w_sumsq[ch0 + 1], red[1][0]);
  }
}

// ---------------- invnorm from sumsq (1 tiny block) ------------------------
__global__ void k_norm(const float* __restrict__ w_sumsq, float* __restrict__ w_invnorm){
  const int s = threadIdx.x;
  if (s < 128) w_invnorm[s] = 1.0f/(sqrtf(w_sumsq[s]) + 1e-8f);
}

// --------- forward comb stages (s=0..7): 256-pt DIF over m per comb --------
// mode 0 (sig=r*2+p <64): packed res pair; mode 1 (sig<256): ru real
// output c-major: spec[sig][c*256 + m]
__global__ void k_fwdA(const int mode, const float* __restrict__ w_resT,
                       const float* __restrict__ w_invnorm,
                       const float* __restrict__ w_routed,
                       float2* __restrict__ spec){
  const int wg = blockIdx.x;
  const int cpair = wg & 127;
  const int sig = wg >> 7;
  const int c0 = cpair*2;
  const int t = threadIdx.x;
  __shared__ float re[2][264], im[2][264];
#pragma unroll
  for (int i = 0; i < 2; i++){
    const int li = t + i*256;
    const int cc = li >> 8, m = li & 255;
    const int c = c0 + cc;
    float vx = 0.0f, vy = 0.0f;
    if (m < 128){                       // n = c + 256*m < 32768
      if (mode == 0){
        const int rr = sig >> 1, pq = sig & 1;
        const int ch0 = rr*4 + pq*2;
        vx = w_resT[(size_t)ch0*32768 + c*128 + m] * w_invnorm[ch0];
        vy = w_resT[(size_t)(ch0+1)*32768 + c*128 + m] * w_invnorm[ch0+1];
      } else {
        const int n = c + 256*m;
        int lo, hi; float w;
        interp128(n, lo, hi, w);
        const float* rp = w_routed + sig*128;
        float rv = rp[lo]*(1.0f - w) + rp[hi]*w;
        vx = rv * jax_noise((uint32_t)sig*32768u + (uint32_t)n);
      }
    }
    re[cc][SK(m)] = vx; im[cc][SK(m)] = vy;
  }
  __syncthreads();
  const int arr = t >> 7, b = t & 127;
  for (int s = 0; s < 8; s++){
    const int ls = 7 - s;
    const int hl = 1 << ls;
    const int g = b >> ls, j = b & (hl - 1);
    const int i0 = g*2*hl + j, i1 = i0 + hl;
    float2 u = make_float2(re[arr][SK(i0)], im[arr][SK(i0)]);
    float2 v = make_float2(re[arr][SK(i1)], im[arr][SK(i1)]);
    uint32_t e = (((uint32_t)(c0 + arr) + 256u*(uint32_t)j) << s) & 0xFFFFu;
    float2 w = twid(e, UNIT64K, -1.0f);
    re[arr][SK(i0)] = u.x + v.x; im[arr][SK(i0)] = u.y + v.y;
    float2 d = make_float2(u.x - v.x, u.y - v.y);
    float2 dv = cmul(d, w);
    re[arr][SK(i1)] = dv.x; im[arr][SK(i1)] = dv.y;
    __syncthreads();
  }
#pragma unroll
  for (int i = 0; i < 2; i++){
    const int li = t + i*256;
    const int cc = li >> 8, m = li & 255;
    spec[(size_t)sig*65536 + (size_t)(c0+cc)*256 + m] =
        make_float2(re[cc][SK(m)], im[cc][SK(m)]);
  }
}

// ------- forward block stages (s=8..15) for res spectra, in place ----------
__global__ void k_fwdB(float2* __restrict__ spec){
  const int wg = blockIdx.x;
  const int mq = wg & 31;
  const int sig = wg >> 5;
  const int m8 = mq*8;
  const int t = threadIdx.x;
  __shared__ float re[8][264], im[8][264];
  float2* base = spec + (size_t)sig*65536;
#pragma unroll
  for (int i = 0; i < 8; i++){
    const int li = t + i*256;          // li = c*8 + mm
    const int mm = li & 7, c = li >> 3;
    float2 v = base[(size_t)c*256 + m8 + mm];
    re[mm][SK(c)] = v.x; im[mm][SK(c)] = v.y;
  }
  __syncthreads();
  for (int s = 8; s < 16; s++){
    const int ls = 15 - s;
    const int hl = 1 << ls;            // 128..1
#pragma unroll
    for (int it = 0; it < 4; it++){
      const int task = t + it*256;
      const int arr = task >> 7, b = task & 127;
      const int g = b >> ls, j = b & (hl - 1);
      const int i0 = g*2*hl + j, i1 = i0 + hl;
      float2 u = make_float2(re[arr][SK(i0)], im[arr][SK(i0)]);
      float2 v = make_float2(re[arr][SK(i1)], im[arr][SK(i1)]);
      float2 w = twid((uint32_t)(j << s), UNIT64K, -1.0f);
      re[arr][SK(i0)] = u.x + v.x; im[arr][SK(i0)] = u.y + v.y;
      float2 d = make_float2(u.x - v.x, u.y - v.y);
      float2 dv = cmul(d, w);
      re[arr][SK(i1)] = dv.x; im[arr][SK(i1)] = dv.y;
    }
    __syncthreads();
  }
#pragma unroll
  for (int i = 0; i < 8; i++){
    const int li = t + i*256;
    const int mm = li & 7, c = li >> 3;
    base[(size_t)c*256 + m8 + mm] = make_float2(re[mm][SK(c)], im[mm][SK(c)]);
  }
}

// ---- FUSED: ru fwd block stages + product(p=0,1) + inverse block stages ----
// in: ruspec = comb-stage output [g][c*256+m]; respspec fully transformed.
// out: chunk n-major CH[gl*2+p][m*256 + c]
// Fwd-spectrum snapshot lives in LDS (Fre/Fim, per-thread-owned linear cells,
// stride-1 conflict-free, no syncs) -- NOT registers (round-4 spill bug).
__global__ __launch_bounds__(256, 4)
void k_conv(const float2* __restrict__ ruspec,
            const float2* __restrict__ respspec,
            float2* __restrict__ chunkbuf, const int gbase){
  const int wg = blockIdx.x;
  const int mq = wg & 31;
  const int gl = wg >> 5;
  const int g = gbase + gl;
  const int r = g & 31;
  const int m8 = mq*8;
  const int t = threadIdx.x;
  __shared__ float re[8][264], im[8][264];
  __shared__ float Fre[2048], Fim[2048];
  const float2* A = ruspec + (size_t)g*65536;
#pragma unroll
  for (int i = 0; i < 8; i++){
    const int li = t + i*256;          // li = c*8 + mm
    const int mm = li & 7, c = li >> 3;
    float2 v = A[(size_t)c*256 + m8 + mm];
    re[mm][SK(c)] = v.x; im[mm][SK(c)] = v.y;
  }
  __syncthreads();
  // forward block stages s=8..15
  for (int s = 8; s < 16; s++){
    const int ls = 15 - s;
    const int hl = 1 << ls;
#pragma unroll
    for (int it = 0; it < 4; it++){
      const int task = t + it*256;
      const int arr = task >> 7, b = task & 127;
      const int gg = b >> ls, j = b & (hl - 1);
      const int i0 = gg*2*hl + j, i1 = i0 + hl;
      float2 u = make_float2(re[arr][SK(i0)], im[arr][SK(i0)]);
      float2 v = make_float2(re[arr][SK(i1)], im[arr][SK(i1)]);
      float2 w = twid((uint32_t)(j << s), UNIT64K, -1.0f);
      re[arr][SK(i0)] = u.x + v.x; im[arr][SK(i0)] = u.y + v.y;
      float2 d = make_float2(u.x - v.x, u.y - v.y);
      float2 dv = cmul(d, w);
      re[arr][SK(i1)] = dv.x; im[arr][SK(i1)] = dv.y;
    }
    __syncthreads();
  }
  // snapshot forward spectrum to linear LDS (own cells only, no sync needed)
#pragma unroll
  for (int i = 0; i < 8; i++){
    const int li = t + i*256;
    const int mm = li & 7, c = li >> 3;
    Fre[li] = re[mm][SK(c)]; Fim[li] = im[mm][SK(c)];
  }
#pragma unroll 1
  for (int p = 0; p < 2; p++){
    __syncthreads();                   // protect work LDS vs prior O-reads
    const float2* B = respspec + (size_t)(r*2 + p)*65536;
#pragma unroll
    for (int i = 0; i < 8; i++){
      const int li = t + i*256;
      const int mm = li & 7, c = li >> 3;
      float2 b = B[(size_t)c*256 + m8 + mm];
      float ar = Fre[li], ai = Fim[li];
      re[mm][SK(c)] = ar*b.x - ai*b.y;
      im[mm][SK(c)] = ar*b.y + ai*b.x;
    }
    __syncthreads();
    // inverse block stages s=15..8
    for (int s = 15; s >= 8; s--){
      const int ls = 15 - s;
      const int hl = 1 << ls;
#pragma unroll
      for (int it = 0; it < 4; it++){
        const int task = t + it*256;
        const int arr = task >> 7, b = task & 127;
        const int g2 = b >> ls, j = b & (hl - 1);
        const int i0 = g2*2*hl + j, i1 = i0 + hl;
        float2 pp = make_float2(re[arr][SK(i0)], im[arr][SK(i0)]);
        float2 qq = make_float2(re[arr][SK(i1)], im[arr][SK(i1)]);
        float2 w = twid((uint32_t)(j << s), UNIT64K, +1.0f);
        float2 v = cmul(qq, w);
        re[arr][SK(i0)] = pp.x + v.x; im[arr][SK(i0)] = pp.y + v.y;
        re[arr][SK(i1)] = pp.x - v.x; im[arr][SK(i1)] = pp.y - v.y;
      }
      __syncthreads();
    }
    float2* O = chunkbuf + (size_t)(gl*2 + p)*65536;
#pragma unroll
    for (int i = 0; i < 8; i++){
      const int li = t + i*256;        // li = mm*256 + c -> contiguous rows
      const int mm = li >> 8, c = li & 255;
      O[(size_t)(m8+mm)*256 + c] = make_float2(re[mm][SK(c)], im[mm][SK(c)]);
    }
  }
}

// -- inverse comb stages (s=7..0): 8 combs x 2 p per block, fused epilogue --
__global__ void k_invA_w(const float2* __restrict__ chunkbuf, const int gbase,
                         const float* __restrict__ w_sm, const float* __restrict__ gains,
                         float* __restrict__ out0){
  const int wg = blockIdx.x;
  const int c8 = wg & 31;
  const int gl = wg >> 5;
  const int g = gbase + gl;
  const int r = g & 31, be = g >> 5;
  const int c0 = c8*8;
  const int t = threadIdx.x;
  __shared__ float re[2][8][264], im[2][8][264];
#pragma unroll
  for (int p = 0; p < 2; p++){
    const float2* C = chunkbuf + (size_t)(gl*2 + p)*65536;
#pragma unroll
    for (int i = 0; i < 8; i++){
      const int li = t + i*256;        // li = m*8 + cc -> 64B clusters
      const int cc = li & 7, m = li >> 3;
      float2 v = C[(size_t)m*256 + c0 + cc];
      re[p][cc][SK(m)] = v.x; im[p][cc][SK(m)] = v.y;
    }
  }
  __syncthreads();
  for (int s = 7; s >= 0; s--){
    const int ls = 7 - s;
    const int hl = 1 << ls;            // 1..128
#pragma unroll
    for (int it = 0; it < 8; it++){
      const int task = t + it*256;     // p(1) cc(3) b(7)
      const int b = task & 127;
      const int cc = (task >> 7) & 7;
      const int p = task >> 10;
      const int g2 = b >> ls, j = b & (hl - 1);
      const int i0 = g2*2*hl + j, i1 = i0 + hl;
      float2 pp = make_float2(re[p][cc][SK(i0)], im[p][cc][SK(i0)]);
      float2 qq = make_float2(re[p][cc][SK(i1)], im[p][cc][SK(i1)]);
      uint32_t e = (((uint32_t)(c0 + cc) + 256u*(uint32_t)j) << s) & 0xFFFFu;
      float2 w = twid(e, UNIT64K, +1.0f);
      float2 v = cmul(qq, w);
      re[p][cc][SK(i0)] = pp.x + v.x; im[p][cc][SK(i0)] = pp.y + v.y;
      re[p][cc][SK(i1)] = pp.x - v.x; im[p][cc][SK(i1)] = pp.y - v.y;
    }
    __syncthreads();
  }
  const float gv = fabsf(gains[r]);
  const float* smb = w_sm + be*512;
#pragma unroll
  for (int it = 0; it < 4; it++){
    const int li = t + it*256;         // li = m*8 + cc, m < 128
    const int cc = li & 7, m = li >> 3;
    const int tt = c0 + cc + 256*m;
    int lo, hi; float w;
    interp128(tt, lo, hi, w);
    float val = 0.0f;
#pragma unroll
    for (int p = 0; p < 2; p++){
      float z_re = re[p][cc][SK(m)], z_im = im[p][cc][SK(m)];
      float dw0 = smb[(2*p  )*128 + lo]*(1.0f - w) + smb[(2*p  )*128 + hi]*w;
      float dw1 = smb[(2*p+1)*128 + lo]*(1.0f - w) + smb[(2*p+1)*128 + hi]*w;
      val += dw0*z_re + dw1*z_im;
    }
    val *= (1.0f/65536.0f);
    atomicAdd(&out0[(size_t)be*32768 + tt], tanhf(val*gv));
  }
}

extern "C" void kernel_launch(void* const* d_in, const int* in_sizes, int n_in,
                              void* d_out, int out_size, void* d_ws, size_t ws_size,
                              hipStream_t stream){
  const float* ctrl   = (const float*)d_in[0];
  const float* defm   = (const float*)d_in[1];
  const float* router = (const float*)d_in[2];
  const float* amp    = (const float*)d_in[3];
  const float* phase  = (const float*)d_in[4];
  const float* decay  = (const float*)d_in[5];
  const float* gains  = (const float*)d_in[6];
  float* out = (float*)d_out;
  float* ws  = (float*)d_ws;

  // ws layout (float offsets)
  float*  w_resT    = ws;                         // 128*32768      = 4,194,304
  float*  w_routed  = ws + 4194304;               // 32768
  float*  w_sm      = ws + 4227072;               // 4096
  float*  w_invnorm = ws + 4231168;               // 128
  float*  w_sumsq   = ws + 4231296;               // 128
  float2* w_ruspec  = (float2*)(ws + 4231424);    // 256*65536 c    = 33,554,432 f
  float2* w_resp    = (float2*)(ws + 37785856);   // 64*65536 c     = 8,388,608 f
  float2* w_chunk   = (float2*)(ws + 46174464);   // 2G*65536 c
  const size_t base_f = 46174464;
  // frames scratch aliases the ruspec region (ruspec written later by fwdA)
  float2* w_fr      = w_ruspec;                   // 2048*2048 c = 8,388,608 f

  int G = 0;
  for (int gg = 64; gg >= 1; gg >>= 1){
    size_t need = (base_f + (size_t)gg*262144) * sizeof(float);
    if (need <= ws_size){ G = gg; break; }
  }

  hipMemsetAsync(d_out, 0, 262144*sizeof(float), stream);  // out0 (atomicAdd)
  k_routed<<<132, 256, 0, stream>>>(ctrl, defm, router, w_routed, w_sm, out + 262144);
  if (G == 0) return;  // diagnostic: out1 ok, out0 stays 0 => ws too small

  hipMemsetAsync(w_sumsq, 0, 128*sizeof(float), stream);
  k_frames<<<2048, 256, 0, stream>>>(amp, phase, decay, w_fr);
  k_ola<<<512, 256, 0, stream>>>(w_fr, w_resT, w_sumsq);
  k_norm<<<1, 128, 0, stream>>>(w_sumsq, w_invnorm);
  k_fwdA<<<64*128, 256, 0, stream>>>(0, w_resT, w_invnorm, w_routed, w_resp);
  k_fwdB<<<64*32, 256, 0, stream>>>(w_resp);
  k_fwdA<<<256*128, 256, 0, stream>>>(1, w_resT, w_invnorm, w_routed, w_ruspec);
  for (int gb = 0; gb < 256; gb += G){
    k_conv<<<G*32, 256, 0, stream>>>(w_ruspec, w_resp, w_chunk, gb);
    k_invA_w<<<G*32, 256, 0, stream>>>(w_chunk, gb, w_sm, gains, out);
  }
}

// Round 6
// 554.542 us; speedup vs baseline: 1.4542x; 1.3360x over previous
//
#include <hip/hip_runtime.h>
#include <hip/hip_fp16.h>
#include <stdint.h>

// ResonanceLayer: routed einsum -> resonance irfft (x-pair packed, frames to
// scratch) -> OLA+transpose+norm -> upsample*threefry-noise -> 65536-pt FFT
// convolution with complex-packed res spectra -> softmax-deformation mix ->
// tanh(gain*x) summed over resonators.
//
// FFT: radix-2 DIF forward (natural->bitrev), DIT inverse (bitrev->natural);
// spectra stay in bitrev order (products are order-consistent).
// Round-6: all conv-side intermediates (ruspec, resp, chunk) stored as packed
// __half2 (re,im) -- halves the dominant HBM streams (fresh writes measured
// at ~2x cost on this part). 16-element slab ownership keeps 64B granularity
// at 4B/element. 1/65536 inverse-FFT scale folded into the product so chunk
// values sit in fp16 normal range. G=128 -> only 2 conv + 2 invA dispatches.

#define PI_F     3.14159265358979323846f
#define TWOPI_F  6.28318530717958647692f
#define UNIT64K  (TWOPI_F/65536.0f)
#define UNIT2K   (TWOPI_F/2048.0f)
#define SCALE64K (1.0f/65536.0f)
#define SK(i)    ((i) + ((i) >> 5))      // LDS skew: kills 4-way bank conflicts

__device__ __forceinline__ float2 cmul(float2 a, float2 b){
  return make_float2(a.x*b.x - a.y*b.y, a.x*b.y + a.y*b.x);
}

__device__ __forceinline__ float2 twid(uint32_t e, float unit, float sign){
  float ang = (float)e * unit;
  float sn, cn;
  __sincosf(ang, &sn, &cn);
  return make_float2(cn, sign*sn);
}

__device__ __forceinline__ uint32_t rotl32(uint32_t v, int r){
  return (v << r) | (v >> (32 - r));
}

// Threefry-2x32, key = (0, 123)
__device__ __forceinline__ void threefry2x32(uint32_t c0, uint32_t c1,
                                             uint32_t& o0, uint32_t& o1){
  const uint32_t k0 = 0u, k1 = 123u;
  const uint32_t k2 = 0x1BD11BDAu ^ k0 ^ k1;
  const uint32_t ks[3] = {k0, k1, k2};
  uint32_t x0 = c0 + k0, x1 = c1 + k1;
#pragma unroll
  for (int i = 0; i < 5; i++){
    if ((i & 1) == 0){
      x0 += x1; x1 = rotl32(x1,13); x1 ^= x0;
      x0 += x1; x1 = rotl32(x1,15); x1 ^= x0;
      x0 += x1; x1 = rotl32(x1,26); x1 ^= x0;
      x0 += x1; x1 = rotl32(x1, 6); x1 ^= x0;
    } else {
      x0 += x1; x1 = rotl32(x1,17); x1 ^= x0;
      x0 += x1; x1 = rotl32(x1,29); x1 ^= x0;
      x0 += x1; x1 = rotl32(x1,16); x1 ^= x0;
      x0 += x1; x1 = rotl32(x1,24); x1 ^= x0;
    }
    x0 += ks[(i+1)%3];
    x1 += ks[(i+2)%3] + (uint32_t)(i+1);
  }
  o0 = x0; o1 = x1;
}

__device__ __forceinline__ float jax_noise(uint32_t p){
  uint32_t b0, b1;
  threefry2x32(0u, p, b0, b1);
  uint32_t bits = b0 ^ b1;
  float u = __uint_as_float((bits >> 9) | 0x3f800000u) - 1.0f;
  return fmaxf(-1.0f, u*2.0f - 1.0f);
}

__device__ __forceinline__ void interp128(int t, int& lo, int& hi, float& w){
  float posf = ((float)t + 0.5f) * (1.0f/256.0f) - 0.5f;
  posf = fminf(fmaxf(posf, 0.0f), 127.0f);
  lo = (int)posf;
  hi = lo + 1; if (hi > 127) hi = 127;
  w = posf - (float)lo;
}

// ---------------- routed einsum + output1 + softmax(deformations) ----------
__global__ void k_routed(const float* __restrict__ ctrl, const float* __restrict__ defm,
                         const float* __restrict__ router,
                         float* __restrict__ w_routed, float* __restrict__ w_sm,
                         float* __restrict__ out1){
  int idx = blockIdx.x*blockDim.x + threadIdx.x;
  if (idx < 32768){
    int f = idx & 127, r = (idx >> 7) & 31, be = idx >> 12;
    float acc = 0.0f;
#pragma unroll
    for (int c = 0; c < 16; c++)
      acc += ctrl[(be*16 + c)*128 + f] * router[c*32 + r];
    w_routed[idx] = acc;
    out1[idx] = acc;
  } else if (idx < 32768 + 1024){
    int j = idx - 32768;
    int f = j & 127, be = j >> 7;
    float v[4];
#pragma unroll
    for (int x = 0; x < 4; x++)
      v[x] = defm[(be*4 + x)*128 + f] + (x == 0 ? 1.0f : 0.0f);
    float mx = fmaxf(fmaxf(v[0], v[1]), fmaxf(v[2], v[3]));
    float s = 0.0f;
#pragma unroll
    for (int x = 0; x < 4; x++){ v[x] = expf(v[x] - mx); s += v[x]; }
#pragma unroll
    for (int x = 0; x < 4; x++) w_sm[(be*4 + x)*128 + f] = v[x]/s;
  }
}

// ---- resonance frames: packed complex irfft(2048) of x-pairs + hann -------
// output: w_fr[(rp*32+f)*2048 + u]  (contiguous float2 per frame, no atomics)
__global__ void k_frames(const float* __restrict__ amp, const float* __restrict__ phase,
                         const float* __restrict__ decay, float2* __restrict__ w_fr){
  const int wg = blockIdx.x;          // (r,p,f)
  const int f = wg & 31;
  const int rp = wg >> 5;             // r*2 + p
  const int p = rp & 1;
  const int r = rp >> 1;
  const int t = threadIdx.x;
  __shared__ float2 buf[2048];

  for (int k = t; k <= 1024; k += 256){
    float2 S[2];
#pragma unroll
    for (int d = 0; d < 2; d++){
      const int x = 2*p + d;
      const int base = (r*1025 + k)*4 + x;
      float a  = fabsf(amp[base]);
      float ph = tanhf(phase[base]) * PI_F;
      float sg = 1.0f / (1.0f + expf(-decay[base]));
      float dc = 0.5f + 0.45f * sg;
      float mag = expf(logf(dc + 1e-12f) * (float)(f+1)) * a;
      float snv, csv;
      sincosf(ph, &snv, &csv);
      float re = mag * csv, im = mag * snv;
      if (k == 0 || k == 1024) im = 0.0f;
      S[d] = make_float2(re, im);
    }
    buf[__brev((uint32_t)k) >> 21] =
        make_float2(S[0].x - S[1].y, S[0].y + S[1].x);
    if (k >= 1 && k <= 1023)
      buf[__brev((uint32_t)(2048 - k)) >> 21] =
          make_float2(S[0].x + S[1].y, -S[0].y + S[1].x);
  }
  __syncthreads();
  for (int s = 10; s >= 0; s--){
    const int ls = 10 - s;
    const int hl = 1 << ls;
    for (int bi = t; bi < 1024; bi += 256){
      const int g = bi >> ls, j = bi & (hl - 1);
      const int i0 = g*2*hl + j, i1 = i0 + hl;
      float2 pp = buf[i0], qq = buf[i1];
      float2 w = twid((uint32_t)(j << s), UNIT2K, +1.0f);
      float2 v = cmul(qq, w);
      buf[i0] = make_float2(pp.x+v.x, pp.y+v.y);
      buf[i1] = make_float2(pp.x-v.x, pp.y-v.y);
    }
    __syncthreads();
  }
  float2* O = w_fr + (size_t)wg*2048;
  for (int u = t; u < 2048; u += 256){
    float hann = 0.5f - 0.5f*cosf(TWOPI_F * (float)u / 2048.0f);
    float sc = (1.0f/2048.0f) * hann;
    O[u] = make_float2(buf[u].x*sc, buf[u].y*sc);
  }
}

// ---- OLA + transpose + sum-of-squares ------------------------------------
__global__ void k_ola(const float2* __restrict__ w_fr, float* __restrict__ w_resT,
                      float* __restrict__ w_sumsq){
  const int wg = blockIdx.x;           // rp*8 + cq
  const int cq = wg & 7;
  const int rp = wg >> 3;
  const int c0 = cq*32;
  const int r = rp >> 1, p = rp & 1;
  const int ch0 = r*4 + p*2;
  const int t = threadIdx.x;
  __shared__ float tx[32][129], ty[32][129];
  __shared__ float red[2][256];
  const float2* F = w_fr + (size_t)rp*32*2048;
  float acc0 = 0.0f, acc1 = 0.0f;
#pragma unroll
  for (int it = 0; it < 16; it++){
    const int idx = it*256 + t;        // m*32 + c'  (time-ordered reads)
    const int cp = idx & 31, m = idx >> 5;
    const int n = c0 + cp + 256*m;
    const int f = n >> 10, u = n & 1023;
    float2 a = F[(size_t)f*2048 + u];
    float vx = a.x, vy = a.y;
    if (f > 0){
      float2 b = F[(size_t)(f-1)*2048 + u + 1024];
      vx += b.x; vy += b.y;
    }
    tx[cp][m] = vx; ty[cp][m] = vy;
    acc0 += vx*vx; acc1 += vy*vy;
  }
  red[0][t] = acc0; red[1][t] = acc1;
  __syncthreads();
#pragma unroll
  for (int it = 0; it < 16; it++){
    const int idx = it*256 + t;        // c'*128 + m  (contiguous writes)
    const int m = idx & 127, cp = idx >> 7;
    w_resT[(size_t)ch0*32768 + (size_t)(c0+cp)*128 + m]     = tx[cp][m];
    w_resT[(size_t)(ch0+1)*32768 + (size_t)(c0+cp)*128 + m] = ty[cp][m];
  }
  for (int off = 128; off > 0; off >>= 1){
    __syncthreads();
    if (t < off){ red[0][t] += red[0][t+off]; red[1][t] += red[1][t+off]; }
  }
  if (t == 0){
    atomicAdd(&w_sumsq[ch0],     red[0][0]);
    atomicAdd(&w_sumsq[ch0 + 1], red[1][0]);
  }
}

// ---------------- invnorm from sumsq (1 tiny block) ------------------------
__global__ void k_norm(const float* __restrict__ w_sumsq, float* __restrict__ w_invnorm){
  const int s = threadIdx.x;
  if (s < 128) w_invnorm[s] = 1.0f/(sqrtf(w_sumsq[s]) + 1e-8f);
}

// --------- forward comb stages (s=0..7): 256-pt DIF over m per comb --------
// mode 0 (sig=r*2+p <64): packed res pair -> outf (fp32)
// mode 1 (sig<256): ru real -> outh (fp16)
// output c-major: [sig][c*256 + m]
__global__ void k_fwdA(const int mode, const float* __restrict__ w_resT,
                       const float* __restrict__ w_invnorm,
                       const float* __restrict__ w_routed,
                       float2* __restrict__ outf, __half2* __restrict__ outh){
  const int wg = blockIdx.x;
  const int cpair = wg & 127;
  const int sig = wg >> 7;
  const int c0 = cpair*2;
  const int t = threadIdx.x;
  __shared__ float re[2][264], im[2][264];
#pragma unroll
  for (int i = 0; i < 2; i++){
    const int li = t + i*256;
    const int cc = li >> 8, m = li & 255;
    const int c = c0 + cc;
    float vx = 0.0f, vy = 0.0f;
    if (m < 128){                       // n = c + 256*m < 32768
      if (mode == 0){
        const int rr = sig >> 1, pq = sig & 1;
        const int ch0 = rr*4 + pq*2;
        vx = w_resT[(size_t)ch0*32768 + c*128 + m] * w_invnorm[ch0];
        vy = w_resT[(size_t)(ch0+1)*32768 + c*128 + m] * w_invnorm[ch0+1];
      } else {
        const int n = c + 256*m;
        int lo, hi; float w;
        interp128(n, lo, hi, w);
        const float* rp = w_routed + sig*128;
        float rv = rp[lo]*(1.0f - w) + rp[hi]*w;
        vx = rv * jax_noise((uint32_t)sig*32768u + (uint32_t)n);
      }
    }
    re[cc][SK(m)] = vx; im[cc][SK(m)] = vy;
  }
  __syncthreads();
  const int arr = t >> 7, b = t & 127;
  for (int s = 0; s < 8; s++){
    const int ls = 7 - s;
    const int hl = 1 << ls;
    const int g = b >> ls, j = b & (hl - 1);
    const int i0 = g*2*hl + j, i1 = i0 + hl;
    float2 u = make_float2(re[arr][SK(i0)], im[arr][SK(i0)]);
    float2 v = make_float2(re[arr][SK(i1)], im[arr][SK(i1)]);
    uint32_t e = (((uint32_t)(c0 + arr) + 256u*(uint32_t)j) << s) & 0xFFFFu;
    float2 w = twid(e, UNIT64K, -1.0f);
    re[arr][SK(i0)] = u.x + v.x; im[arr][SK(i0)] = u.y + v.y;
    float2 d = make_float2(u.x - v.x, u.y - v.y);
    float2 dv = cmul(d, w);
    re[arr][SK(i1)] = dv.x; im[arr][SK(i1)] = dv.y;
    __syncthreads();
  }
#pragma unroll
  for (int i = 0; i < 2; i++){
    const int li = t + i*256;
    const int cc = li >> 8, m = li & 255;
    const size_t idx = (size_t)sig*65536 + (size_t)(c0+cc)*256 + m;
    if (mode == 0)
      outf[idx] = make_float2(re[cc][SK(m)], im[cc][SK(m)]);
    else
      outh[idx] = __floats2half2_rn(re[cc][SK(m)], im[cc][SK(m)]);
  }
}

// ------- forward block stages (s=8..15) for res spectra: fp32 -> fp16 ------
// 16-m slabs; reads float2 (128B runs), writes half2 (64B runs)
__global__ void k_fwdB(const float2* __restrict__ specf, __half2* __restrict__ spech){
  const int wg = blockIdx.x;
  const int mq = wg & 15;
  const int sig = wg >> 4;
  const int m16 = mq*16;
  const int t = threadIdx.x;
  __shared__ float re[16][264], im[16][264];
  const float2* base = specf + (size_t)sig*65536;
#pragma unroll
  for (int i = 0; i < 16; i++){
    const int li = t + i*256;          // li = c*16 + mm
    const int mm = li & 15, c = li >> 4;
    float2 v = base[(size_t)c*256 + m16 + mm];
    re[mm][SK(c)] = v.x; im[mm][SK(c)] = v.y;
  }
  __syncthreads();
  for (int s = 8; s < 16; s++){
    const int ls = 15 - s;
    const int hl = 1 << ls;            // 128..1
#pragma unroll
    for (int it = 0; it < 8; it++){
      const int task = t + it*256;     // arr(4) b(7)
      const int arr = task >> 7, b = task & 127;
      const int g = b >> ls, j = b & (hl - 1);
      const int i0 = g*2*hl + j, i1 = i0 + hl;
      float2 u = make_float2(re[arr][SK(i0)], im[arr][SK(i0)]);
      float2 v = make_float2(re[arr][SK(i1)], im[arr][SK(i1)]);
      float2 w = twid((uint32_t)(j << s), UNIT64K, -1.0f);
      re[arr][SK(i0)] = u.x + v.x; im[arr][SK(i0)] = u.y + v.y;
      float2 d = make_float2(u.x - v.x, u.y - v.y);
      float2 dv = cmul(d, w);
      re[arr][SK(i1)] = dv.x; im[arr][SK(i1)] = dv.y;
    }
    __syncthreads();
  }
  __half2* outb = spech + (size_t)sig*65536;
#pragma unroll
  for (int i = 0; i < 16; i++){
    const int li = t + i*256;
    const int mm = li & 15, c = li >> 4;
    outb[(size_t)c*256 + m16 + mm] = __floats2half2_rn(re[mm][SK(c)], im[mm][SK(c)]);
  }
}

// ---- FUSED: ru fwd block stages + product(p=0,1)*scale + inv block stages --
// 16-m slabs, fp16 in/out, fp32 LDS work, fp16 LDS snapshot of fwd spectrum.
// out: chunk n-major CH[gl*2+p][m*256 + c] (half2)
__global__ __launch_bounds__(256, 3)
void k_conv(const __half2* __restrict__ ruspec,
            const __half2* __restrict__ respspec,
            __half2* __restrict__ chunkbuf, const int gbase){
  const int wg = blockIdx.x;
  const int mq = wg & 15;
  const int gl = wg >> 4;
  const int g = gbase + gl;
  const int r = g & 31;
  const int m16 = mq*16;
  const int t = threadIdx.x;
  __shared__ float re[16][264], im[16][264];
  __shared__ __half2 Fh[4096];
  const __half2* A = ruspec + (size_t)g*65536;
#pragma unroll
  for (int i = 0; i < 16; i++){
    const int li = t + i*256;          // li = c*16 + mm
    const int mm = li & 15, c = li >> 4;
    float2 v = __half22float2(A[(size_t)c*256 + m16 + mm]);
    re[mm][SK(c)] = v.x; im[mm][SK(c)] = v.y;
  }
  __syncthreads();
  // forward block stages s=8..15
  for (int s = 8; s < 16; s++){
    const int ls = 15 - s;
    const int hl = 1 << ls;
#pragma unroll
    for (int it = 0; it < 8; it++){
      const int task = t + it*256;
      const int arr = task >> 7, b = task & 127;
      const int gg = b >> ls, j = b & (hl - 1);
      const int i0 = gg*2*hl + j, i1 = i0 + hl;
      float2 u = make_float2(re[arr][SK(i0)], im[arr][SK(i0)]);
      float2 v = make_float2(re[arr][SK(i1)], im[arr][SK(i1)]);
      float2 w = twid((uint32_t)(j << s), UNIT64K, -1.0f);
      re[arr][SK(i0)] = u.x + v.x; im[arr][SK(i0)] = u.y + v.y;
      float2 d = make_float2(u.x - v.x, u.y - v.y);
      float2 dv = cmul(d, w);
      re[arr][SK(i1)] = dv.x; im[arr][SK(i1)] = dv.y;
    }
    __syncthreads();
  }
  // snapshot fwd spectrum to fp16 LDS (per-thread-owned cells, no sync)
#pragma unroll
  for (int i = 0; i < 16; i++){
    const int li = t + i*256;
    const int mm = li & 15, c = li >> 4;
    Fh[li] = __floats2half2_rn(re[mm][SK(c)], im[mm][SK(c)]);
  }
#pragma unroll 1
  for (int p = 0; p < 2; p++){
    __syncthreads();                   // protect work LDS vs prior O-reads
    const __half2* B = respspec + (size_t)(r*2 + p)*65536;
#pragma unroll
    for (int i = 0; i < 16; i++){
      const int li = t + i*256;
      const int mm = li & 15, c = li >> 4;
      float2 b = __half22float2(B[(size_t)c*256 + m16 + mm]);
      float2 f = __half22float2(Fh[li]);
      re[mm][SK(c)] = (f.x*b.x - f.y*b.y) * SCALE64K;
      im[mm][SK(c)] = (f.x*b.y + f.y*b.x) * SCALE64K;
    }
    __syncthreads();
    // inverse block stages s=15..8
    for (int s = 15; s >= 8; s--){
      const int ls = 15 - s;
      const int hl = 1 << ls;
#pragma unroll
      for (int it = 0; it < 8; it++){
        const int task = t + it*256;
        const int arr = task >> 7, b = task & 127;
        const int g2 = b >> ls, j = b & (hl - 1);
        const int i0 = g2*2*hl + j, i1 = i0 + hl;
        float2 pp = make_float2(re[arr][SK(i0)], im[arr][SK(i0)]);
        float2 qq = make_float2(re[arr][SK(i1)], im[arr][SK(i1)]);
        float2 w = twid((uint32_t)(j << s), UNIT64K, +1.0f);
        float2 v = cmul(qq, w);
        re[arr][SK(i0)] = pp.x + v.x; im[arr][SK(i0)] = pp.y + v.y;
        re[arr][SK(i1)] = pp.x - v.x; im[arr][SK(i1)] = pp.y - v.y;
      }
      __syncthreads();
    }
    __half2* O = chunkbuf + (size_t)(gl*2 + p)*65536;
#pragma unroll
    for (int i = 0; i < 16; i++){
      const int li = t + i*256;        // li = mm*256 + c -> contiguous rows
      const int mm = li >> 8, c = li & 255;
      O[(size_t)(m16+mm)*256 + c] = __floats2half2_rn(re[mm][SK(c)], im[mm][SK(c)]);
    }
  }
}

// -- inverse comb stages (s=7..0): 16 combs x 2 p per block, fused epilogue --
// LDS cells stay packed half2; butterflies unpack->fp32->repack.
__global__ __launch_bounds__(256, 4)
void k_invA_w(const __half2* __restrict__ chunkbuf, const int gbase,
              const float* __restrict__ w_sm, const float* __restrict__ gains,
              float* __restrict__ out0){
  const int wg = blockIdx.x;
  const int c16 = wg & 15;
  const int gl = wg >> 4;
  const int g = gbase + gl;
  const int r = g & 31, be = g >> 5;
  const int c0 = c16*16;
  const int t = threadIdx.x;
  __shared__ __half2 zz[2][16][264];
#pragma unroll
  for (int p = 0; p < 2; p++){
    const __half2* C = chunkbuf + (size_t)(gl*2 + p)*65536;
#pragma unroll
    for (int i = 0; i < 16; i++){
      const int li = t + i*256;        // li = m*16 + cc -> 64B clusters
      const int cc = li & 15, m = li >> 4;
      zz[p][cc][SK(m)] = C[(size_t)m*256 + c0 + cc];
    }
  }
  __syncthreads();
  for (int s = 7; s >= 0; s--){
    const int ls = 7 - s;
    const int hl = 1 << ls;            // 1..128
#pragma unroll
    for (int it = 0; it < 16; it++){
      const int task = t + it*256;     // p(1) cc(4) b(7)
      const int b = task & 127;
      const int cc = (task >> 7) & 15;
      const int p = task >> 11;
      const int g2 = b >> ls, j = b & (hl - 1);
      const int i0 = g2*2*hl + j, i1 = i0 + hl;
      float2 pp = __half22float2(zz[p][cc][SK(i0)]);
      float2 qq = __half22float2(zz[p][cc][SK(i1)]);
      uint32_t e = (((uint32_t)(c0 + cc) + 256u*(uint32_t)j) << s) & 0xFFFFu;
      float2 w = twid(e, UNIT64K, +1.0f);
      float2 v = cmul(qq, w);
      zz[p][cc][SK(i0)] = __floats2half2_rn(pp.x + v.x, pp.y + v.y);
      zz[p][cc][SK(i1)] = __floats2half2_rn(pp.x - v.x, pp.y - v.y);
    }
    __syncthreads();
  }
  const float gv = fabsf(gains[r]);
  const float* smb = w_sm + be*512;
#pragma unroll
  for (int it = 0; it < 8; it++){
    const int li = t + it*256;         // li = m*16 + cc, m < 128
    const int cc = li & 15, m = li >> 4;
    const int tt = c0 + cc + 256*m;
    int lo, hi; float w;
    interp128(tt, lo, hi, w);
    float2 z0 = __half22float2(zz[0][cc][SK(m)]);
    float2 z1 = __half22float2(zz[1][cc][SK(m)]);
    float dw0 = smb[0*128 + lo]*(1.0f - w) + smb[0*128 + hi]*w;
    float dw1 = smb[1*128 + lo]*(1.0f - w) + smb[1*128 + hi]*w;
    float dw2 = smb[2*128 + lo]*(1.0f - w) + smb[2*128 + hi]*w;
    float dw3 = smb[3*128 + lo]*(1.0f - w) + smb[3*128 + hi]*w;
    float val = dw0*z0.x + dw1*z0.y + dw2*z1.x + dw3*z1.y;  // scale pre-folded
    atomicAdd(&out0[(size_t)be*32768 + tt], tanhf(val*gv));
  }
}

extern "C" void kernel_launch(void* const* d_in, const int* in_sizes, int n_in,
                              void* d_out, int out_size, void* d_ws, size_t ws_size,
                              hipStream_t stream){
  const float* ctrl   = (const float*)d_in[0];
  const float* defm   = (const float*)d_in[1];
  const float* router = (const float*)d_in[2];
  const float* amp    = (const float*)d_in[3];
  const float* phase  = (const float*)d_in[4];
  const float* decay  = (const float*)d_in[5];
  const float* gains  = (const float*)d_in[6];
  float* out = (float*)d_out;
  float* ws  = (float*)d_ws;

  // ws layout (float offsets)
  float*   w_resT    = ws;                          // 4,194,304
  float*   w_routed  = ws + 4194304;                // 32,768
  float*   w_sm      = ws + 4227072;                // 4,096
  float*   w_invnorm = ws + 4231168;                // 128
  float*   w_sumsq   = ws + 4231296;                // 128
  __half2* ruspec_h  = (__half2*)(ws + 4231424);    // 256*65536 h2 = 16,777,216 f
  float2*  resp_f    = (float2*)(ws + 21008640);    // 64*65536 c   =  8,388,608 f
  __half2* resp_h    = (__half2*)(ws + 29397248);   // 64*65536 h2  =  4,194,304 f
  __half2* chunk_h   = (__half2*)(ws + 33591552);   // 2G*65536 h2  = G*131,072 f
  const size_t base_f = 33591552;
  // frames scratch aliases ruspec_h region (ruspec written later by fwdA)
  float2* w_fr       = (float2*)ruspec_h;           // 2048*2048 c = 8,388,608 f

  int G = 0;
  for (int gg = 128; gg >= 1; gg >>= 1){
    size_t need = (base_f + (size_t)gg*131072) * sizeof(float);
    if (need <= ws_size){ G = gg; break; }
  }

  hipMemsetAsync(d_out, 0, 262144*sizeof(float), stream);  // out0 (atomicAdd)
  k_routed<<<132, 256, 0, stream>>>(ctrl, defm, router, w_routed, w_sm, out + 262144);
  if (G == 0) return;  // diagnostic: out1 ok, out0 stays 0 => ws too small

  hipMemsetAsync(w_sumsq, 0, 128*sizeof(float), stream);
  k_frames<<<2048, 256, 0, stream>>>(amp, phase, decay, w_fr);
  k_ola<<<512, 256, 0, stream>>>(w_fr, w_resT, w_sumsq);
  k_norm<<<1, 128, 0, stream>>>(w_sumsq, w_invnorm);
  k_fwdA<<<64*128, 256, 0, stream>>>(0, w_resT, w_invnorm, w_routed, resp_f, (\
__half2*)nullptr);
  k_fwdB<<<64*16, 256, 0, stream>>>(resp_f, resp_h);
  k_fwdA<<<256*128, 256, 0, stream>>>(1, w_resT, w_invnorm, w_routed,
                                      (float2*)nullptr, ruspec_h);
  for (int gb = 0; gb < 256; gb += G){
    k_conv<<<G*16, 256, 0, stream>>>(ruspec_h, resp_h, chunk_h, gb);
    k_invA_w<<<G*16, 256, 0, stream>>>(chunk_h, gb, w_sm, gains, out);
  }
}

// Round 7
// 514.613 us; speedup vs baseline: 1.5670x; 1.0776x over previous
//
#include <hip/hip_runtime.h>
#include <hip/hip_fp16.h>
#include <stdint.h>

// ResonanceLayer: routed einsum -> resonance irfft (x-pair packed, frames to
// scratch) -> OLA+transpose+norm -> upsample*threefry-noise -> 65536-pt FFT
// convolution with complex-packed res spectra -> softmax-deformation mix ->
// tanh(gain*x) summed over resonators.
//
// Round-7: conv-side LDS FFTs (k_fwdB / k_conv / k_invA_w) switch to
//  (a) row pitch 265 (9 mod 32) -- round-6's pitch-264 16-row layout put
//      staging on banks {0,8,16,24} = 4-way conflict (1.9e7 conflict cycles);
//  (b) pairwise-fused radix-2 stages: each thread pulls a 4-element quad,
//      does 2 stages in registers, writes back once. Same arithmetic & same
//      twiddles; half the LDS ops, half the barriers, -25% sincos.

#define PI_F     3.14159265358979323846f
#define TWOPI_F  6.28318530717958647692f
#define UNIT64K  (TWOPI_F/65536.0f)
#define UNIT2K   (TWOPI_F/2048.0f)
#define SCALE64K (1.0f/65536.0f)
#define SK(i)    ((i) + ((i) >> 5))      // within-row skew for stride patterns
#define RP 265                           // row pitch: 9 mod 32, spreads rows

__device__ __forceinline__ float2 cmul(float2 a, float2 b){
  return make_float2(a.x*b.x - a.y*b.y, a.x*b.y + a.y*b.x);
}

__device__ __forceinline__ float2 twid(uint32_t e, float unit, float sign){
  float ang = (float)e * unit;
  float sn, cn;
  __sincosf(ang, &sn, &cn);
  return make_float2(cn, sign*sn);
}

// DIF butterfly: u' = u+v ; v' = (u-v)*w
__device__ __forceinline__ void bfly_fwd(float2& u, float2& v, float2 w){
  float2 d = make_float2(u.x - v.x, u.y - v.y);
  u = make_float2(u.x + v.x, u.y + v.y);
  v = cmul(d, w);
}
// DIT butterfly: t = v*w ; u' = u+t ; v' = u-t
__device__ __forceinline__ void bfly_inv(float2& u, float2& v, float2 w){
  float2 tv = cmul(v, w);
  v = make_float2(u.x - tv.x, u.y - tv.y);
  u = make_float2(u.x + tv.x, u.y + tv.y);
}

__device__ __forceinline__ uint32_t rotl32(uint32_t v, int r){
  return (v << r) | (v >> (32 - r));
}

// Threefry-2x32, key = (0, 123)
__device__ __forceinline__ void threefry2x32(uint32_t c0, uint32_t c1,
                                             uint32_t& o0, uint32_t& o1){
  const uint32_t k0 = 0u, k1 = 123u;
  const uint32_t k2 = 0x1BD11BDAu ^ k0 ^ k1;
  const uint32_t ks[3] = {k0, k1, k2};
  uint32_t x0 = c0 + k0, x1 = c1 + k1;
#pragma unroll
  for (int i = 0; i < 5; i++){
    if ((i & 1) == 0){
      x0 += x1; x1 = rotl32(x1,13); x1 ^= x0;
      x0 += x1; x1 = rotl32(x1,15); x1 ^= x0;
      x0 += x1; x1 = rotl32(x1,26); x1 ^= x0;
      x0 += x1; x1 = rotl32(x1, 6); x1 ^= x0;
    } else {
      x0 += x1; x1 = rotl32(x1,17); x1 ^= x0;
      x0 += x1; x1 = rotl32(x1,29); x1 ^= x0;
      x0 += x1; x1 = rotl32(x1,16); x1 ^= x0;
      x0 += x1; x1 = rotl32(x1,24); x1 ^= x0;
    }
    x0 += ks[(i+1)%3];
    x1 += ks[(i+2)%3] + (uint32_t)(i+1);
  }
  o0 = x0; o1 = x1;
}

__device__ __forceinline__ float jax_noise(uint32_t p){
  uint32_t b0, b1;
  threefry2x32(0u, p, b0, b1);
  uint32_t bits = b0 ^ b1;
  float u = __uint_as_float((bits >> 9) | 0x3f800000u) - 1.0f;
  return fmaxf(-1.0f, u*2.0f - 1.0f);
}

__device__ __forceinline__ void interp128(int t, int& lo, int& hi, float& w){
  float posf = ((float)t + 0.5f) * (1.0f/256.0f) - 0.5f;
  posf = fminf(fmaxf(posf, 0.0f), 127.0f);
  lo = (int)posf;
  hi = lo + 1; if (hi > 127) hi = 127;
  w = posf - (float)lo;
}

// ---- fused-pair forward block FFT (DIF, stages 8..15) on 16x256 rows ------
__device__ __forceinline__ void fwd_block_fft(float (*re)[RP], float (*im)[RP],
                                              const int t){
  for (int sp = 0; sp < 4; sp++){
    const int s  = 8 + 2*sp;
    const int hl = 1 << (7 - 2*sp);    // 128,32,8,2
    const int hh = hl >> 1;            // 64,16,4,1
    const int lj = 6 - 2*sp;
#pragma unroll
    for (int it = 0; it < 4; it++){
      const int qq = t + it*256;
      const int row = qq >> 6, q = qq & 63;
      const int j = q & (hh - 1), g = q >> lj;
      const int base = g*2*hl + j;
      float* R = re[row]; float* I = im[row];
      const int i0 = SK(base), i1 = SK(base+hh), i2 = SK(base+hl), i3 = SK(base+hl+hh);
      float2 u0 = make_float2(R[i0], I[i0]);
      float2 u1 = make_float2(R[i1], I[i1]);
      float2 u2 = make_float2(R[i2], I[i2]);
      float2 u3 = make_float2(R[i3], I[i3]);
      float2 wA0 = twid((uint32_t)(j << s),        UNIT64K, -1.0f);
      float2 wA1 = twid((uint32_t)((j + hh) << s), UNIT64K, -1.0f);
      float2 wB  = twid((uint32_t)(j << (s + 1)),  UNIT64K, -1.0f);
      bfly_fwd(u0, u2, wA0);
      bfly_fwd(u1, u3, wA1);
      bfly_fwd(u0, u1, wB);
      bfly_fwd(u2, u3, wB);
      R[i0] = u0.x; I[i0] = u0.y;
      R[i1] = u1.x; I[i1] = u1.y;
      R[i2] = u2.x; I[i2] = u2.y;
      R[i3] = u3.x; I[i3] = u3.y;
    }
    __syncthreads();
  }
}

// ---- fused-pair inverse block FFT (DIT, stages 15..8) on 16x256 rows ------
__device__ __forceinline__ void inv_block_fft(float (*re)[RP], float (*im)[RP],
                                              const int t){
  for (int sp = 0; sp < 4; sp++){
    const int sA = 15 - 2*sp, sB = sA - 1;
    const int hA = 1 << (2*sp);        // 1,4,16,64
    const int lA = 2*sp;
#pragma unroll
    for (int it = 0; it < 4; it++){
      const int qq = t + it*256;
      const int row = qq >> 6, q = qq & 63;
      const int j = q & (hA - 1), g = q >> lA;
      const int base = g*4*hA + j;
      float* R = re[row]; float* I = im[row];
      const int i0 = SK(base), i1 = SK(base+hA), i2 = SK(base+2*hA), i3 = SK(base+3*hA);
      float2 u0 = make_float2(R[i0], I[i0]);
      float2 u1 = make_float2(R[i1], I[i1]);
      float2 u2 = make_float2(R[i2], I[i2]);
      float2 u3 = make_float2(R[i3], I[i3]);
      float2 wA  = twid((uint32_t)(j << sA),        UNIT64K, +1.0f);
      float2 wB0 = twid((uint32_t)(j << sB),        UNIT64K, +1.0f);
      float2 wB1 = twid((uint32_t)((j + hA) << sB), UNIT64K, +1.0f);
      bfly_inv(u0, u1, wA);
      bfly_inv(u2, u3, wA);
      bfly_inv(u0, u2, wB0);
      bfly_inv(u1, u3, wB1);
      R[i0] = u0.x; I[i0] = u0.y;
      R[i1] = u1.x; I[i1] = u1.y;
      R[i2] = u2.x; I[i2] = u2.y;
      R[i3] = u3.x; I[i3] = u3.y;
    }
    __syncthreads();
  }
}

// ---------------- routed einsum + output1 + softmax(deformations) ----------
__global__ void k_routed(const float* __restrict__ ctrl, const float* __restrict__ defm,
                         const float* __restrict__ router,
                         float* __restrict__ w_routed, float* __restrict__ w_sm,
                         float* __restrict__ out1){
  int idx = blockIdx.x*blockDim.x + threadIdx.x;
  if (idx < 32768){
    int f = idx & 127, r = (idx >> 7) & 31, be = idx >> 12;
    float acc = 0.0f;
#pragma unroll
    for (int c = 0; c < 16; c++)
      acc += ctrl[(be*16 + c)*128 + f] * router[c*32 + r];
    w_routed[idx] = acc;
    out1[idx] = acc;
  } else if (idx < 32768 + 1024){
    int j = idx - 32768;
    int f = j & 127, be = j >> 7;
    float v[4];
#pragma unroll
    for (int x = 0; x < 4; x++)
      v[x] = defm[(be*4 + x)*128 + f] + (x == 0 ? 1.0f : 0.0f);
    float mx = fmaxf(fmaxf(v[0], v[1]), fmaxf(v[2], v[3]));
    float s = 0.0f;
#pragma unroll
    for (int x = 0; x < 4; x++){ v[x] = expf(v[x] - mx); s += v[x]; }
#pragma unroll
    for (int x = 0; x < 4; x++) w_sm[(be*4 + x)*128 + f] = v[x]/s;
  }
}

// ---- resonance frames: packed complex irfft(2048) of x-pairs + hann -------
__global__ void k_frames(const float* __restrict__ amp, const float* __restrict__ phase,
                         const float* __restrict__ decay, float2* __restrict__ w_fr){
  const int wg = blockIdx.x;          // (r,p,f)
  const int f = wg & 31;
  const int rp = wg >> 5;             // r*2 + p
  const int p = rp & 1;
  const int r = rp >> 1;
  const int t = threadIdx.x;
  __shared__ float2 buf[2048];

  for (int k = t; k <= 1024; k += 256){
    float2 S[2];
#pragma unroll
    for (int d = 0; d < 2; d++){
      const int x = 2*p + d;
      const int base = (r*1025 + k)*4 + x;
      float a  = fabsf(amp[base]);
      float ph = tanhf(phase[base]) * PI_F;
      float sg = 1.0f / (1.0f + expf(-decay[base]));
      float dc = 0.5f + 0.45f * sg;
      float mag = expf(logf(dc + 1e-12f) * (float)(f+1)) * a;
      float snv, csv;
      sincosf(ph, &snv, &csv);
      float re = mag * csv, im = mag * snv;
      if (k == 0 || k == 1024) im = 0.0f;
      S[d] = make_float2(re, im);
    }
    buf[__brev((uint32_t)k) >> 21] =
        make_float2(S[0].x - S[1].y, S[0].y + S[1].x);
    if (k >= 1 && k <= 1023)
      buf[__brev((uint32_t)(2048 - k)) >> 21] =
          make_float2(S[0].x + S[1].y, -S[0].y + S[1].x);
  }
  __syncthreads();
  for (int s = 10; s >= 0; s--){
    const int ls = 10 - s;
    const int hl = 1 << ls;
    for (int bi = t; bi < 1024; bi += 256){
      const int g = bi >> ls, j = bi & (hl - 1);
      const int i0 = g*2*hl + j, i1 = i0 + hl;
      float2 pp = buf[i0], qq = buf[i1];
      float2 w = twid((uint32_t)(j << s), UNIT2K, +1.0f);
      float2 v = cmul(qq, w);
      buf[i0] = make_float2(pp.x+v.x, pp.y+v.y);
      buf[i1] = make_float2(pp.x-v.x, pp.y-v.y);
    }
    __syncthreads();
  }
  float2* O = w_fr + (size_t)wg*2048;
  for (int u = t; u < 2048; u += 256){
    float hann = 0.5f - 0.5f*cosf(TWOPI_F * (float)u / 2048.0f);
    float sc = (1.0f/2048.0f) * hann;
    O[u] = make_float2(buf[u].x*sc, buf[u].y*sc);
  }
}

// ---- OLA + transpose + sum-of-squares ------------------------------------
__global__ void k_ola(const float2* __restrict__ w_fr, float* __restrict__ w_resT,
                      float* __restrict__ w_sumsq){
  const int wg = blockIdx.x;           // rp*8 + cq
  const int cq = wg & 7;
  const int rp = wg >> 3;
  const int c0 = cq*32;
  const int r = rp >> 1, p = rp & 1;
  const int ch0 = r*4 + p*2;
  const int t = threadIdx.x;
  __shared__ float tx[32][129], ty[32][129];
  __shared__ float red[2][256];
  const float2* F = w_fr + (size_t)rp*32*2048;
  float acc0 = 0.0f, acc1 = 0.0f;
#pragma unroll
  for (int it = 0; it < 16; it++){
    const int idx = it*256 + t;        // m*32 + c'  (time-ordered reads)
    const int cp = idx & 31, m = idx >> 5;
    const int n = c0 + cp + 256*m;
    const int f = n >> 10, u = n & 1023;
    float2 a = F[(size_t)f*2048 + u];
    float vx = a.x, vy = a.y;
    if (f > 0){
      float2 b = F[(size_t)(f-1)*2048 + u + 1024];
      vx += b.x; vy += b.y;
    }
    tx[cp][m] = vx; ty[cp][m] = vy;
    acc0 += vx*vx; acc1 += vy*vy;
  }
  red[0][t] = acc0; red[1][t] = acc1;
  __syncthreads();
#pragma unroll
  for (int it = 0; it < 16; it++){
    const int idx = it*256 + t;        // c'*128 + m  (contiguous writes)
    const int m = idx & 127, cp = idx >> 7;
    w_resT[(size_t)ch0*32768 + (size_t)(c0+cp)*128 + m]     = tx[cp][m];
    w_resT[(size_t)(ch0+1)*32768 + (size_t)(c0+cp)*128 + m] = ty[cp][m];
  }
  for (int off = 128; off > 0; off >>= 1){
    __syncthreads();
    if (t < off){ red[0][t] += red[0][t+off]; red[1][t] += red[1][t+off]; }
  }
  if (t == 0){
    atomicAdd(&w_sumsq[ch0],     red[0][0]);
    atomicAdd(&w_sumsq[ch0 + 1], red[1][0]);
  }
}

// ---------------- invnorm from sumsq (1 tiny block) ------------------------
__global__ void k_norm(const float* __restrict__ w_sumsq, float* __restrict__ w_invnorm){
  const int s = threadIdx.x;
  if (s < 128) w_invnorm[s] = 1.0f/(sqrtf(w_sumsq[s]) + 1e-8f);
}

// --------- forward comb stages (s=0..7): 256-pt DIF over m per comb --------
// mode 0 (sig=r*2+p <64): packed res pair -> outf (fp32)
// mode 1 (sig<256): ru real -> outh (fp16)
__global__ void k_fwdA(const int mode, const float* __restrict__ w_resT,
                       const float* __restrict__ w_invnorm,
                       const float* __restrict__ w_routed,
                       float2* __restrict__ outf, __half2* __restrict__ outh){
  const int wg = blockIdx.x;
  const int cpair = wg & 127;
  const int sig = wg >> 7;
  const int c0 = cpair*2;
  const int t = threadIdx.x;
  __shared__ float re[2][264], im[2][264];
#pragma unroll
  for (int i = 0; i < 2; i++){
    const int li = t + i*256;
    const int cc = li >> 8, m = li & 255;
    const int c = c0 + cc;
    float vx = 0.0f, vy = 0.0f;
    if (m < 128){                       // n = c + 256*m < 32768
      if (mode == 0){
        const int rr = sig >> 1, pq = sig & 1;
        const int ch0 = rr*4 + pq*2;
        vx = w_resT[(size_t)ch0*32768 + c*128 + m] * w_invnorm[ch0];
        vy = w_resT[(size_t)(ch0+1)*32768 + c*128 + m] * w_invnorm[ch0+1];
      } else {
        const int n = c + 256*m;
        int lo, hi; float w;
        interp128(n, lo, hi, w);
        const float* rp = w_routed + sig*128;
        float rv = rp[lo]*(1.0f - w) + rp[hi]*w;
        vx = rv * jax_noise((uint32_t)sig*32768u + (uint32_t)n);
      }
    }
    re[cc][SK(m)] = vx; im[cc][SK(m)] = vy;
  }
  __syncthreads();
  const int arr = t >> 7, b = t & 127;
  for (int s = 0; s < 8; s++){
    const int ls = 7 - s;
    const int hl = 1 << ls;
    const int g = b >> ls, j = b & (hl - 1);
    const int i0 = g*2*hl + j, i1 = i0 + hl;
    float2 u = make_float2(re[arr][SK(i0)], im[arr][SK(i0)]);
    float2 v = make_float2(re[arr][SK(i1)], im[arr][SK(i1)]);
    uint32_t e = (((uint32_t)(c0 + arr) + 256u*(uint32_t)j) << s) & 0xFFFFu;
    float2 w = twid(e, UNIT64K, -1.0f);
    re[arr][SK(i0)] = u.x + v.x; im[arr][SK(i0)] = u.y + v.y;
    float2 d = make_float2(u.x - v.x, u.y - v.y);
    float2 dv = cmul(d, w);
    re[arr][SK(i1)] = dv.x; im[arr][SK(i1)] = dv.y;
    __syncthreads();
  }
#pragma unroll
  for (int i = 0; i < 2; i++){
    const int li = t + i*256;
    const int cc = li >> 8, m = li & 255;
    const size_t idx = (size_t)sig*65536 + (size_t)(c0+cc)*256 + m;
    if (mode == 0)
      outf[idx] = make_float2(re[cc][SK(m)], im[cc][SK(m)]);
    else
      outh[idx] = __floats2half2_rn(re[cc][SK(m)], im[cc][SK(m)]);
  }
}

// ------- forward block stages (s=8..15) for res spectra: fp32 -> fp16 ------
__global__ void k_fwdB(const float2* __restrict__ specf, __half2* __restrict__ spech){
  const int wg = blockIdx.x;
  const int mq = wg & 15;
  const int sig = wg >> 4;
  const int m16 = mq*16;
  const int t = threadIdx.x;
  __shared__ float re[16][RP], im[16][RP];
  const float2* base = specf + (size_t)sig*65536;
#pragma unroll
  for (int i = 0; i < 16; i++){
    const int li = t + i*256;          // li = c*16 + mm
    const int mm = li & 15, c = li >> 4;
    float2 v = base[(size_t)c*256 + m16 + mm];
    re[mm][SK(c)] = v.x; im[mm][SK(c)] = v.y;
  }
  __syncthreads();
  fwd_block_fft(re, im, t);
  __half2* outb = spech + (size_t)sig*65536;
#pragma unroll
  for (int i = 0; i < 16; i++){
    const int li = t + i*256;
    const int mm = li & 15, c = li >> 4;
    outb[(size_t)c*256 + m16 + mm] = __floats2half2_rn(re[mm][SK(c)], im[mm][SK(c)]);
  }
}

// ---- FUSED: ru fwd block stages + product(p=0,1)*scale + inv block stages --
__global__ __launch_bounds__(256, 3)
void k_conv(const __half2* __restrict__ ruspec,
            const __half2* __restrict__ respspec,
            __half2* __restrict__ chunkbuf, const int gbase){
  const int wg = blockIdx.x;
  const int mq = wg & 15;
  const int gl = wg >> 4;
  const int g = gbase + gl;
  const int r = g & 31;
  const int m16 = mq*16;
  const int t = threadIdx.x;
  __shared__ float re[16][RP], im[16][RP];
  __shared__ __half2 Fh[4096];
  const __half2* A = ruspec + (size_t)g*65536;
#pragma unroll
  for (int i = 0; i < 16; i++){
    const int li = t + i*256;          // li = c*16 + mm
    const int mm = li & 15, c = li >> 4;
    float2 v = __half22float2(A[(size_t)c*256 + m16 + mm]);
    re[mm][SK(c)] = v.x; im[mm][SK(c)] = v.y;
  }
  __syncthreads();
  fwd_block_fft(re, im, t);
  // snapshot fwd spectrum to fp16 LDS (per-thread-owned cells, no sync)
#pragma unroll
  for (int i = 0; i < 16; i++){
    const int li = t + i*256;
    const int mm = li & 15, c = li >> 4;
    Fh[li] = __floats2half2_rn(re[mm][SK(c)], im[mm][SK(c)]);
  }
#pragma unroll 1
  for (int p = 0; p < 2; p++){
    __syncthreads();                   // protect work LDS vs prior reads
    const __half2* B = respspec + (size_t)(r*2 + p)*65536;
#pragma unroll
    for (int i = 0; i < 16; i++){
      const int li = t + i*256;
      const int mm = li & 15, c = li >> 4;
      float2 b = __half22float2(B[(size_t)c*256 + m16 + mm]);
      float2 f = __half22float2(Fh[li]);
      re[mm][SK(c)] = (f.x*b.x - f.y*b.y) * SCALE64K;
      im[mm][SK(c)] = (f.x*b.y + f.y*b.x) * SCALE64K;
    }
    __syncthreads();
    inv_block_fft(re, im, t);
    __half2* O = chunkbuf + (size_t)(gl*2 + p)*65536;
#pragma unroll
    for (int i = 0; i < 16; i++){
      const int li = t + i*256;        // li = mm*256 + c -> contiguous rows
      const int mm = li >> 8, c = li & 255;
      O[(size_t)(m16+mm)*256 + c] = __floats2half2_rn(re[mm][SK(c)], im[mm][SK(c)]);
    }
  }
}

// -- inverse comb stages (s=7..0, fused pairs): 16 c x 2 p, fused epilogue --
__global__ __launch_bounds__(256, 4)
void k_invA_w(const __half2* __restrict__ chunkbuf, const int gbase,
              const float* __restrict__ w_sm, const float* __restrict__ gains,
              float* __restrict__ out0){
  const int wg = blockIdx.x;
  const int c16 = wg & 15;
  const int gl = wg >> 4;
  const int g = gbase + gl;
  const int r = g & 31, be = g >> 5;
  const int c0 = c16*16;
  const int t = threadIdx.x;
  __shared__ __half2 zz[2][16][RP];
#pragma unroll
  for (int p = 0; p < 2; p++){
    const __half2* C = chunkbuf + (size_t)(gl*2 + p)*65536;
#pragma unroll
    for (int i = 0; i < 16; i++){
      const int li = t + i*256;        // li = m*16 + cc -> 64B clusters
      const int cc = li & 15, m = li >> 4;
      zz[p][cc][SK(m)] = C[(size_t)m*256 + c0 + cc];
    }
  }
  __syncthreads();
  for (int sp = 0; sp < 4; sp++){
    const int sA = 7 - 2*sp, sB = sA - 1;
    const int hA = 1 << (2*sp);        // 1,4,16,64
    const int lA = 2*sp;
#pragma unroll
    for (int it = 0; it < 8; it++){
      const int qq = t + it*256;       // 2048 quads: row(5) q(6)
      const int row = qq >> 6, q = qq & 63;
      const int p = row >> 4, cc = row & 15;
      const int j = q & (hA - 1), gq = q >> lA;
      const int base = gq*4*hA + j;
      __half2* Z = zz[p][cc];
      const int i0 = SK(base), i1 = SK(base+hA), i2 = SK(base+2*hA), i3 = SK(base+3*hA);
      float2 u0 = __half22float2(Z[i0]);
      float2 u1 = __half22float2(Z[i1]);
      float2 u2 = __half22float2(Z[i2]);
      float2 u3 = __half22float2(Z[i3]);
      const uint32_t cg = (uint32_t)(c0 + cc);
      float2 wA  = twid(((cg + 256u*(uint32_t)j) << sA) & 0xFFFFu, UNIT64K, +1.0f);
      float2 wB0 = twid(((cg + 256u*(uint32_t)j) << sB) & 0xFFFFu, UNIT64K, +1.0f);
      float2 wB1 = twid(((cg + 256u*(uint32_t)(j + hA)) << sB) & 0xFFFFu, UNIT64K, +1.0f);
      bfly_inv(u0, u1, wA);
      bfly_inv(u2, u3, wA);
      bfly_inv(u0, u2, wB0);
      bfly_inv(u1, u3, wB1);
      Z[i0] = __floats2half2_rn(u0.x, u0.y);
      Z[i1] = __floats2half2_rn(u1.x, u1.y);
      Z[i2] = __floats2half2_rn(u2.x, u2.y);
      Z[i3] = __floats2half2_rn(u3.x, u3.y);
    }
    __syncthreads();
  }
  const float gv = fabsf(gains[r]);
  const float* smb = w_sm + be*512;
#pragma unroll
  for (int it = 0; it < 8; it++){
    const int li = t + it*256;         // li = m*16 + cc, m < 128
    const int cc = li & 15, m = li >> 4;
    const int tt = c0 + cc + 256*m;
    int lo, hi; float w;
    interp128(tt, lo, hi, w);
    float2 z0 = __half22float2(zz[0][cc][SK(m)]);
    float2 z1 = __half22float2(zz[1][cc][SK(m)]);
    float dw0 = smb[0*128 + lo]*(1.0f - w) + smb[0*128 + hi]*w;
    float dw1 = smb[1*128 + lo]*(1.0f - w) + smb[1*128 + hi]*w;
    float dw2 = smb[2*128 + lo]*(1.0f - w) + smb[2*128 + hi]*w;
    float dw3 = smb[3*128 + lo]*(1.0f - w) + smb[3*128 + hi]*w;
    float val = dw0*z0.x + dw1*z0.y + dw2*z1.x + dw3*z1.y;  // scale pre-folded
    atomicAdd(&out0[(size_t)be*32768 + tt], tanhf(val*gv));
  }
}

extern "C" void kernel_launch(void* const* d_in, const int* in_sizes, int n_in,
                              void* d_out, int out_size, void* d_ws, size_t ws_size,
                              hipStream_t stream){
  const float* ctrl   = (const float*)d_in[0];
  const float* defm   = (const float*)d_in[1];
  const float* router = (const float*)d_in[2];
  const float* amp    = (const float*)d_in[3];
  const float* phase  = (const float*)d_in[4];
  const float* decay  = (const float*)d_in[5];
  const float* gains  = (const float*)d_in[6];
  float* out = (float*)d_out;
  float* ws  = (float*)d_ws;

  // ws layout (float offsets)
  float*   w_resT    = ws;                          // 4,194,304
  float*   w_routed  = ws + 4194304;                // 32,768
  float*   w_sm      = ws + 4227072;                // 4,096
  float*   w_invnorm = ws + 4231168;                // 128
  float*   w_sumsq   = ws + 4231296;                // 128
  __half2* ruspec_h  = (__half2*)(ws + 4231424);    // 256*65536 h2 = 16,777,216 f
  float2*  resp_f    = (float2*)(ws + 21008640);    // 64*65536 c   =  8,388,608 f
  __half2* resp_h    = (__half2*)(ws + 29397248);   // 64*65536 h2  =  4,194,304 f
  __half2* chunk_h   = (__half2*)(ws + 33591552);   // 2G*65536 h2  = G*131,072 f
  const size_t base_f = 33591552;
  // frames scratch aliases ruspec_h region (ruspec written later by fwdA)
  float2* w_fr       = (float2*)ruspec_h;           // 2048*2048 c = 8,388,608 f

  int G = 0;
  for (int gg = 128; gg >= 1; gg >>= 1){
    size_t need = (base_f + (size_t)gg*131072) * sizeof(float);
    if (need <= ws_size){ G = gg; break; }
  }

  hipMemsetAsync(d_out, 0, 262144*sizeof(float), stream);  // out0 (atomicAdd)
  k_routed<<<132, 256, 0, stream>>>(ctrl, defm, router, w_routed, w_sm, out + 262144);
  if (G == 0) return;  // diagnostic: out1 ok, out0 stays 0 => ws too small

  hipMemsetAsync(w_sumsq, 0, 128*sizeof(float), stream);
  k_frames<<<2048, 256, 0, stream>>>(amp, phase, decay, w_fr);
  k_ola<<<512, 256, 0, stream>>>(w_fr, w_resT, w_sumsq);
  k_norm<<<1, 128, 0, stream>>>(w_sumsq, w_invnorm);
  k_fwdA<<<64*128, 256, 0, stream>>>(0, w_resT, w_invnorm, w_routed, resp_f,
                                     (__half2*)nullptr);
  k_fwdB<<<64*16, 256, 0, stream>>>(resp_f, resp_h);
  k_fwdA<<<256*128, 256, 0, stream>>>(1, w_resT, w_invnorm, w_routed,
                                      (float2*)nullptr, ruspec_h);
  for (int gb = 0; gb < 256; gb += G){
    k_conv<<<G*16, 256, 0, stream>>>(ruspec_h, resp_h, chunk_h, gb);
    k_invA_w<<<G*16, 256, 0, stream>>>(chunk_h, gb, w_sm, gains, out);
  }
}

// Round 8
// 459.586 us; speedup vs baseline: 1.7547x; 1.1197x over previous
//
#include <hip/hip_runtime.h>
#include <hip/hip_fp16.h>
#include <stdint.h>

// ResonanceLayer: routed einsum -> resonance irfft (x-pair packed, frames to
// scratch) -> OLA+transpose+norm -> upsample*threefry-noise -> 65536-pt FFT
// convolution with complex-packed res spectra -> softmax-deformation mix ->
// tanh(gain*x) summed over resonators.
//
// Round-8: the fused-pair quad loops in fwd/inv_block_fft go from full unroll
// (x4) to `#pragma unroll 1`. Round-7's full unroll kept ~80 values live
// (32 loaded floats + addresses + twiddles) while pipelining ds_reads ->
// scratch spill: k_conv FETCH 97->142MB, WRITE 64->145MB with no new explicit
// HBM accesses. One quad per trip keeps ~20 live; 12 waves/CU hide latency.

#define PI_F     3.14159265358979323846f
#define TWOPI_F  6.28318530717958647692f
#define UNIT64K  (TWOPI_F/65536.0f)
#define UNIT2K   (TWOPI_F/2048.0f)
#define SCALE64K (1.0f/65536.0f)
#define SK(i)    ((i) + ((i) >> 5))      // within-row skew for stride patterns
#define RP 265                           // row pitch: 9 mod 32, spreads rows

__device__ __forceinline__ float2 cmul(float2 a, float2 b){
  return make_float2(a.x*b.x - a.y*b.y, a.x*b.y + a.y*b.x);
}

__device__ __forceinline__ float2 twid(uint32_t e, float unit, float sign){
  float ang = (float)e * unit;
  float sn, cn;
  __sincosf(ang, &sn, &cn);
  return make_float2(cn, sign*sn);
}

// DIF butterfly: u' = u+v ; v' = (u-v)*w
__device__ __forceinline__ void bfly_fwd(float2& u, float2& v, float2 w){
  float2 d = make_float2(u.x - v.x, u.y - v.y);
  u = make_float2(u.x + v.x, u.y + v.y);
  v = cmul(d, w);
}
// DIT butterfly: t = v*w ; u' = u+t ; v' = u-t
__device__ __forceinline__ void bfly_inv(float2& u, float2& v, float2 w){
  float2 tv = cmul(v, w);
  v = make_float2(u.x - tv.x, u.y - tv.y);
  u = make_float2(u.x + tv.x, u.y + tv.y);
}

__device__ __forceinline__ uint32_t rotl32(uint32_t v, int r){
  return (v << r) | (v >> (32 - r));
}

// Threefry-2x32, key = (0, 123)
__device__ __forceinline__ void threefry2x32(uint32_t c0, uint32_t c1,
                                             uint32_t& o0, uint32_t& o1){
  const uint32_t k0 = 0u, k1 = 123u;
  const uint32_t k2 = 0x1BD11BDAu ^ k0 ^ k1;
  const uint32_t ks[3] = {k0, k1, k2};
  uint32_t x0 = c0 + k0, x1 = c1 + k1;
#pragma unroll
  for (int i = 0; i < 5; i++){
    if ((i & 1) == 0){
      x0 += x1; x1 = rotl32(x1,13); x1 ^= x0;
      x0 += x1; x1 = rotl32(x1,15); x1 ^= x0;
      x0 += x1; x1 = rotl32(x1,26); x1 ^= x0;
      x0 += x1; x1 = rotl32(x1, 6); x1 ^= x0;
    } else {
      x0 += x1; x1 = rotl32(x1,17); x1 ^= x0;
      x0 += x1; x1 = rotl32(x1,29); x1 ^= x0;
      x0 += x1; x1 = rotl32(x1,16); x1 ^= x0;
      x0 += x1; x1 = rotl32(x1,24); x1 ^= x0;
    }
    x0 += ks[(i+1)%3];
    x1 += ks[(i+2)%3] + (uint32_t)(i+1);
  }
  o0 = x0; o1 = x1;
}

__device__ __forceinline__ float jax_noise(uint32_t p){
  uint32_t b0, b1;
  threefry2x32(0u, p, b0, b1);
  uint32_t bits = b0 ^ b1;
  float u = __uint_as_float((bits >> 9) | 0x3f800000u) - 1.0f;
  return fmaxf(-1.0f, u*2.0f - 1.0f);
}

__device__ __forceinline__ void interp128(int t, int& lo, int& hi, float& w){
  float posf = ((float)t + 0.5f) * (1.0f/256.0f) - 0.5f;
  posf = fminf(fmaxf(posf, 0.0f), 127.0f);
  lo = (int)posf;
  hi = lo + 1; if (hi > 127) hi = 127;
  w = posf - (float)lo;
}

// ---- fused-pair forward block FFT (DIF, stages 8..15) on 16x256 rows ------
__device__ __forceinline__ void fwd_block_fft(float (*re)[RP], float (*im)[RP],
                                              const int t){
  for (int sp = 0; sp < 4; sp++){
    const int s  = 8 + 2*sp;
    const int hl = 1 << (7 - 2*sp);    // 128,32,8,2
    const int hh = hl >> 1;            // 64,16,4,1
    const int lj = 6 - 2*sp;
#pragma unroll 1
    for (int it = 0; it < 4; it++){
      const int qq = t + it*256;
      const int row = qq >> 6, q = qq & 63;
      const int j = q & (hh - 1), g = q >> lj;
      const int base = g*2*hl + j;
      float* R = re[row]; float* I = im[row];
      const int i0 = SK(base), i1 = SK(base+hh), i2 = SK(base+hl), i3 = SK(base+hl+hh);
      float2 u0 = make_float2(R[i0], I[i0]);
      float2 u1 = make_float2(R[i1], I[i1]);
      float2 u2 = make_float2(R[i2], I[i2]);
      float2 u3 = make_float2(R[i3], I[i3]);
      float2 wA0 = twid((uint32_t)(j << s),        UNIT64K, -1.0f);
      float2 wA1 = twid((uint32_t)((j + hh) << s), UNIT64K, -1.0f);
      float2 wB  = twid((uint32_t)(j << (s + 1)),  UNIT64K, -1.0f);
      bfly_fwd(u0, u2, wA0);
      bfly_fwd(u1, u3, wA1);
      bfly_fwd(u0, u1, wB);
      bfly_fwd(u2, u3, wB);
      R[i0] = u0.x; I[i0] = u0.y;
      R[i1] = u1.x; I[i1] = u1.y;
      R[i2] = u2.x; I[i2] = u2.y;
      R[i3] = u3.x; I[i3] = u3.y;
    }
    __syncthreads();
  }
}

// ---- fused-pair inverse block FFT (DIT, stages 15..8) on 16x256 rows ------
__device__ __forceinline__ void inv_block_fft(float (*re)[RP], float (*im)[RP],
                                              const int t){
  for (int sp = 0; sp < 4; sp++){
    const int sA = 15 - 2*sp, sB = sA - 1;
    const int hA = 1 << (2*sp);        // 1,4,16,64
    const int lA = 2*sp;
#pragma unroll 1
    for (int it = 0; it < 4; it++){
      const int qq = t + it*256;
      const int row = qq >> 6, q = qq & 63;
      const int j = q & (hA - 1), g = q >> lA;
      const int base = g*4*hA + j;
      float* R = re[row]; float* I = im[row];
      const int i0 = SK(base), i1 = SK(base+hA), i2 = SK(base+2*hA), i3 = SK(base+3*hA);
      float2 u0 = make_float2(R[i0], I[i0]);
      float2 u1 = make_float2(R[i1], I[i1]);
      float2 u2 = make_float2(R[i2], I[i2]);
      float2 u3 = make_float2(R[i3], I[i3]);
      float2 wA  = twid((uint32_t)(j << sA),        UNIT64K, +1.0f);
      float2 wB0 = twid((uint32_t)(j << sB),        UNIT64K, +1.0f);
      float2 wB1 = twid((uint32_t)((j + hA) << sB), UNIT64K, +1.0f);
      bfly_inv(u0, u1, wA);
      bfly_inv(u2, u3, wA);
      bfly_inv(u0, u2, wB0);
      bfly_inv(u1, u3, wB1);
      R[i0] = u0.x; I[i0] = u0.y;
      R[i1] = u1.x; I[i1] = u1.y;
      R[i2] = u2.x; I[i2] = u2.y;
      R[i3] = u3.x; I[i3] = u3.y;
    }
    __syncthreads();
  }
}

// ---------------- routed einsum + output1 + softmax(deformations) ----------
__global__ void k_routed(const float* __restrict__ ctrl, const float* __restrict__ defm,
                         const float* __restrict__ router,
                         float* __restrict__ w_routed, float* __restrict__ w_sm,
                         float* __restrict__ out1){
  int idx = blockIdx.x*blockDim.x + threadIdx.x;
  if (idx < 32768){
    int f = idx & 127, r = (idx >> 7) & 31, be = idx >> 12;
    float acc = 0.0f;
#pragma unroll
    for (int c = 0; c < 16; c++)
      acc += ctrl[(be*16 + c)*128 + f] * router[c*32 + r];
    w_routed[idx] = acc;
    out1[idx] = acc;
  } else if (idx < 32768 + 1024){
    int j = idx - 32768;
    int f = j & 127, be = j >> 7;
    float v[4];
#pragma unroll
    for (int x = 0; x < 4; x++)
      v[x] = defm[(be*4 + x)*128 + f] + (x == 0 ? 1.0f : 0.0f);
    float mx = fmaxf(fmaxf(v[0], v[1]), fmaxf(v[2], v[3]));
    float s = 0.0f;
#pragma unroll
    for (int x = 0; x < 4; x++){ v[x] = expf(v[x] - mx); s += v[x]; }
#pragma unroll
    for (int x = 0; x < 4; x++) w_sm[(be*4 + x)*128 + f] = v[x]/s;
  }
}

// ---- resonance frames: packed complex irfft(2048) of x-pairs + hann -------
__global__ void k_frames(const float* __restrict__ amp, const float* __restrict__ phase,
                         const float* __restrict__ decay, float2* __restrict__ w_fr){
  const int wg = blockIdx.x;          // (r,p,f)
  const int f = wg & 31;
  const int rp = wg >> 5;             // r*2 + p
  const int p = rp & 1;
  const int r = rp >> 1;
  const int t = threadIdx.x;
  __shared__ float2 buf[2048];

  for (int k = t; k <= 1024; k += 256){
    float2 S[2];
#pragma unroll
    for (int d = 0; d < 2; d++){
      const int x = 2*p + d;
      const int base = (r*1025 + k)*4 + x;
      float a  = fabsf(amp[base]);
      float ph = tanhf(phase[base]) * PI_F;
      float sg = 1.0f / (1.0f + expf(-decay[base]));
      float dc = 0.5f + 0.45f * sg;
      float mag = expf(logf(dc + 1e-12f) * (float)(f+1)) * a;
      float snv, csv;
      sincosf(ph, &snv, &csv);
      float re = mag * csv, im = mag * snv;
      if (k == 0 || k == 1024) im = 0.0f;
      S[d] = make_float2(re, im);
    }
    buf[__brev((uint32_t)k) >> 21] =
        make_float2(S[0].x - S[1].y, S[0].y + S[1].x);
    if (k >= 1 && k <= 1023)
      buf[__brev((uint32_t)(2048 - k)) >> 21] =
          make_float2(S[0].x + S[1].y, -S[0].y + S[1].x);
  }
  __syncthreads();
  for (int s = 10; s >= 0; s--){
    const int ls = 10 - s;
    const int hl = 1 << ls;
    for (int bi = t; bi < 1024; bi += 256){
      const int g = bi >> ls, j = bi & (hl - 1);
      const int i0 = g*2*hl + j, i1 = i0 + hl;
      float2 pp = buf[i0], qq = buf[i1];
      float2 w = twid((uint32_t)(j << s), UNIT2K, +1.0f);
      float2 v = cmul(qq, w);
      buf[i0] = make_float2(pp.x+v.x, pp.y+v.y);
      buf[i1] = make_float2(pp.x-v.x, pp.y-v.y);
    }
    __syncthreads();
  }
  float2* O = w_fr + (size_t)wg*2048;
  for (int u = t; u < 2048; u += 256){
    float hann = 0.5f - 0.5f*cosf(TWOPI_F * (float)u / 2048.0f);
    float sc = (1.0f/2048.0f) * hann;
    O[u] = make_float2(buf[u].x*sc, buf[u].y*sc);
  }
}

// ---- OLA + transpose + sum-of-squares ------------------------------------
__global__ void k_ola(const float2* __restrict__ w_fr, float* __restrict__ w_resT,
                      float* __restrict__ w_sumsq){
  const int wg = blockIdx.x;           // rp*8 + cq
  const int cq = wg & 7;
  const int rp = wg >> 3;
  const int c0 = cq*32;
  const int r = rp >> 1, p = rp & 1;
  const int ch0 = r*4 + p*2;
  const int t = threadIdx.x;
  __shared__ float tx[32][129], ty[32][129];
  __shared__ float red[2][256];
  const float2* F = w_fr + (size_t)rp*32*2048;
  float acc0 = 0.0f, acc1 = 0.0f;
#pragma unroll
  for (int it = 0; it < 16; it++){
    const int idx = it*256 + t;        // m*32 + c'  (time-ordered reads)
    const int cp = idx & 31, m = idx >> 5;
    const int n = c0 + cp + 256*m;
    const int f = n >> 10, u = n & 1023;
    float2 a = F[(size_t)f*2048 + u];
    float vx = a.x, vy = a.y;
    if (f > 0){
      float2 b = F[(size_t)(f-1)*2048 + u + 1024];
      vx += b.x; vy += b.y;
    }
    tx[cp][m] = vx; ty[cp][m] = vy;
    acc0 += vx*vx; acc1 += vy*vy;
  }
  red[0][t] = acc0; red[1][t] = acc1;
  __syncthreads();
#pragma unroll
  for (int it = 0; it < 16; it++){
    const int idx = it*256 + t;        // c'*128 + m  (contiguous writes)
    const int m = idx & 127, cp = idx >> 7;
    w_resT[(size_t)ch0*32768 + (size_t)(c0+cp)*128 + m]     = tx[cp][m];
    w_resT[(size_t)(ch0+1)*32768 + (size_t)(c0+cp)*128 + m] = ty[cp][m];
  }
  for (int off = 128; off > 0; off >>= 1){
    __syncthreads();
    if (t < off){ red[0][t] += red[0][t+off]; red[1][t] += red[1][t+off]; }
  }
  if (t == 0){
    atomicAdd(&w_sumsq[ch0],     red[0][0]);
    atomicAdd(&w_sumsq[ch0 + 1], red[1][0]);
  }
}

// ---------------- invnorm from sumsq (1 tiny block) ------------------------
__global__ void k_norm(const float* __restrict__ w_sumsq, float* __restrict__ w_invnorm){
  const int s = threadIdx.x;
  if (s < 128) w_invnorm[s] = 1.0f/(sqrtf(w_sumsq[s]) + 1e-8f);
}

// --------- forward comb stages (s=0..7): 256-pt DIF over m per comb --------
// mode 0 (sig=r*2+p <64): packed res pair -> outf (fp32)
// mode 1 (sig<256): ru real -> outh (fp16)
__global__ void k_fwdA(const int mode, const float* __restrict__ w_resT,
                       const float* __restrict__ w_invnorm,
                       const float* __restrict__ w_routed,
                       float2* __restrict__ outf, __half2* __restrict__ outh){
  const int wg = blockIdx.x;
  const int cpair = wg & 127;
  const int sig = wg >> 7;
  const int c0 = cpair*2;
  const int t = threadIdx.x;
  __shared__ float re[2][264], im[2][264];
#pragma unroll
  for (int i = 0; i < 2; i++){
    const int li = t + i*256;
    const int cc = li >> 8, m = li & 255;
    const int c = c0 + cc;
    float vx = 0.0f, vy = 0.0f;
    if (m < 128){                       // n = c + 256*m < 32768
      if (mode == 0){
        const int rr = sig >> 1, pq = sig & 1;
        const int ch0 = rr*4 + pq*2;
        vx = w_resT[(size_t)ch0*32768 + c*128 + m] * w_invnorm[ch0];
        vy = w_resT[(size_t)(ch0+1)*32768 + c*128 + m] * w_invnorm[ch0+1];
      } else {
        const int n = c + 256*m;
        int lo, hi; float w;
        interp128(n, lo, hi, w);
        const float* rp = w_routed + sig*128;
        float rv = rp[lo]*(1.0f - w) + rp[hi]*w;
        vx = rv * jax_noise((uint32_t)sig*32768u + (uint32_t)n);
      }
    }
    re[cc][SK(m)] = vx; im[cc][SK(m)] = vy;
  }
  __syncthreads();
  const int arr = t >> 7, b = t & 127;
  for (int s = 0; s < 8; s++){
    const int ls = 7 - s;
    const int hl = 1 << ls;
    const int g = b >> ls, j = b & (hl - 1);
    const int i0 = g*2*hl + j, i1 = i0 + hl;
    float2 u = make_float2(re[arr][SK(i0)], im[arr][SK(i0)]);
    float2 v = make_float2(re[arr][SK(i1)], im[arr][SK(i1)]);
    uint32_t e = (((uint32_t)(c0 + arr) + 256u*(uint32_t)j) << s) & 0xFFFFu;
    float2 w = twid(e, UNIT64K, -1.0f);
    re[arr][SK(i0)] = u.x + v.x; im[arr][SK(i0)] = u.y + v.y;
    float2 d = make_float2(u.x - v.x, u.y - v.y);
    float2 dv = cmul(d, w);
    re[arr][SK(i1)] = dv.x; im[arr][SK(i1)] = dv.y;
    __syncthreads();
  }
#pragma unroll
  for (int i = 0; i < 2; i++){
    const int li = t + i*256;
    const int cc = li >> 8, m = li & 255;
    const size_t idx = (size_t)sig*65536 + (size_t)(c0+cc)*256 + m;
    if (mode == 0)
      outf[idx] = make_float2(re[cc][SK(m)], im[cc][SK(m)]);
    else
      outh[idx] = __floats2half2_rn(re[cc][SK(m)], im[cc][SK(m)]);
  }
}

// ------- forward block stages (s=8..15) for res spectra: fp32 -> fp16 ------
__global__ void k_fwdB(const float2* __restrict__ specf, __half2* __restrict__ spech){
  const int wg = blockIdx.x;
  const int mq = wg & 15;
  const int sig = wg >> 4;
  const int m16 = mq*16;
  const int t = threadIdx.x;
  __shared__ float re[16][RP], im[16][RP];
  const float2* base = specf + (size_t)sig*65536;
#pragma unroll
  for (int i = 0; i < 16; i++){
    const int li = t + i*256;          // li = c*16 + mm
    const int mm = li & 15, c = li >> 4;
    float2 v = base[(size_t)c*256 + m16 + mm];
    re[mm][SK(c)] = v.x; im[mm][SK(c)] = v.y;
  }
  __syncthreads();
  fwd_block_fft(re, im, t);
  __half2* outb = spech + (size_t)sig*65536;
#pragma unroll
  for (int i = 0; i < 16; i++){
    const int li = t + i*256;
    const int mm = li & 15, c = li >> 4;
    outb[(size_t)c*256 + m16 + mm] = __floats2half2_rn(re[mm][SK(c)], im[mm][SK(c)]);
  }
}

// ---- FUSED: ru fwd block stages + product(p=0,1)*scale + inv block stages --
__global__ __launch_bounds__(256, 3)
void k_conv(const __half2* __restrict__ ruspec,
            const __half2* __restrict__ respspec,
            __half2* __restrict__ chunkbuf, const int gbase){
  const int wg = blockIdx.x;
  const int mq = wg & 15;
  const int gl = wg >> 4;
  const int g = gbase + gl;
  const int r = g & 31;
  const int m16 = mq*16;
  const int t = threadIdx.x;
  __shared__ float re[16][RP], im[16][RP];
  __shared__ __half2 Fh[4096];
  const __half2* A = ruspec + (size_t)g*65536;
#pragma unroll
  for (int i = 0; i < 16; i++){
    const int li = t + i*256;          // li = c*16 + mm
    const int mm = li & 15, c = li >> 4;
    float2 v = __half22float2(A[(size_t)c*256 + m16 + mm]);
    re[mm][SK(c)] = v.x; im[mm][SK(c)] = v.y;
  }
  __syncthreads();
  fwd_block_fft(re, im, t);
  // snapshot fwd spectrum to fp16 LDS (per-thread-owned cells, no sync)
#pragma unroll
  for (int i = 0; i < 16; i++){
    const int li = t + i*256;
    const int mm = li & 15, c = li >> 4;
    Fh[li] = __floats2half2_rn(re[mm][SK(c)], im[mm][SK(c)]);
  }
#pragma unroll 1
  for (int p = 0; p < 2; p++){
    __syncthreads();                   // protect work LDS vs prior reads
    const __half2* B = respspec + (size_t)(r*2 + p)*65536;
#pragma unroll
    for (int i = 0; i < 16; i++){
      const int li = t + i*256;
      const int mm = li & 15, c = li >> 4;
      float2 b = __half22float2(B[(size_t)c*256 + m16 + mm]);
      float2 f = __half22float2(Fh[li]);
      re[mm][SK(c)] = (f.x*b.x - f.y*b.y) * SCALE64K;
      im[mm][SK(c)] = (f.x*b.y + f.y*b.x) * SCALE64K;
    }
    __syncthreads();
    inv_block_fft(re, im, t);
    __half2* O = chunkbuf + (size_t)(gl*2 + p)*65536;
#pragma unroll
    for (int i = 0; i < 16; i++){
      const int li = t + i*256;        // li = mm*256 + c -> contiguous rows
      const int mm = li >> 8, c = li & 255;
      O[(size_t)(m16+mm)*256 + c] = __floats2half2_rn(re[mm][SK(c)], im[mm][SK(c)]);
    }
  }
}

// -- inverse comb stages (s=7..0, fused pairs): 16 c x 2 p, fused epilogue --
__global__ __launch_bounds__(256, 4)
void k_invA_w(const __half2* __restrict__ chunkbuf, const int gbase,
              const float* __restrict__ w_sm, const float* __restrict__ gains,
              float* __restrict__ out0){
  const int wg = blockIdx.x;
  const int c16 = wg & 15;
  const int gl = wg >> 4;
  const int g = gbase + gl;
  const int r = g & 31, be = g >> 5;
  const int c0 = c16*16;
  const int t = threadIdx.x;
  __shared__ __half2 zz[2][16][RP];
#pragma unroll
  for (int p = 0; p < 2; p++){
    const __half2* C = chunkbuf + (size_t)(gl*2 + p)*65536;
#pragma unroll
    for (int i = 0; i < 16; i++){
      const int li = t + i*256;        // li = m*16 + cc -> 64B clusters
      const int cc = li & 15, m = li >> 4;
      zz[p][cc][SK(m)] = C[(size_t)m*256 + c0 + cc];
    }
  }
  __syncthreads();
  for (int sp = 0; sp < 4; sp++){
    const int sA = 7 - 2*sp, sB = sA - 1;
    const int hA = 1 << (2*sp);        // 1,4,16,64
    const int lA = 2*sp;
#pragma unroll 1
    for (int it = 0; it < 8; it++){
      const int qq = t + it*256;       // 2048 quads: row(5) q(6)
      const int row = qq >> 6, q = qq & 63;
      const int p = row >> 4, cc = row & 15;
      const int j = q & (hA - 1), gq = q >> lA;
      const int base = gq*4*hA + j;
      __half2* Z = zz[p][cc];
      const int i0 = SK(base), i1 = SK(base+hA), i2 = SK(base+2*hA), i3 = SK(base+3*hA);
      float2 u0 = __half22float2(Z[i0]);
      float2 u1 = __half22float2(Z[i1]);
      float2 u2 = __half22float2(Z[i2]);
      float2 u3 = __half22float2(Z[i3]);
      const uint32_t cg = (uint32_t)(c0 + cc);
      float2 wA  = twid(((cg + 256u*(uint32_t)j) << sA) & 0xFFFFu, UNIT64K, +1.0f);
      float2 wB0 = twid(((cg + 256u*(uint32_t)j) << sB) & 0xFFFFu, UNIT64K, +1.0f);
      float2 wB1 = twid(((cg + 256u*(uint32_t)(j + hA)) << sB) & 0xFFFFu, UNIT64K, +1.0f);
      bfly_inv(u0, u1, wA);
      bfly_inv(u2, u3, wA);
      bfly_inv(u0, u2, wB0);
      bfly_inv(u1, u3, wB1);
      Z[i0] = __floats2half2_rn(u0.x, u0.y);
      Z[i1] = __floats2half2_rn(u1.x, u1.y);
      Z[i2] = __floats2half2_rn(u2.x, u2.y);
      Z[i3] = __floats2half2_rn(u3.x, u3.y);
    }
    __syncthreads();
  }
  const float gv = fabsf(gains[r]);
  const float* smb = w_sm + be*512;
#pragma unroll
  for (int it = 0; it < 8; it++){
    const int li = t + it*256;         // li = m*16 + cc, m < 128
    const int cc = li & 15, m = li >> 4;
    const int tt = c0 + cc + 256*m;
    int lo, hi; float w;
    interp128(tt, lo, hi, w);
    float2 z0 = __half22float2(zz[0][cc][SK(m)]);
    float2 z1 = __half22float2(zz[1][cc][SK(m)]);
    float dw0 = smb[0*128 + lo]*(1.0f - w) + smb[0*128 + hi]*w;
    float dw1 = smb[1*128 + lo]*(1.0f - w) + smb[1*128 + hi]*w;
    float dw2 = smb[2*128 + lo]*(1.0f - w) + smb[2*128 + hi]*w;
    float dw3 = smb[3*128 + lo]*(1.0f - w) + smb[3*128 + hi]*w;
    float val = dw0*z0.x + dw1*z0.y + dw2*z1.x + dw3*z1.y;  // scale pre-folded
    atomicAdd(&out0[(size_t)be*32768 + tt], tanhf(val*gv));
  }
}

extern "C" void kernel_launch(void* const* d_in, const int* in_sizes, int n_in,
                              void* d_out, int out_size, void* d_ws, size_t ws_size,
                              hipStream_t stream){
  const float* ctrl   = (const float*)d_in[0];
  const float* defm   = (const float*)d_in[1];
  const float* router = (const float*)d_in[2];
  const float* amp    = (const float*)d_in[3];
  const float* phase  = (const float*)d_in[4];
  const float* decay  = (const float*)d_in[5];
  const float* gains  = (const float*)d_in[6];
  float* out = (float*)d_out;
  float* ws  = (float*)d_ws;

  // ws layout (float offsets)
  float*   w_resT    = ws;                          // 4,194,304
  float*   w_routed  = ws + 4194304;                // 32,768
  float*   w_sm      = ws + 4227072;                // 4,096
  float*   w_invnorm = ws + 4231168;                // 128
  float*   w_sumsq   = ws + 4231296;                // 128
  __half2* ruspec_h  = (__half2*)(ws + 4231424);    // 256*65536 h2 = 16,777,216 f
  float2*  resp_f    = (float2*)(ws + 21008640);    // 64*65536 c   =  8,388,608 f
  __half2* resp_h    = (__half2*)(ws + 29397248);   // 64*65536 h2  =  4,194,304 f
  __half2* chunk_h   = (__half2*)(ws + 33591552);   // 2G*65536 h2  = G*131,072 f
  const size_t base_f = 33591552;
  // frames scratch aliases ruspec_h region (ruspec written later by fwdA)
  float2* w_fr       = (float2*)ruspec_h;           // 2048*2048 c = 8,388,608 f

  int G = 0;
  for (int gg = 128; gg >= 1; gg >>= 1){
    size_t need = (base_f + (size_t)gg*131072) * sizeof(float);
    if (need <= ws_size){ G = gg; break; }
  }

  hipMemsetAsync(d_out, 0, 262144*sizeof(float), stream);  // out0 (atomicAdd)
  k_routed<<<132, 256, 0, stream>>>(ctrl, defm, router, w_routed, w_sm, out + 262144);
  if (G == 0) return;  // diagnostic: out1 ok, out0 stays 0 => ws too small

  hipMemsetAsync(w_sumsq, 0, 128*sizeof(float), stream);
  k_frames<<<2048, 256, 0, stream>>>(amp, phase, decay, w_fr);
  k_ola<<<512, 256, 0, stream>>>(w_fr, w_resT, w_sumsq);
  k_norm<<<1, 128, 0, stream>>>(w_sumsq, w_invnorm);
  k_fwdA<<<64*128, 256, 0, stream>>>(0, w_resT, w_invnorm, w_routed, resp_f,
                                     (__half2*)nullptr);
  k_fwdB<<<64*16, 256, 0, stream>>>(resp_f, resp_h);
  k_fwdA<<<256*128, 256, 0, stream>>>(1, w_resT, w_invnorm, w_routed,
                                      (float2*)nullptr, ruspec_h);
  for (int gb = 0; gb < 256; gb += G){
    k_conv<<<G*16, 256, 0, stream>>>(ruspec_h, resp_h, chunk_h, gb);
    k_invA_w<<<G*16, 256, 0, stream>>>(chunk_h, gb, w_sm, gains, out);
  }
}

// Round 9
// 437.309 us; speedup vs baseline: 1.8440x; 1.0509x over previous
//
#include <hip/hip_runtime.h>
#include <hip/hip_fp16.h>
#include <stdint.h>

// ResonanceLayer: routed einsum -> resonance irfft (x-pair packed, frames to
// scratch) -> OLA+transpose+norm -> upsample*threefry-noise -> 65536-pt FFT
// convolution with complex-packed res spectra -> softmax-deformation mix ->
// tanh(gain*x) summed over resonators.
//
// Round-9: conv-side LDS FFTs switch to packed-half2 LDS cells (one 4B cell
// per complex sample; butterflies unpack->fp32->repack). Halves LDS ops and
// LDS bytes: k_conv 50.7->36.1KB => 4 blocks/CU (16 waves, was 12). Skew
// SK3(i)=i+3*(i>>4) caps stage conflicts at ~3-way (old i>>5 skew left 4-way
// at stride-64 sets = the measured 1.47e7 conflict cycles). Row pitch 308
// (== 4*odd mod 32) makes 16-row staging exactly 2-way (free).

#define PI_F     3.14159265358979323846f
#define TWOPI_F  6.28318530717958647692f
#define UNIT64K  (TWOPI_F/65536.0f)
#define UNIT2K   (TWOPI_F/2048.0f)
#define SCALE64K (1.0f/65536.0f)
#define SK3(i)   ((i) + 3*((i) >> 4))    // per-16 pad: <=3-way on all strides
#define RPH 308                          // row pitch (>=301, ==4*5 mod 32)

__device__ __forceinline__ float2 cmul(float2 a, float2 b){
  return make_float2(a.x*b.x - a.y*b.y, a.x*b.y + a.y*b.x);
}

__device__ __forceinline__ float2 twid(uint32_t e, float unit, float sign){
  float ang = (float)e * unit;
  float sn, cn;
  __sincosf(ang, &sn, &cn);
  return make_float2(cn, sign*sn);
}

// DIF butterfly: u' = u+v ; v' = (u-v)*w
__device__ __forceinline__ void bfly_fwd(float2& u, float2& v, float2 w){
  float2 d = make_float2(u.x - v.x, u.y - v.y);
  u = make_float2(u.x + v.x, u.y + v.y);
  v = cmul(d, w);
}
// DIT butterfly: t = v*w ; u' = u+t ; v' = u-t
__device__ __forceinline__ void bfly_inv(float2& u, float2& v, float2 w){
  float2 tv = cmul(v, w);
  v = make_float2(u.x - tv.x, u.y - tv.y);
  u = make_float2(u.x + tv.x, u.y + tv.y);
}

__device__ __forceinline__ uint32_t rotl32(uint32_t v, int r){
  return (v << r) | (v >> (32 - r));
}

// Threefry-2x32, key = (0, 123)
__device__ __forceinline__ void threefry2x32(uint32_t c0, uint32_t c1,
                                             uint32_t& o0, uint32_t& o1){
  const uint32_t k0 = 0u, k1 = 123u;
  const uint32_t k2 = 0x1BD11BDAu ^ k0 ^ k1;
  const uint32_t ks[3] = {k0, k1, k2};
  uint32_t x0 = c0 + k0, x1 = c1 + k1;
#pragma unroll
  for (int i = 0; i < 5; i++){
    if ((i & 1) == 0){
      x0 += x1; x1 = rotl32(x1,13); x1 ^= x0;
      x0 += x1; x1 = rotl32(x1,15); x1 ^= x0;
      x0 += x1; x1 = rotl32(x1,26); x1 ^= x0;
      x0 += x1; x1 = rotl32(x1, 6); x1 ^= x0;
    } else {
      x0 += x1; x1 = rotl32(x1,17); x1 ^= x0;
      x0 += x1; x1 = rotl32(x1,29); x1 ^= x0;
      x0 += x1; x1 = rotl32(x1,16); x1 ^= x0;
      x0 += x1; x1 = rotl32(x1,24); x1 ^= x0;
    }
    x0 += ks[(i+1)%3];
    x1 += ks[(i+2)%3] + (uint32_t)(i+1);
  }
  o0 = x0; o1 = x1;
}

__device__ __forceinline__ float jax_noise(uint32_t p){
  uint32_t b0, b1;
  threefry2x32(0u, p, b0, b1);
  uint32_t bits = b0 ^ b1;
  float u = __uint_as_float((bits >> 9) | 0x3f800000u) - 1.0f;
  return fmaxf(-1.0f, u*2.0f - 1.0f);
}

__device__ __forceinline__ void interp128(int t, int& lo, int& hi, float& w){
  float posf = ((float)t + 0.5f) * (1.0f/256.0f) - 0.5f;
  posf = fminf(fmaxf(posf, 0.0f), 127.0f);
  lo = (int)posf;
  hi = lo + 1; if (hi > 127) hi = 127;
  w = posf - (float)lo;
}

// ---- fused-pair forward block FFT (DIF, stages 8..15), half2 cells --------
__device__ __forceinline__ void fwd_block_fft(__half2 (*buf)[RPH], const int t){
  for (int sp = 0; sp < 4; sp++){
    const int s  = 8 + 2*sp;
    const int hl = 1 << (7 - 2*sp);    // 128,32,8,2
    const int hh = hl >> 1;            // 64,16,4,1
    const int lj = 6 - 2*sp;
#pragma unroll 1
    for (int it = 0; it < 4; it++){
      const int qq = t + it*256;
      const int row = qq >> 6, q = qq & 63;
      const int j = q & (hh - 1), g = q >> lj;
      const int base = g*2*hl + j;
      __half2* B = buf[row];
      const int i0 = SK3(base), i1 = SK3(base+hh), i2 = SK3(base+hl), i3 = SK3(base+hl+hh);
      float2 u0 = __half22float2(B[i0]);
      float2 u1 = __half22float2(B[i1]);
      float2 u2 = __half22float2(B[i2]);
      float2 u3 = __half22float2(B[i3]);
      float2 wA0 = twid((uint32_t)(j << s),        UNIT64K, -1.0f);
      float2 wA1 = twid((uint32_t)((j + hh) << s), UNIT64K, -1.0f);
      float2 wB  = twid((uint32_t)(j << (s + 1)),  UNIT64K, -1.0f);
      bfly_fwd(u0, u2, wA0);
      bfly_fwd(u1, u3, wA1);
      bfly_fwd(u0, u1, wB);
      bfly_fwd(u2, u3, wB);
      B[i0] = __floats2half2_rn(u0.x, u0.y);
      B[i1] = __floats2half2_rn(u1.x, u1.y);
      B[i2] = __floats2half2_rn(u2.x, u2.y);
      B[i3] = __floats2half2_rn(u3.x, u3.y);
    }
    __syncthreads();
  }
}

// ---- fused-pair inverse block FFT (DIT, stages 15..8), half2 cells --------
__device__ __forceinline__ void inv_block_fft(__half2 (*buf)[RPH], const int t){
  for (int sp = 0; sp < 4; sp++){
    const int sA = 15 - 2*sp, sB = sA - 1;
    const int hA = 1 << (2*sp);        // 1,4,16,64
    const int lA = 2*sp;
#pragma unroll 1
    for (int it = 0; it < 4; it++){
      const int qq = t + it*256;
      const int row = qq >> 6, q = qq & 63;
      const int j = q & (hA - 1), g = q >> lA;
      const int base = g*4*hA + j;
      __half2* B = buf[row];
      const int i0 = SK3(base), i1 = SK3(base+hA), i2 = SK3(base+2*hA), i3 = SK3(base+3*hA);
      float2 u0 = __half22float2(B[i0]);
      float2 u1 = __half22float2(B[i1]);
      float2 u2 = __half22float2(B[i2]);
      float2 u3 = __half22float2(B[i3]);
      float2 wA  = twid((uint32_t)(j << sA),        UNIT64K, +1.0f);
      float2 wB0 = twid((uint32_t)(j << sB),        UNIT64K, +1.0f);
      float2 wB1 = twid((uint32_t)((j + hA) << sB), UNIT64K, +1.0f);
      bfly_inv(u0, u1, wA);
      bfly_inv(u2, u3, wA);
      bfly_inv(u0, u2, wB0);
      bfly_inv(u1, u3, wB1);
      B[i0] = __floats2half2_rn(u0.x, u0.y);
      B[i1] = __floats2half2_rn(u1.x, u1.y);
      B[i2] = __floats2half2_rn(u2.x, u2.y);
      B[i3] = __floats2half2_rn(u3.x, u3.y);
    }
    __syncthreads();
  }
}

// ---------------- routed einsum + output1 + softmax(deformations) ----------
__global__ void k_routed(const float* __restrict__ ctrl, const float* __restrict__ defm,
                         const float* __restrict__ router,
                         float* __restrict__ w_routed, float* __restrict__ w_sm,
                         float* __restrict__ out1){
  int idx = blockIdx.x*blockDim.x + threadIdx.x;
  if (idx < 32768){
    int f = idx & 127, r = (idx >> 7) & 31, be = idx >> 12;
    float acc = 0.0f;
#pragma unroll
    for (int c = 0; c < 16; c++)
      acc += ctrl[(be*16 + c)*128 + f] * router[c*32 + r];
    w_routed[idx] = acc;
    out1[idx] = acc;
  } else if (idx < 32768 + 1024){
    int j = idx - 32768;
    int f = j & 127, be = j >> 7;
    float v[4];
#pragma unroll
    for (int x = 0; x < 4; x++)
      v[x] = defm[(be*4 + x)*128 + f] + (x == 0 ? 1.0f : 0.0f);
    float mx = fmaxf(fmaxf(v[0], v[1]), fmaxf(v[2], v[3]));
    float s = 0.0f;
#pragma unroll
    for (int x = 0; x < 4; x++){ v[x] = expf(v[x] - mx); s += v[x]; }
#pragma unroll
    for (int x = 0; x < 4; x++) w_sm[(be*4 + x)*128 + f] = v[x]/s;
  }
}

// ---- resonance frames: packed complex irfft(2048) of x-pairs + hann -------
__global__ void k_frames(const float* __restrict__ amp, const float* __restrict__ phase,
                         const float* __restrict__ decay, float2* __restrict__ w_fr){
  const int wg = blockIdx.x;          // (r,p,f)
  const int f = wg & 31;
  const int rp = wg >> 5;             // r*2 + p
  const int p = rp & 1;
  const int r = rp >> 1;
  const int t = threadIdx.x;
  __shared__ float2 buf[2048];

  for (int k = t; k <= 1024; k += 256){
    float2 S[2];
#pragma unroll
    for (int d = 0; d < 2; d++){
      const int x = 2*p + d;
      const int base = (r*1025 + k)*4 + x;
      float a  = fabsf(amp[base]);
      float ph = tanhf(phase[base]) * PI_F;
      float sg = 1.0f / (1.0f + expf(-decay[base]));
      float dc = 0.5f + 0.45f * sg;
      float mag = expf(logf(dc + 1e-12f) * (float)(f+1)) * a;
      float snv, csv;
      sincosf(ph, &snv, &csv);
      float re = mag * csv, im = mag * snv;
      if (k == 0 || k == 1024) im = 0.0f;
      S[d] = make_float2(re, im);
    }
    buf[__brev((uint32_t)k) >> 21] =
        make_float2(S[0].x - S[1].y, S[0].y + S[1].x);
    if (k >= 1 && k <= 1023)
      buf[__brev((uint32_t)(2048 - k)) >> 21] =
          make_float2(S[0].x + S[1].y, -S[0].y + S[1].x);
  }
  __syncthreads();
  for (int s = 10; s >= 0; s--){
    const int ls = 10 - s;
    const int hl = 1 << ls;
    for (int bi = t; bi < 1024; bi += 256){
      const int g = bi >> ls, j = bi & (hl - 1);
      const int i0 = g*2*hl + j, i1 = i0 + hl;
      float2 pp = buf[i0], qq = buf[i1];
      float2 w = twid((uint32_t)(j << s), UNIT2K, +1.0f);
      float2 v = cmul(qq, w);
      buf[i0] = make_float2(pp.x+v.x, pp.y+v.y);
      buf[i1] = make_float2(pp.x-v.x, pp.y-v.y);
    }
    __syncthreads();
  }
  float2* O = w_fr + (size_t)wg*2048;
  for (int u = t; u < 2048; u += 256){
    float hann = 0.5f - 0.5f*cosf(TWOPI_F * (float)u / 2048.0f);
    float sc = (1.0f/2048.0f) * hann;
    O[u] = make_float2(buf[u].x*sc, buf[u].y*sc);
  }
}

// ---- OLA + transpose + sum-of-squares ------------------------------------
__global__ void k_ola(const float2* __restrict__ w_fr, float* __restrict__ w_resT,
                      float* __restrict__ w_sumsq){
  const int wg = blockIdx.x;           // rp*8 + cq
  const int cq = wg & 7;
  const int rp = wg >> 3;
  const int c0 = cq*32;
  const int r = rp >> 1, p = rp & 1;
  const int ch0 = r*4 + p*2;
  const int t = threadIdx.x;
  __shared__ float tx[32][129], ty[32][129];
  __shared__ float red[2][256];
  const float2* F = w_fr + (size_t)rp*32*2048;
  float acc0 = 0.0f, acc1 = 0.0f;
#pragma unroll
  for (int it = 0; it < 16; it++){
    const int idx = it*256 + t;        // m*32 + c'  (time-ordered reads)
    const int cp = idx & 31, m = idx >> 5;
    const int n = c0 + cp + 256*m;
    const int f = n >> 10, u = n & 1023;
    float2 a = F[(size_t)f*2048 + u];
    float vx = a.x, vy = a.y;
    if (f > 0){
      float2 b = F[(size_t)(f-1)*2048 + u + 1024];
      vx += b.x; vy += b.y;
    }
    tx[cp][m] = vx; ty[cp][m] = vy;
    acc0 += vx*vx; acc1 += vy*vy;
  }
  red[0][t] = acc0; red[1][t] = acc1;
  __syncthreads();
#pragma unroll
  for (int it = 0; it < 16; it++){
    const int idx = it*256 + t;        // c'*128 + m  (contiguous writes)
    const int m = idx & 127, cp = idx >> 7;
    w_resT[(size_t)ch0*32768 + (size_t)(c0+cp)*128 + m]     = tx[cp][m];
    w_resT[(size_t)(ch0+1)*32768 + (size_t)(c0+cp)*128 + m] = ty[cp][m];
  }
  for (int off = 128; off > 0; off >>= 1){
    __syncthreads();
    if (t < off){ red[0][t] += red[0][t+off]; red[1][t] += red[1][t+off]; }
  }
  if (t == 0){
    atomicAdd(&w_sumsq[ch0],     red[0][0]);
    atomicAdd(&w_sumsq[ch0 + 1], red[1][0]);
  }
}

// ---------------- invnorm from sumsq (1 tiny block) ------------------------
__global__ void k_norm(const float* __restrict__ w_sumsq, float* __restrict__ w_invnorm){
  const int s = threadIdx.x;
  if (s < 128) w_invnorm[s] = 1.0f/(sqrtf(w_sumsq[s]) + 1e-8f);
}

// --------- forward comb stages (s=0..7): 256-pt DIF over m per comb --------
// mode 0 (sig=r*2+p <64): packed res pair -> outf (fp32)
// mode 1 (sig<256): ru real -> outh (fp16)
__global__ void k_fwdA(const int mode, const float* __restrict__ w_resT,
                       const float* __restrict__ w_invnorm,
                       const float* __restrict__ w_routed,
                       float2* __restrict__ outf, __half2* __restrict__ outh){
  const int wg = blockIdx.x;
  const int cpair = wg & 127;
  const int sig = wg >> 7;
  const int c0 = cpair*2;
  const int t = threadIdx.x;
  __shared__ float re[2][RPH], im[2][RPH];
#pragma unroll
  for (int i = 0; i < 2; i++){
    const int li = t + i*256;
    const int cc = li >> 8, m = li & 255;
    const int c = c0 + cc;
    float vx = 0.0f, vy = 0.0f;
    if (m < 128){                       // n = c + 256*m < 32768
      if (mode == 0){
        const int rr = sig >> 1, pq = sig & 1;
        const int ch0 = rr*4 + pq*2;
        vx = w_resT[(size_t)ch0*32768 + c*128 + m] * w_invnorm[ch0];
        vy = w_resT[(size_t)(ch0+1)*32768 + c*128 + m] * w_invnorm[ch0+1];
      } else {
        const int n = c + 256*m;
        int lo, hi; float w;
        interp128(n, lo, hi, w);
        const float* rp = w_routed + sig*128;
        float rv = rp[lo]*(1.0f - w) + rp[hi]*w;
        vx = rv * jax_noise((uint32_t)sig*32768u + (uint32_t)n);
      }
    }
    re[cc][SK3(m)] = vx; im[cc][SK3(m)] = vy;
  }
  __syncthreads();
  const int arr = t >> 7, b = t & 127;
  for (int s = 0; s < 8; s++){
    const int ls = 7 - s;
    const int hl = 1 << ls;
    const int g = b >> ls, j = b & (hl - 1);
    const int i0 = g*2*hl + j, i1 = i0 + hl;
    float2 u = make_float2(re[arr][SK3(i0)], im[arr][SK3(i0)]);
    float2 v = make_float2(re[arr][SK3(i1)], im[arr][SK3(i1)]);
    uint32_t e = (((uint32_t)(c0 + arr) + 256u*(uint32_t)j) << s) & 0xFFFFu;
    float2 w = twid(e, UNIT64K, -1.0f);
    re[arr][SK3(i0)] = u.x + v.x; im[arr][SK3(i0)] = u.y + v.y;
    float2 d = make_float2(u.x - v.x, u.y - v.y);
    float2 dv = cmul(d, w);
    re[arr][SK3(i1)] = dv.x; im[arr][SK3(i1)] = dv.y;
    __syncthreads();
  }
#pragma unroll
  for (int i = 0; i < 2; i++){
    const int li = t + i*256;
    const int cc = li >> 8, m = li & 255;
    const size_t idx = (size_t)sig*65536 + (size_t)(c0+cc)*256 + m;
    if (mode == 0)
      outf[idx] = make_float2(re[cc][SK3(m)], im[cc][SK3(m)]);
    else
      outh[idx] = __floats2half2_rn(re[cc][SK3(m)], im[cc][SK3(m)]);
  }
}

// ------- forward block stages (s=8..15) for res spectra: fp32 -> fp16 ------
__global__ void k_fwdB(const float2* __restrict__ specf, __half2* __restrict__ spech){
  const int wg = blockIdx.x;
  const int mq = wg & 15;
  const int sig = wg >> 4;
  const int m16 = mq*16;
  const int t = threadIdx.x;
  __shared__ __half2 buf[16][RPH];
  const float2* base = specf + (size_t)sig*65536;
#pragma unroll
  for (int i = 0; i < 16; i++){
    const int li = t + i*256;          // li = c*16 + mm
    const int mm = li & 15, c = li >> 4;
    float2 v = base[(size_t)c*256 + m16 + mm];
    buf[mm][SK3(c)] = __floats2half2_rn(v.x, v.y);
  }
  __syncthreads();
  fwd_block_fft(buf, t);
  __half2* outb = spech + (size_t)sig*65536;
#pragma unroll
  for (int i = 0; i < 16; i++){
    const int li = t + i*256;
    const int mm = li & 15, c = li >> 4;
    outb[(size_t)c*256 + m16 + mm] = buf[mm][SK3(c)];
  }
}

// ---- FUSED: ru fwd block stages + product(p=0,1)*scale + inv block stages --
__global__ __launch_bounds__(256, 4)
void k_conv(const __half2* __restrict__ ruspec,
            const __half2* __restrict__ respspec,
            __half2* __restrict__ chunkbuf, const int gbase){
  const int wg = blockIdx.x;
  const int mq = wg & 15;
  const int gl = wg >> 4;
  const int g = gbase + gl;
  const int r = g & 31;
  const int m16 = mq*16;
  const int t = threadIdx.x;
  __shared__ __half2 buf[16][RPH];
  __shared__ __half2 Fh[4096];
  const __half2* A = ruspec + (size_t)g*65536;
#pragma unroll
  for (int i = 0; i < 16; i++){
    const int li = t + i*256;          // li = c*16 + mm
    const int mm = li & 15, c = li >> 4;
    buf[mm][SK3(c)] = A[(size_t)c*256 + m16 + mm];
  }
  __syncthreads();
  fwd_block_fft(buf, t);
  // snapshot fwd spectrum (per-thread-owned cells, no sync needed)
#pragma unroll
  for (int i = 0; i < 16; i++){
    const int li = t + i*256;
    const int mm = li & 15, c = li >> 4;
    Fh[li] = buf[mm][SK3(c)];
  }
#pragma unroll 1
  for (int p = 0; p < 2; p++){
    __syncthreads();                   // protect work LDS vs prior reads
    const __half2* B = respspec + (size_t)(r*2 + p)*65536;
#pragma unroll
    for (int i = 0; i < 16; i++){
      const int li = t + i*256;
      const int mm = li & 15, c = li >> 4;
      float2 b = __half22float2(B[(size_t)c*256 + m16 + mm]);
      float2 f = __half22float2(Fh[li]);
      buf[mm][SK3(c)] = __floats2half2_rn((f.x*b.x - f.y*b.y) * SCALE64K,
                                          (f.x*b.y + f.y*b.x) * SCALE64K);
    }
    __syncthreads();
    inv_block_fft(buf, t);
    __half2* O = chunkbuf + (size_t)(gl*2 + p)*65536;
#pragma unroll
    for (int i = 0; i < 16; i++){
      const int li = t + i*256;        // li = mm*256 + c -> contiguous rows
      const int mm = li >> 8, c = li & 255;
      O[(size_t)(m16+mm)*256 + c] = buf[mm][SK3(c)];
    }
  }
}

// -- inverse comb stages (s=7..0, fused pairs): 16 c x 2 p, fused epilogue --
__global__ __launch_bounds__(256, 4)
void k_invA_w(const __half2* __restrict__ chunkbuf, const int gbase,
              const float* __restrict__ w_sm, const float* __restrict__ gains,
              float* __restrict__ out0){
  const int wg = blockIdx.x;
  const int c16 = wg & 15;
  const int gl = wg >> 4;
  const int g = gbase + gl;
  const int r = g & 31, be = g >> 5;
  const int c0 = c16*16;
  const int t = threadIdx.x;
  __shared__ __half2 zz[2][16][RPH];
#pragma unroll
  for (int p = 0; p < 2; p++){
    const __half2* C = chunkbuf + (size_t)(gl*2 + p)*65536;
#pragma unroll
    for (int i = 0; i < 16; i++){
      const int li = t + i*256;        // li = m*16 + cc -> 64B clusters
      const int cc = li & 15, m = li >> 4;
      zz[p][cc][SK3(m)] = C[(size_t)m*256 + c0 + cc];
    }
  }
  __syncthreads();
  for (int sp = 0; sp < 4; sp++){
    const int sA = 7 - 2*sp, sB = sA - 1;
    const int hA = 1 << (2*sp);        // 1,4,16,64
    const int lA = 2*sp;
#pragma unroll 1
    for (int it = 0; it < 8; it++){
      const int qq = t + it*256;       // 2048 quads: row(5) q(6)
      const int row = qq >> 6, q = qq & 63;
      const int p = row >> 4, cc = row & 15;
      const int j = q & (hA - 1), gq = q >> lA;
      const int base = gq*4*hA + j;
      __half2* Z = zz[p][cc];
      const int i0 = SK3(base), i1 = SK3(base+hA), i2 = SK3(base+2*hA), i3 = SK3(base+3*hA);
      float2 u0 = __half22float2(Z[i0]);
      float2 u1 = __half22float2(Z[i1]);
      float2 u2 = __half22float2(Z[i2]);
      float2 u3 = __half22float2(Z[i3]);
      const uint32_t cg = (uint32_t)(c0 + cc);
      float2 wA  = twid(((cg + 256u*(uint32_t)j) << sA) & 0xFFFFu, UNIT64K, +1.0f);
      float2 wB0 = twid(((cg + 256u*(uint32_t)j) << sB) & 0xFFFFu, UNIT64K, +1.0f);
      float2 wB1 = twid(((cg + 256u*(uint32_t)(j + hA)) << sB) & 0xFFFFu, UNIT64K, +1.0f);
      bfly_inv(u0, u1, wA);
      bfly_inv(u2, u3, wA);
      bfly_inv(u0, u2, wB0);
      bfly_inv(u1, u3, wB1);
      Z[i0] = __floats2half2_rn(u0.x, u0.y);
      Z[i1] = __floats2half2_rn(u1.x, u1.y);
      Z[i2] = __floats2half2_rn(u2.x, u2.y);
      Z[i3] = __floats2half2_rn(u3.x, u3.y);
    }
    __syncthreads();
  }
  const float gv = fabsf(gains[r]);
  const float* smb = w_sm + be*512;
#pragma unroll
  for (int it = 0; it < 8; it++){
    const int li = t + it*256;         // li = m*16 + cc, m < 128
    const int cc = li & 15, m = li >> 4;
    const int tt = c0 + cc + 256*m;
    int lo, hi; float w;
    interp128(tt, lo, hi, w);
    float2 z0 = __half22float2(zz[0][cc][SK3(m)]);
    float2 z1 = __half22float2(zz[1][cc][SK3(m)]);
    float dw0 = smb[0*128 + lo]*(1.0f - w) + smb[0*128 + hi]*w;
    float dw1 = smb[1*128 + lo]*(1.0f - w) + smb[1*128 + hi]*w;
    float dw2 = smb[2*128 + lo]*(1.0f - w) + smb[2*128 + hi]*w;
    float dw3 = smb[3*128 + lo]*(1.0f - w) + smb[3*128 + hi]*w;
    float val = dw0*z0.x + dw1*z0.y + dw2*z1.x + dw3*z1.y;  // scale pre-folded
    atomicAdd(&out0[(size_t)be*32768 + tt], tanhf(val*gv));
  }
}

extern "C" void kernel_launch(void* const* d_in, const int* in_sizes, int n_in,
                              void* d_out, int out_size, void* d_ws, size_t ws_size,
                              hipStream_t stream){
  const float* ctrl   = (const float*)d_in[0];
  const float* defm   = (const float*)d_in[1];
  const float* router = (const float*)d_in[2];
  const float* amp    = (const float*)d_in[3];
  const float* phase  = (const float*)d_in[4];
  const float* decay  = (const float*)d_in[5];
  const float* gains  = (const float*)d_in[6];
  float* out = (float*)d_out;
  float* ws  = (float*)d_ws;

  // ws layout (float offsets)
  float*   w_resT    = ws;                          // 4,194,304
  float*   w_routed  = ws + 4194304;                // 32,768
  float*   w_sm      = ws + 4227072;                // 4,096
  float*   w_invnorm = ws + 4231168;                // 128
  float*   w_sumsq   = ws + 4231296;                // 128
  __half2* ruspec_h  = (__half2*)(ws + 4231424);    // 256*65536 h2 = 16,777,216 f
  float2*  resp_f    = (float2*)(ws + 21008640);    // 64*65536 c   =  8,388,608 f
  __half2* resp_h    = (__half2*)(ws + 29397248);   // 64*65536 h2  =  4,194,304 f
  __half2* chunk_h   = (__half2*)(ws + 33591552);   // 2G*65536 h2  = G*131,072 f
  const size_t base_f = 33591552;
  // frames scratch aliases ruspec_h region (ruspec written later by fwdA)
  float2* w_fr       = (float2*)ruspec_h;           // 2048*2048 c = 8,388,608 f

  int G = 0;
  for (int gg = 128; gg >= 1; gg >>= 1){
    size_t need = (base_f + (size_t)gg*131072) * sizeof(float);
    if (need <= ws_size){ G = gg; break; }
  }

  hipMemsetAsync(d_out, 0, 262144*sizeof(float), stream);  // out0 (atomicAdd)
  k_routed<<<132, 256, 0, stream>>>(ctrl, defm, router, w_routed, w_sm, out + 262144);
  if (G == 0) return;  // diagnostic: out1 ok, out0 stays 0 => ws too small

  hipMemsetAsync(w_sumsq, 0, 128*sizeof(float), stream);
  k_frames<<<2048, 256, 0, stream>>>(amp, phase, decay, w_fr);
  k_ola<<<512, 256, 0, stream>>>(w_fr, w_resT, w_sumsq);
  k_norm<<<1, 128, 0, stream>>>(w_sumsq, w_invnorm);
  k_fwdA<<<64*128, 256, 0, stream>>>(0, w_resT, w_invnorm, w_routed, resp_f,
                                     (__half2*)nullptr);
  k_fwdB<<<64*16, 256, 0, stream>>>(resp_f, resp_h);
  k_fwdA<<<256*128, 256, 0, stream>>>(1, w_resT, w_invnorm, w_routed,
                                      (float2*)nullptr, ruspec_h);
  for (int gb = 0; gb < 256; gb += G){
    k_conv<<<G*16, 256, 0, stream>>>(ruspec_h, resp_h, chunk_h, gb);
    k_invA_w<<<G*16, 256, 0, stream>>>(chunk_h, gb, w_sm, gains, out);
  }
}

// Round 10
// 412.293 us; speedup vs baseline: 1.9559x; 1.0607x over previous
//
#include <hip/hip_runtime.h>
#include <hip/hip_fp16.h>
#include <stdint.h>

// ResonanceLayer: routed einsum -> resonance irfft (x-pair packed, frames to
// scratch) -> OLA+transpose+norm -> upsample*threefry-noise -> 65536-pt FFT
// convolution with complex-packed res spectra -> softmax-deformation mix ->
// tanh(gain*x) summed over resonators.
//
// Round-10: k_fwdA rebuilt like the round-9 conv kernels -- 4 combs/block,
// pair-fused quad stages (4 passes, one 4-pt quad per thread), packed-half2
// LDS cells with SK3 skew, and staging re-indexed (j=i*256+t -> cc=j&3,
// m=j>>2) so threefry runs on all 64 lanes (old layout idled t>=128 through
// the ~60-op noise gen). Mode-0 writes half2 directly; fwdB in-place.

#define PI_F     3.14159265358979323846f
#define TWOPI_F  6.28318530717958647692f
#define UNIT64K  (TWOPI_F/65536.0f)
#define UNIT2K   (TWOPI_F/2048.0f)
#define SCALE64K (1.0f/65536.0f)
#define SK3(i)   ((i) + 3*((i) >> 4))    // per-16 pad: <=3-way on all strides
#define RPH 308                          // row pitch (>=301, ==4*5 mod 32)

__device__ __forceinline__ float2 cmul(float2 a, float2 b){
  return make_float2(a.x*b.x - a.y*b.y, a.x*b.y + a.y*b.x);
}

__device__ __forceinline__ float2 twid(uint32_t e, float unit, float sign){
  float ang = (float)e * unit;
  float sn, cn;
  __sincosf(ang, &sn, &cn);
  return make_float2(cn, sign*sn);
}

// DIF butterfly: u' = u+v ; v' = (u-v)*w
__device__ __forceinline__ void bfly_fwd(float2& u, float2& v, float2 w){
  float2 d = make_float2(u.x - v.x, u.y - v.y);
  u = make_float2(u.x + v.x, u.y + v.y);
  v = cmul(d, w);
}
// DIT butterfly: t = v*w ; u' = u+t ; v' = u-t
__device__ __forceinline__ void bfly_inv(float2& u, float2& v, float2 w){
  float2 tv = cmul(v, w);
  v = make_float2(u.x - tv.x, u.y - tv.y);
  u = make_float2(u.x + tv.x, u.y + tv.y);
}

__device__ __forceinline__ uint32_t rotl32(uint32_t v, int r){
  return (v << r) | (v >> (32 - r));
}

// Threefry-2x32, key = (0, 123)
__device__ __forceinline__ void threefry2x32(uint32_t c0, uint32_t c1,
                                             uint32_t& o0, uint32_t& o1){
  const uint32_t k0 = 0u, k1 = 123u;
  const uint32_t k2 = 0x1BD11BDAu ^ k0 ^ k1;
  const uint32_t ks[3] = {k0, k1, k2};
  uint32_t x0 = c0 + k0, x1 = c1 + k1;
#pragma unroll
  for (int i = 0; i < 5; i++){
    if ((i & 1) == 0){
      x0 += x1; x1 = rotl32(x1,13); x1 ^= x0;
      x0 += x1; x1 = rotl32(x1,15); x1 ^= x0;
      x0 += x1; x1 = rotl32(x1,26); x1 ^= x0;
      x0 += x1; x1 = rotl32(x1, 6); x1 ^= x0;
    } else {
      x0 += x1; x1 = rotl32(x1,17); x1 ^= x0;
      x0 += x1; x1 = rotl32(x1,29); x1 ^= x0;
      x0 += x1; x1 = rotl32(x1,16); x1 ^= x0;
      x0 += x1; x1 = rotl32(x1,24); x1 ^= x0;
    }
    x0 += ks[(i+1)%3];
    x1 += ks[(i+2)%3] + (uint32_t)(i+1);
  }
  o0 = x0; o1 = x1;
}

__device__ __forceinline__ float jax_noise(uint32_t p){
  uint32_t b0, b1;
  threefry2x32(0u, p, b0, b1);
  uint32_t bits = b0 ^ b1;
  float u = __uint_as_float((bits >> 9) | 0x3f800000u) - 1.0f;
  return fmaxf(-1.0f, u*2.0f - 1.0f);
}

__device__ __forceinline__ void interp128(int t, int& lo, int& hi, float& w){
  float posf = ((float)t + 0.5f) * (1.0f/256.0f) - 0.5f;
  posf = fminf(fmaxf(posf, 0.0f), 127.0f);
  lo = (int)posf;
  hi = lo + 1; if (hi > 127) hi = 127;
  w = posf - (float)lo;
}

// ---- fused-pair forward block FFT (DIF, stages 8..15), half2 cells --------
__device__ __forceinline__ void fwd_block_fft(__half2 (*buf)[RPH], const int t){
  for (int sp = 0; sp < 4; sp++){
    const int s  = 8 + 2*sp;
    const int hl = 1 << (7 - 2*sp);    // 128,32,8,2
    const int hh = hl >> 1;            // 64,16,4,1
    const int lj = 6 - 2*sp;
#pragma unroll 1
    for (int it = 0; it < 4; it++){
      const int qq = t + it*256;
      const int row = qq >> 6, q = qq & 63;
      const int j = q & (hh - 1), g = q >> lj;
      const int base = g*2*hl + j;
      __half2* B = buf[row];
      const int i0 = SK3(base), i1 = SK3(base+hh), i2 = SK3(base+hl), i3 = SK3(base+hl+hh);
      float2 u0 = __half22float2(B[i0]);
      float2 u1 = __half22float2(B[i1]);
      float2 u2 = __half22float2(B[i2]);
      float2 u3 = __half22float2(B[i3]);
      float2 wA0 = twid((uint32_t)(j << s),        UNIT64K, -1.0f);
      float2 wA1 = twid((uint32_t)((j + hh) << s), UNIT64K, -1.0f);
      float2 wB  = twid((uint32_t)(j << (s + 1)),  UNIT64K, -1.0f);
      bfly_fwd(u0, u2, wA0);
      bfly_fwd(u1, u3, wA1);
      bfly_fwd(u0, u1, wB);
      bfly_fwd(u2, u3, wB);
      B[i0] = __floats2half2_rn(u0.x, u0.y);
      B[i1] = __floats2half2_rn(u1.x, u1.y);
      B[i2] = __floats2half2_rn(u2.x, u2.y);
      B[i3] = __floats2half2_rn(u3.x, u3.y);
    }
    __syncthreads();
  }
}

// ---- fused-pair inverse block FFT (DIT, stages 15..8), half2 cells --------
__device__ __forceinline__ void inv_block_fft(__half2 (*buf)[RPH], const int t){
  for (int sp = 0; sp < 4; sp++){
    const int sA = 15 - 2*sp, sB = sA - 1;
    const int hA = 1 << (2*sp);        // 1,4,16,64
    const int lA = 2*sp;
#pragma unroll 1
    for (int it = 0; it < 4; it++){
      const int qq = t + it*256;
      const int row = qq >> 6, q = qq & 63;
      const int j = q & (hA - 1), g = q >> lA;
      const int base = g*4*hA + j;
      __half2* B = buf[row];
      const int i0 = SK3(base), i1 = SK3(base+hA), i2 = SK3(base+2*hA), i3 = SK3(base+3*hA);
      float2 u0 = __half22float2(B[i0]);
      float2 u1 = __half22float2(B[i1]);
      float2 u2 = __half22float2(B[i2]);
      float2 u3 = __half22float2(B[i3]);
      float2 wA  = twid((uint32_t)(j << sA),        UNIT64K, +1.0f);
      float2 wB0 = twid((uint32_t)(j << sB),        UNIT64K, +1.0f);
      float2 wB1 = twid((uint32_t)((j + hA) << sB), UNIT64K, +1.0f);
      bfly_inv(u0, u1, wA);
      bfly_inv(u2, u3, wA);
      bfly_inv(u0, u2, wB0);
      bfly_inv(u1, u3, wB1);
      B[i0] = __floats2half2_rn(u0.x, u0.y);
      B[i1] = __floats2half2_rn(u1.x, u1.y);
      B[i2] = __floats2half2_rn(u2.x, u2.y);
      B[i3] = __floats2half2_rn(u3.x, u3.y);
    }
    __syncthreads();
  }
}

// ---------------- routed einsum + output1 + softmax(deformations) ----------
__global__ void k_routed(const float* __restrict__ ctrl, const float* __restrict__ defm,
                         const float* __restrict__ router,
                         float* __restrict__ w_routed, float* __restrict__ w_sm,
                         float* __restrict__ out1){
  int idx = blockIdx.x*blockDim.x + threadIdx.x;
  if (idx < 32768){
    int f = idx & 127, r = (idx >> 7) & 31, be = idx >> 12;
    float acc = 0.0f;
#pragma unroll
    for (int c = 0; c < 16; c++)
      acc += ctrl[(be*16 + c)*128 + f] * router[c*32 + r];
    w_routed[idx] = acc;
    out1[idx] = acc;
  } else if (idx < 32768 + 1024){
    int j = idx - 32768;
    int f = j & 127, be = j >> 7;
    float v[4];
#pragma unroll
    for (int x = 0; x < 4; x++)
      v[x] = defm[(be*4 + x)*128 + f] + (x == 0 ? 1.0f : 0.0f);
    float mx = fmaxf(fmaxf(v[0], v[1]), fmaxf(v[2], v[3]));
    float s = 0.0f;
#pragma unroll
    for (int x = 0; x < 4; x++){ v[x] = expf(v[x] - mx); s += v[x]; }
#pragma unroll
    for (int x = 0; x < 4; x++) w_sm[(be*4 + x)*128 + f] = v[x]/s;
  }
}

// ---- resonance frames: packed complex irfft(2048) of x-pairs + hann -------
__global__ void k_frames(const float* __restrict__ amp, const float* __restrict__ phase,
                         const float* __restrict__ decay, float2* __restrict__ w_fr){
  const int wg = blockIdx.x;          // (r,p,f)
  const int f = wg & 31;
  const int rp = wg >> 5;             // r*2 + p
  const int p = rp & 1;
  const int r = rp >> 1;
  const int t = threadIdx.x;
  __shared__ float2 buf[2048];

  for (int k = t; k <= 1024; k += 256){
    float2 S[2];
#pragma unroll
    for (int d = 0; d < 2; d++){
      const int x = 2*p + d;
      const int base = (r*1025 + k)*4 + x;
      float a  = fabsf(amp[base]);
      float ph = tanhf(phase[base]) * PI_F;
      float sg = 1.0f / (1.0f + expf(-decay[base]));
      float dc = 0.5f + 0.45f * sg;
      float mag = expf(logf(dc + 1e-12f) * (float)(f+1)) * a;
      float snv, csv;
      sincosf(ph, &snv, &csv);
      float re = mag * csv, im = mag * snv;
      if (k == 0 || k == 1024) im = 0.0f;
      S[d] = make_float2(re, im);
    }
    buf[__brev((uint32_t)k) >> 21] =
        make_float2(S[0].x - S[1].y, S[0].y + S[1].x);
    if (k >= 1 && k <= 1023)
      buf[__brev((uint32_t)(2048 - k)) >> 21] =
          make_float2(S[0].x + S[1].y, -S[0].y + S[1].x);
  }
  __syncthreads();
  for (int s = 10; s >= 0; s--){
    const int ls = 10 - s;
    const int hl = 1 << ls;
    for (int bi = t; bi < 1024; bi += 256){
      const int g = bi >> ls, j = bi & (hl - 1);
      const int i0 = g*2*hl + j, i1 = i0 + hl;
      float2 pp = buf[i0], qq = buf[i1];
      float2 w = twid((uint32_t)(j << s), UNIT2K, +1.0f);
      float2 v = cmul(qq, w);
      buf[i0] = make_float2(pp.x+v.x, pp.y+v.y);
      buf[i1] = make_float2(pp.x-v.x, pp.y-v.y);
    }
    __syncthreads();
  }
  float2* O = w_fr + (size_t)wg*2048;
  for (int u = t; u < 2048; u += 256){
    float hann = 0.5f - 0.5f*cosf(TWOPI_F * (float)u / 2048.0f);
    float sc = (1.0f/2048.0f) * hann;
    O[u] = make_float2(buf[u].x*sc, buf[u].y*sc);
  }
}

// ---- OLA + transpose + sum-of-squares ------------------------------------
__global__ void k_ola(const float2* __restrict__ w_fr, float* __restrict__ w_resT,
                      float* __restrict__ w_sumsq){
  const int wg = blockIdx.x;           // rp*8 + cq
  const int cq = wg & 7;
  const int rp = wg >> 3;
  const int c0 = cq*32;
  const int r = rp >> 1, p = rp & 1;
  const int ch0 = r*4 + p*2;
  const int t = threadIdx.x;
  __shared__ float tx[32][129], ty[32][129];
  __shared__ float red[2][256];
  const float2* F = w_fr + (size_t)rp*32*2048;
  float acc0 = 0.0f, acc1 = 0.0f;
#pragma unroll
  for (int it = 0; it < 16; it++){
    const int idx = it*256 + t;        // m*32 + c'  (time-ordered reads)
    const int cp = idx & 31, m = idx >> 5;
    const int n = c0 + cp + 256*m;
    const int f = n >> 10, u = n & 1023;
    float2 a = F[(size_t)f*2048 + u];
    float vx = a.x, vy = a.y;
    if (f > 0){
      float2 b = F[(size_t)(f-1)*2048 + u + 1024];
      vx += b.x; vy += b.y;
    }
    tx[cp][m] = vx; ty[cp][m] = vy;
    acc0 += vx*vx; acc1 += vy*vy;
  }
  red[0][t] = acc0; red[1][t] = acc1;
  __syncthreads();
#pragma unroll
  for (int it = 0; it < 16; it++){
    const int idx = it*256 + t;        // c'*128 + m  (contiguous writes)
    const int m = idx & 127, cp = idx >> 7;
    w_resT[(size_t)ch0*32768 + (size_t)(c0+cp)*128 + m]     = tx[cp][m];
    w_resT[(size_t)(ch0+1)*32768 + (size_t)(c0+cp)*128 + m] = ty[cp][m];
  }
  for (int off = 128; off > 0; off >>= 1){
    __syncthreads();
    if (t < off){ red[0][t] += red[0][t+off]; red[1][t] += red[1][t+off]; }
  }
  if (t == 0){
    atomicAdd(&w_sumsq[ch0],     red[0][0]);
    atomicAdd(&w_sumsq[ch0 + 1], red[1][0]);
  }
}

// ---------------- invnorm from sumsq (1 tiny block) ------------------------
__global__ void k_norm(const float* __restrict__ w_sumsq, float* __restrict__ w_invnorm){
  const int s = threadIdx.x;
  if (s < 128) w_invnorm[s] = 1.0f/(sqrtf(w_sumsq[s]) + 1e-8f);
}

// --------- forward comb stages (s=0..7): 256-pt DIF over m, 4 combs/block --
// mode 0 (sig=r*2+p <64): packed res pair; mode 1 (sig<256): ru real+noise.
// Quad stages (pair-fused), half2 LDS. output c-major: outh[sig][c*256+m].
__global__ void k_fwdA(const int mode, const float* __restrict__ w_resT,
                       const float* __restrict__ w_invnorm,
                       const float* __restrict__ w_routed,
                       __half2* __restrict__ outh){
  const int wg = blockIdx.x;
  const int cq = wg & 63;
  const int sig = wg >> 6;
  const int c0 = cq*4;
  const int t = threadIdx.x;
  __shared__ __half2 buf[4][RPH];
  // staging: nonzero half m<128 spread over all lanes (2 per thread)
  if (mode == 0){
    const int rr = sig >> 1, pq = sig & 1;
    const int ch0 = rr*4 + pq*2;
    const float inv0 = w_invnorm[ch0], inv1 = w_invnorm[ch0+1];
#pragma unroll
    for (int i = 0; i < 2; i++){
      const int j = i*256 + t;
      const int cc = j & 3, m = j >> 2;        // m in [0,128)
      const int c = c0 + cc;
      float vx = w_resT[(size_t)ch0*32768 + c*128 + m] * inv0;
      float vy = w_resT[(size_t)(ch0+1)*32768 + c*128 + m] * inv1;
      buf[cc][SK3(m)] = __floats2half2_rn(vx, vy);
      buf[cc][SK3(m + 128)] = __floats2half2_rn(0.0f, 0.0f);
    }
  } else {
    const float* rp = w_routed + sig*128;
#pragma unroll
    for (int i = 0; i < 2; i++){
      const int j = i*256 + t;
      const int cc = j & 3, m = j >> 2;        // m in [0,128)
      const int c = c0 + cc;
      const int n = c + 256*m;
      int lo, hi; float w;
      interp128(n, lo, hi, w);
      float rv = rp[lo]*(1.0f - w) + rp[hi]*w;
      float vx = rv * jax_noise((uint32_t)sig*32768u + (uint32_t)n);
      buf[cc][SK3(m)] = __floats2half2_rn(vx, 0.0f);
      buf[cc][SK3(m + 128)] = __floats2half2_rn(0.0f, 0.0f);
    }
  }
  __syncthreads();
  // pair-fused comb stages: sp covers (s, s+1) = (2sp, 2sp+1)
  for (int sp = 0; sp < 4; sp++){
    const int s  = 2*sp;
    const int hh = 1 << (6 - 2*sp);    // 64,16,4,1
    const int hl = hh << 1;            // 128,32,8,2
    const int lj = 6 - 2*sp;
    const int row = t >> 6, q = t & 63;      // 256 quads, one per thread
    const int j = q & (hh - 1), g = q >> lj;
    const int base = g*2*hl + j;
    const uint32_t c = (uint32_t)(c0 + row);
    __half2* B = buf[row];
    const int i0 = SK3(base), i1 = SK3(base+hh), i2 = SK3(base+hl), i3 = SK3(base+hl+hh);
    float2 u0 = __half22float2(B[i0]);
    float2 u1 = __half22float2(B[i1]);
    float2 u2 = __half22float2(B[i2]);
    float2 u3 = __half22float2(B[i3]);
    float2 wA0 = twid(((c + 256u*(uint32_t)j) << s) & 0xFFFFu,        UNIT64K, -1.0f);
    float2 wA1 = twid(((c + 256u*(uint32_t)(j + hh)) << s) & 0xFFFFu, UNIT64K, -1.0f);
    float2 wB  = twid(((c + 256u*(uint32_t)j) << (s + 1)) & 0xFFFFu,  UNIT64K, -1.0f);
    bfly_fwd(u0, u2, wA0);
    bfly_fwd(u1, u3, wA1);
    bfly_fwd(u0, u1, wB);
    bfly_fwd(u2, u3, wB);
    B[i0] = __floats2half2_rn(u0.x, u0.y);
    B[i1] = __floats2half2_rn(u1.x, u1.y);
    B[i2] = __floats2half2_rn(u2.x, u2.y);
    B[i3] = __floats2half2_rn(u3.x, u3.y);
    __syncthreads();
  }
#pragma unroll
  for (int i = 0; i < 4; i++){
    const int cc = i, m = t;                  // contiguous 256B runs per row
    outh[(size_t)sig*65536 + (size_t)(c0+cc)*256 + m] = buf[cc][SK3(m)];
  }
}

// ------- forward block stages (s=8..15) for res spectra: in-place half2 ----
__global__ void k_fwdB(__half2* __restrict__ spech){
  const int wg = blockIdx.x;
  const int mq = wg & 15;
  const int sig = wg >> 4;
  const int m16 = mq*16;
  const int t = threadIdx.x;
  __shared__ __half2 buf[16][RPH];
  __half2* base = spech + (size_t)sig*65536;
#pragma unroll
  for (int i = 0; i < 16; i++){
    const int li = t + i*256;          // li = c*16 + mm
    const int mm = li & 15, c = li >> 4;
    buf[mm][SK3(c)] = base[(size_t)c*256 + m16 + mm];
  }
  __syncthreads();
  fwd_block_fft(buf, t);
#pragma unroll
  for (int i = 0; i < 16; i++){
    const int li = t + i*256;
    const int mm = li & 15, c = li >> 4;
    base[(size_t)c*256 + m16 + mm] = buf[mm][SK3(c)];
  }
}

// ---- FUSED: ru fwd block stages + product(p=0,1)*scale + inv block stages --
__global__ __launch_bounds__(256, 4)
void k_conv(const __half2* __restrict__ ruspec,
            const __half2* __restrict__ respspec,
            __half2* __restrict__ chunkbuf, const int gbase){
  const int wg = blockIdx.x;
  const int mq = wg & 15;
  const int gl = wg >> 4;
  const int g = gbase + gl;
  const int r = g & 31;
  const int m16 = mq*16;
  const int t = threadIdx.x;
  __shared__ __half2 buf[16][RPH];
  __shared__ __half2 Fh[4096];
  const __half2* A = ruspec + (size_t)g*65536;
#pragma unroll
  for (int i = 0; i < 16; i++){
    const int li = t + i*256;          // li = c*16 + mm
    const int mm = li & 15, c = li >> 4;
    buf[mm][SK3(c)] = A[(size_t)c*256 + m16 + mm];
  }
  __syncthreads();
  fwd_block_fft(buf, t);
  // snapshot fwd spectrum (per-thread-owned cells, no sync needed)
#pragma unroll
  for (int i = 0; i < 16; i++){
    const int li = t + i*256;
    const int mm = li & 15, c = li >> 4;
    Fh[li] = buf[mm][SK3(c)];
  }
#pragma unroll 1
  for (int p = 0; p < 2; p++){
    __syncthreads();                   // protect work LDS vs prior reads
    const __half2* B = respspec + (size_t)(r*2 + p)*65536;
#pragma unroll
    for (int i = 0; i < 16; i++){
      const int li = t + i*256;
      const int mm = li & 15, c = li >> 4;
      float2 b = __half22float2(B[(size_t)c*256 + m16 + mm]);
      float2 f = __half22float2(Fh[li]);
      buf[mm][SK3(c)] = __floats2half2_rn((f.x*b.x - f.y*b.y) * SCALE64K,
                                          (f.x*b.y + f.y*b.x) * SCALE64K);
    }
    __syncthreads();
    inv_block_fft(buf, t);
    __half2* O = chunkbuf + (size_t)(gl*2 + p)*65536;
#pragma unroll
    for (int i = 0; i < 16; i++){
      const int li = t + i*256;        // li = mm*256 + c -> contiguous rows
      const int mm = li >> 8, c = li & 255;
      O[(size_t)(m16+mm)*256 + c] = buf[mm][SK3(c)];
    }
  }
}

// -- inverse comb stages (s=7..0, fused pairs): 16 c x 2 p, fused epilogue --
__global__ __launch_bounds__(256, 4)
void k_invA_w(const __half2* __restrict__ chunkbuf, const int gbase,
              const float* __restrict__ w_sm, const float* __restrict__ gains,
              float* __restrict__ out0){
  const int wg = blockIdx.x;
  const int c16 = wg & 15;
  const int gl = wg >> 4;
  const int g = gbase + gl;
  const int r = g & 31, be = g >> 5;
  const int c0 = c16*16;
  const int t = threadIdx.x;
  __shared__ __half2 zz[2][16][RPH];
#pragma unroll
  for (int p = 0; p < 2; p++){
    const __half2* C = chunkbuf + (size_t)(gl*2 + p)*65536;
#pragma unroll
    for (int i = 0; i < 16; i++){
      const int li = t + i*256;        // li = m*16 + cc -> 64B clusters
      const int cc = li & 15, m = li >> 4;
      zz[p][cc][SK3(m)] = C[(size_t)m*256 + c0 + cc];
    }
  }
  __syncthreads();
  for (int sp = 0; sp < 4; sp++){
    const int sA = 7 - 2*sp, sB = sA - 1;
    const int hA = 1 << (2*sp);        // 1,4,16,64
    const int lA = 2*sp;
#pragma unroll 1
    for (int it = 0; it < 8; it++){
      const int qq = t + it*256;       // 2048 quads: row(5) q(6)
      const int row = qq >> 6, q = qq & 63;
      const int p = row >> 4, cc = row & 15;
      const int j = q & (hA - 1), gq = q >> lA;
      const int base = gq*4*hA + j;
      __half2* Z = zz[p][cc];
      const int i0 = SK3(base), i1 = SK3(base+hA), i2 = SK3(base+2*hA), i3 = SK3(base+3*hA);
      float2 u0 = __half22float2(Z[i0]);
      float2 u1 = __half22float2(Z[i1]);
      float2 u2 = __half22float2(Z[i2]);
      float2 u3 = __half22float2(Z[i3]);
      const uint32_t cg = (uint32_t)(c0 + cc);
      float2 wA  = twid(((cg + 256u*(uint32_t)j) << sA) & 0xFFFFu, UNIT64K, +1.0f);
      float2 wB0 = twid(((cg + 256u*(uint32_t)j) << sB) & 0xFFFFu, UNIT64K, +1.0f);
      float2 wB1 = twid(((cg + 256u*(uint32_t)(j + hA)) << sB) & 0xFFFFu, UNIT64K, +1.0f);
      bfly_inv(u0, u1, wA);
      bfly_inv(u2, u3, wA);
      bfly_inv(u0, u2, wB0);
      bfly_inv(u1, u3, wB1);
      Z[i0] = __floats2half2_rn(u0.x, u0.y);
      Z[i1] = __floats2half2_rn(u1.x, u1.y);
      Z[i2] = __floats2half2_rn(u2.x, u2.y);
      Z[i3] = __floats2half2_rn(u3.x, u3.y);
    }
    __syncthreads();
  }
  const float gv = fabsf(gains[r]);
  const float* smb = w_sm + be*512;
#pragma unroll
  for (int it = 0; it < 8; it++){
    const int li = t + it*256;         // li = m*16 + cc, m < 128
    const int cc = li & 15, m = li >> 4;
    const int tt = c0 + cc + 256*m;
    int lo, hi; float w;
    interp128(tt, lo, hi, w);
    float2 z0 = __half22float2(zz[0][cc][SK3(m)]);
    float2 z1 = __half22float2(zz[1][cc][SK3(m)]);
    float dw0 = smb[0*128 + lo]*(1.0f - w) + smb[0*128 + hi]*w;
    float dw1 = smb[1*128 + lo]*(1.0f - w) + smb[1*128 + hi]*w;
    float dw2 = smb[2*128 + lo]*(1.0f - w) + smb[2*128 + hi]*w;
    float dw3 = smb[3*128 + lo]*(1.0f - w) + smb[3*128 + hi]*w;
    float val = dw0*z0.x + dw1*z0.y + dw2*z1.x + dw3*z1.y;  // scale pre-folded
    atomicAdd(&out0[(size_t)be*32768 + tt], tanhf(val*gv));
  }
}

extern "C" void kernel_launch(void* const* d_in, const int* in_sizes, int n_in,
                              void* d_out, int out_size, void* d_ws, size_t ws_size,
                              hipStream_t stream){
  const float* ctrl   = (const float*)d_in[0];
  const float* defm   = (const float*)d_in[1];
  const float* router = (const float*)d_in[2];
  const float* amp    = (const float*)d_in[3];
  const float* phase  = (const float*)d_in[4];
  const float* decay  = (const float*)d_in[5];
  const float* gains  = (const float*)d_in[6];
  float* out = (float*)d_out;
  float* ws  = (float*)d_ws;

  // ws layout (float offsets)
  float*   w_resT    = ws;                          // 4,194,304
  float*   w_routed  = ws + 4194304;                // 32,768
  float*   w_sm      = ws + 4227072;                // 4,096
  float*   w_invnorm = ws + 4231168;                // 128
  float*   w_sumsq   = ws + 4231296;                // 128
  __half2* ruspec_h  = (__half2*)(ws + 4231424);    // 256*65536 h2 = 16,777,216 f
  __half2* resp_h    = (__half2*)(ws + 21008640);   // 64*65536 h2  =  4,194,304 f
  __half2* chunk_h   = (__half2*)(ws + 25202944);   // 2G*65536 h2  = G*131,072 f
  const size_t base_f = 25202944;
  // frames scratch aliases ruspec_h region (ruspec written later by fwdA)
  float2* w_fr       = (float2*)ruspec_h;           // 2048*2048 c = 8,388,608 f

  int G = 0;
  for (int gg = 128; gg >= 1; gg >>= 1){
    size_t need = (base_f + (size_t)gg*131072) * sizeof(float);
    if (need <= ws_size){ G = gg; break; }
  }

  hipMemsetAsync(d_out, 0, 262144*sizeof(float), stream);  // out0 (atomicAdd)
  k_routed<<<132, 256, 0, stream>>>(ctrl, defm, router, w_routed, w_sm, out + 262144);
  if (G == 0) return;  // diagnostic: out1 ok, out0 stays 0 => ws too small

  hipMemsetAsync(w_sumsq, 0, 128*sizeof(float), stream);
  k_frames<<<2048, 256, 0, stream>>>(amp, phase, decay, w_fr);
  k_ola<<<512, 256, 0, stream>>>(w_fr, w_resT, w_sumsq);
  k_norm<<<1, 128, 0, stream>>>(w_sumsq, w_invnorm);
  k_fwdA<<<64*64, 256, 0, stream>>>(0, w_resT, w_invnorm, w_routed, resp_h);
  k_fwdB<<<64*16, 256, 0, stream>>>(resp_h);
  k_fwdA<<<256*64, 256, 0, stream>>>(1, w_resT, w_invnorm, w_routed, ruspec_h);
  for (int gb = 0; gb < 256; gb += G){
    k_conv<<<G*16, 256, 0, stream>>>(ruspec_h, resp_h, chunk_h, gb);
    k_invA_w<<<G*16, 256, 0, stream>>>(chunk_h, gb, w_sm, gains, out);
  }
}

// Round 11
// 398.932 us; speedup vs baseline: 2.0214x; 1.0335x over previous
//
#include <hip/hip_runtime.h>
#include <hip/hip_fp16.h>
#include <stdint.h>

// ResonanceLayer: routed einsum -> resonance irfft (x-pair packed, frames to
// scratch) -> OLA+transpose+norm -> upsample*threefry-noise -> 65536-pt FFT
// convolution with complex-packed res spectra -> softmax-deformation mix ->
// tanh(gain*x) summed over resonators.
//
// Round-11: twiddle algebra + invariant hoisting. In every pair-fused pass
// the 3 twiddles obey exact identities: wA1 = w(arg+2^14) = (-/+)i*wA0 (quarter
// turn = swap/negate) and wB = w(2*arg) = wA0^2 (one cmul). One sincos per
// quad instead of three. In fwd/inv_block_fft, q = (t+it*256)&63 = t&63 is
// it-invariant -> j/g/addresses/twiddles hoisted out of the quad loop
// explicitly (only `row` varies). k_conv was 65% VALUBusy at 32% HBM.

#define PI_F     3.14159265358979323846f
#define TWOPI_F  6.28318530717958647692f
#define UNIT64K  (TWOPI_F/65536.0f)
#define UNIT2K   (TWOPI_F/2048.0f)
#define SCALE64K (1.0f/65536.0f)
#define SK3(i)   ((i) + 3*((i) >> 4))    // per-16 pad: <=3-way on all strides
#define RPH 308                          // row pitch (>=301, ==4*5 mod 32)

__device__ __forceinline__ float2 cmul(float2 a, float2 b){
  return make_float2(a.x*b.x - a.y*b.y, a.x*b.y + a.y*b.x);
}

__device__ __forceinline__ float2 twid(uint32_t e, float unit, float sign){
  float ang = (float)e * unit;
  float sn, cn;
  __sincosf(ang, &sn, &cn);
  return make_float2(cn, sign*sn);
}

// quarter-turn helpers: mulnegi(w) = -i*w ; mulposi(w) = +i*w  (exact)
__device__ __forceinline__ float2 mulnegi(float2 w){ return make_float2(w.y, -w.x); }
__device__ __forceinline__ float2 mulposi(float2 w){ return make_float2(-w.y, w.x); }

// DIF butterfly: u' = u+v ; v' = (u-v)*w
__device__ __forceinline__ void bfly_fwd(float2& u, float2& v, float2 w){
  float2 d = make_float2(u.x - v.x, u.y - v.y);
  u = make_float2(u.x + v.x, u.y + v.y);
  v = cmul(d, w);
}
// DIT butterfly: t = v*w ; u' = u+t ; v' = u-t
__device__ __forceinline__ void bfly_inv(float2& u, float2& v, float2 w){
  float2 tv = cmul(v, w);
  v = make_float2(u.x - tv.x, u.y - tv.y);
  u = make_float2(u.x + tv.x, u.y + tv.y);
}

__device__ __forceinline__ uint32_t rotl32(uint32_t v, int r){
  return (v << r) | (v >> (32 - r));
}

// Threefry-2x32, key = (0, 123)
__device__ __forceinline__ void threefry2x32(uint32_t c0, uint32_t c1,
                                             uint32_t& o0, uint32_t& o1){
  const uint32_t k0 = 0u, k1 = 123u;
  const uint32_t k2 = 0x1BD11BDAu ^ k0 ^ k1;
  const uint32_t ks[3] = {k0, k1, k2};
  uint32_t x0 = c0 + k0, x1 = c1 + k1;
#pragma unroll
  for (int i = 0; i < 5; i++){
    if ((i & 1) == 0){
      x0 += x1; x1 = rotl32(x1,13); x1 ^= x0;
      x0 += x1; x1 = rotl32(x1,15); x1 ^= x0;
      x0 += x1; x1 = rotl32(x1,26); x1 ^= x0;
      x0 += x1; x1 = rotl32(x1, 6); x1 ^= x0;
    } else {
      x0 += x1; x1 = rotl32(x1,17); x1 ^= x0;
      x0 += x1; x1 = rotl32(x1,29); x1 ^= x0;
      x0 += x1; x1 = rotl32(x1,16); x1 ^= x0;
      x0 += x1; x1 = rotl32(x1,24); x1 ^= x0;
    }
    x0 += ks[(i+1)%3];
    x1 += ks[(i+2)%3] + (uint32_t)(i+1);
  }
  o0 = x0; o1 = x1;
}

__device__ __forceinline__ float jax_noise(uint32_t p){
  uint32_t b0, b1;
  threefry2x32(0u, p, b0, b1);
  uint32_t bits = b0 ^ b1;
  float u = __uint_as_float((bits >> 9) | 0x3f800000u) - 1.0f;
  return fmaxf(-1.0f, u*2.0f - 1.0f);
}

__device__ __forceinline__ void interp128(int t, int& lo, int& hi, float& w){
  float posf = ((float)t + 0.5f) * (1.0f/256.0f) - 0.5f;
  posf = fminf(fmaxf(posf, 0.0f), 127.0f);
  lo = (int)posf;
  hi = lo + 1; if (hi > 127) hi = 127;
  w = posf - (float)lo;
}

// ---- fused-pair forward block FFT (DIF, stages 8..15), half2 cells --------
// one sincos per pass (wA1 = -i*wA0, wB = wA0^2); addresses it-invariant
__device__ __forceinline__ void fwd_block_fft(__half2 (*buf)[RPH], const int t){
  const int q = t & 63;
  const int row0 = t >> 6;
  for (int sp = 0; sp < 4; sp++){
    const int s  = 8 + 2*sp;
    const int hl = 1 << (7 - 2*sp);    // 128,32,8,2
    const int hh = hl >> 1;            // 64,16,4,1
    const int lj = 6 - 2*sp;
    const int j = q & (hh - 1), g = q >> lj;
    const int base = g*2*hl + j;
    const int i0 = SK3(base), i1 = SK3(base+hh), i2 = SK3(base+hl), i3 = SK3(base+hl+hh);
    const float2 wA0 = twid((uint32_t)(j << s), UNIT64K, -1.0f);
    const float2 wA1 = mulnegi(wA0);          // w((j+hh)<<s) = w(arg+2^14)
    const float2 wB  = cmul(wA0, wA0);        // w(j<<(s+1))  = w(2*arg)
#pragma unroll 1
    for (int it = 0; it < 4; it++){
      __half2* B = buf[row0 + it*4];
      float2 u0 = __half22float2(B[i0]);
      float2 u1 = __half22float2(B[i1]);
      float2 u2 = __half22float2(B[i2]);
      float2 u3 = __half22float2(B[i3]);
      bfly_fwd(u0, u2, wA0);
      bfly_fwd(u1, u3, wA1);
      bfly_fwd(u0, u1, wB);
      bfly_fwd(u2, u3, wB);
      B[i0] = __floats2half2_rn(u0.x, u0.y);
      B[i1] = __floats2half2_rn(u1.x, u1.y);
      B[i2] = __floats2half2_rn(u2.x, u2.y);
      B[i3] = __floats2half2_rn(u3.x, u3.y);
    }
    __syncthreads();
  }
}

// ---- fused-pair inverse block FFT (DIT, stages 15..8), half2 cells --------
// one sincos per pass (wA = wB0^2, wB1 = +i*wB0); addresses it-invariant
__device__ __forceinline__ void inv_block_fft(__half2 (*buf)[RPH], const int t){
  const int q = t & 63;
  const int row0 = t >> 6;
  for (int sp = 0; sp < 4; sp++){
    const int sB = 14 - 2*sp;
    const int hA = 1 << (2*sp);        // 1,4,16,64
    const int lA = 2*sp;
    const int j = q & (hA - 1), g = q >> lA;
    const int base = g*4*hA + j;
    const int i0 = SK3(base), i1 = SK3(base+hA), i2 = SK3(base+2*hA), i3 = SK3(base+3*hA);
    const float2 wB0 = twid((uint32_t)(j << sB), UNIT64K, +1.0f);
    const float2 wA  = cmul(wB0, wB0);        // w(j<<sA) = w(2*argB)
    const float2 wB1 = mulposi(wB0);          // w((j+hA)<<sB) = w(argB+2^14)
#pragma unroll 1
    for (int it = 0; it < 4; it++){
      __half2* B = buf[row0 + it*4];
      float2 u0 = __half22float2(B[i0]);
      float2 u1 = __half22float2(B[i1]);
      float2 u2 = __half22float2(B[i2]);
      float2 u3 = __half22float2(B[i3]);
      bfly_inv(u0, u1, wA);
      bfly_inv(u2, u3, wA);
      bfly_inv(u0, u2, wB0);
      bfly_inv(u1, u3, wB1);
      B[i0] = __floats2half2_rn(u0.x, u0.y);
      B[i1] = __floats2half2_rn(u1.x, u1.y);
      B[i2] = __floats2half2_rn(u2.x, u2.y);
      B[i3] = __floats2half2_rn(u3.x, u3.y);
    }
    __syncthreads();
  }
}

// ---------------- routed einsum + output1 + softmax(deformations) ----------
__global__ void k_routed(const float* __restrict__ ctrl, const float* __restrict__ defm,
                         const float* __restrict__ router,
                         float* __restrict__ w_routed, float* __restrict__ w_sm,
                         float* __restrict__ out1){
  int idx = blockIdx.x*blockDim.x + threadIdx.x;
  if (idx < 32768){
    int f = idx & 127, r = (idx >> 7) & 31, be = idx >> 12;
    float acc = 0.0f;
#pragma unroll
    for (int c = 0; c < 16; c++)
      acc += ctrl[(be*16 + c)*128 + f] * router[c*32 + r];
    w_routed[idx] = acc;
    out1[idx] = acc;
  } else if (idx < 32768 + 1024){
    int j = idx - 32768;
    int f = j & 127, be = j >> 7;
    float v[4];
#pragma unroll
    for (int x = 0; x < 4; x++)
      v[x] = defm[(be*4 + x)*128 + f] + (x == 0 ? 1.0f : 0.0f);
    float mx = fmaxf(fmaxf(v[0], v[1]), fmaxf(v[2], v[3]));
    float s = 0.0f;
#pragma unroll
    for (int x = 0; x < 4; x++){ v[x] = expf(v[x] - mx); s += v[x]; }
#pragma unroll
    for (int x = 0; x < 4; x++) w_sm[(be*4 + x)*128 + f] = v[x]/s;
  }
}

// ---- resonance frames: packed complex irfft(2048) of x-pairs + hann -------
__global__ void k_frames(const float* __restrict__ amp, const float* __restrict__ phase,
                         const float* __restrict__ decay, float2* __restrict__ w_fr){
  const int wg = blockIdx.x;          // (r,p,f)
  const int f = wg & 31;
  const int rp = wg >> 5;             // r*2 + p
  const int p = rp & 1;
  const int r = rp >> 1;
  const int t = threadIdx.x;
  __shared__ float2 buf[2048];

  for (int k = t; k <= 1024; k += 256){
    float2 S[2];
#pragma unroll
    for (int d = 0; d < 2; d++){
      const int x = 2*p + d;
      const int base = (r*1025 + k)*4 + x;
      float a  = fabsf(amp[base]);
      float ph = tanhf(phase[base]) * PI_F;
      float sg = 1.0f / (1.0f + expf(-decay[base]));
      float dc = 0.5f + 0.45f * sg;
      float mag = expf(logf(dc + 1e-12f) * (float)(f+1)) * a;
      float snv, csv;
      sincosf(ph, &snv, &csv);
      float re = mag * csv, im = mag * snv;
      if (k == 0 || k == 1024) im = 0.0f;
      S[d] = make_float2(re, im);
    }
    buf[__brev((uint32_t)k) >> 21] =
        make_float2(S[0].x - S[1].y, S[0].y + S[1].x);
    if (k >= 1 && k <= 1023)
      buf[__brev((uint32_t)(2048 - k)) >> 21] =
          make_float2(S[0].x + S[1].y, -S[0].y + S[1].x);
  }
  __syncthreads();
  for (int s = 10; s >= 0; s--){
    const int ls = 10 - s;
    const int hl = 1 << ls;
    for (int bi = t; bi < 1024; bi += 256){
      const int g = bi >> ls, j = bi & (hl - 1);
      const int i0 = g*2*hl + j, i1 = i0 + hl;
      float2 pp = buf[i0], qq = buf[i1];
      float2 w = twid((uint32_t)(j << s), UNIT2K, +1.0f);
      float2 v = cmul(qq, w);
      buf[i0] = make_float2(pp.x+v.x, pp.y+v.y);
      buf[i1] = make_float2(pp.x-v.x, pp.y-v.y);
    }
    __syncthreads();
  }
  float2* O = w_fr + (size_t)wg*2048;
  for (int u = t; u < 2048; u += 256){
    float hann = 0.5f - 0.5f*cosf(TWOPI_F * (float)u / 2048.0f);
    float sc = (1.0f/2048.0f) * hann;
    O[u] = make_float2(buf[u].x*sc, buf[u].y*sc);
  }
}

// ---- OLA + transpose + sum-of-squares ------------------------------------
__global__ void k_ola(const float2* __restrict__ w_fr, float* __restrict__ w_resT,
                      float* __restrict__ w_sumsq){
  const int wg = blockIdx.x;           // rp*8 + cq
  const int cq = wg & 7;
  const int rp = wg >> 3;
  const int c0 = cq*32;
  const int r = rp >> 1, p = rp & 1;
  const int ch0 = r*4 + p*2;
  const int t = threadIdx.x;
  __shared__ float tx[32][129], ty[32][129];
  __shared__ float red[2][256];
  const float2* F = w_fr + (size_t)rp*32*2048;
  float acc0 = 0.0f, acc1 = 0.0f;
#pragma unroll
  for (int it = 0; it < 16; it++){
    const int idx = it*256 + t;        // m*32 + c'  (time-ordered reads)
    const int cp = idx & 31, m = idx >> 5;
    const int n = c0 + cp + 256*m;
    const int f = n >> 10, u = n & 1023;
    float2 a = F[(size_t)f*2048 + u];
    float vx = a.x, vy = a.y;
    if (f > 0){
      float2 b = F[(size_t)(f-1)*2048 + u + 1024];
      vx += b.x; vy += b.y;
    }
    tx[cp][m] = vx; ty[cp][m] = vy;
    acc0 += vx*vx; acc1 += vy*vy;
  }
  red[0][t] = acc0; red[1][t] = acc1;
  __syncthreads();
#pragma unroll
  for (int it = 0; it < 16; it++){
    const int idx = it*256 + t;        // c'*128 + m  (contiguous writes)
    const int m = idx & 127, cp = idx >> 7;
    w_resT[(size_t)ch0*32768 + (size_t)(c0+cp)*128 + m]     = tx[cp][m];
    w_resT[(size_t)(ch0+1)*32768 + (size_t)(c0+cp)*128 + m] = ty[cp][m];
  }
  for (int off = 128; off > 0; off >>= 1){
    __syncthreads();
    if (t < off){ red[0][t] += red[0][t+off]; red[1][t] += red[1][t+off]; }
  }
  if (t == 0){
    atomicAdd(&w_sumsq[ch0],     red[0][0]);
    atomicAdd(&w_sumsq[ch0 + 1], red[1][0]);
  }
}

// ---------------- invnorm from sumsq (1 tiny block) ------------------------
__global__ void k_norm(const float* __restrict__ w_sumsq, float* __restrict__ w_invnorm){
  const int s = threadIdx.x;
  if (s < 128) w_invnorm[s] = 1.0f/(sqrtf(w_sumsq[s]) + 1e-8f);
}

// --------- forward comb stages (s=0..7): 256-pt DIF over m, 4 combs/block --
// mode 0 (sig=r*2+p <64): packed res pair; mode 1 (sig<256): ru real+noise.
// Quad stages, 1 sincos per pass (wA1 = -i*wA0, wB = wA0^2), half2 LDS.
__global__ void k_fwdA(const int mode, const float* __restrict__ w_resT,
                       const float* __restrict__ w_invnorm,
                       const float* __restrict__ w_routed,
                       __half2* __restrict__ outh){
  const int wg = blockIdx.x;
  const int cq = wg & 63;
  const int sig = wg >> 6;
  const int c0 = cq*4;
  const int t = threadIdx.x;
  __shared__ __half2 buf[4][RPH];
  // staging: nonzero half m<128 spread over all lanes (2 per thread)
  if (mode == 0){
    const int rr = sig >> 1, pq = sig & 1;
    const int ch0 = rr*4 + pq*2;
    const float inv0 = w_invnorm[ch0], inv1 = w_invnorm[ch0+1];
#pragma unroll
    for (int i = 0; i < 2; i++){
      const int j = i*256 + t;
      const int cc = j & 3, m = j >> 2;        // m in [0,128)
      const int c = c0 + cc;
      float vx = w_resT[(size_t)ch0*32768 + c*128 + m] * inv0;
      float vy = w_resT[(size_t)(ch0+1)*32768 + c*128 + m] * inv1;
      buf[cc][SK3(m)] = __floats2half2_rn(vx, vy);
      buf[cc][SK3(m + 128)] = __floats2half2_rn(0.0f, 0.0f);
    }
  } else {
    const float* rp = w_routed + sig*128;
#pragma unroll
    for (int i = 0; i < 2; i++){
      const int j = i*256 + t;
      const int cc = j & 3, m = j >> 2;        // m in [0,128)
      const int c = c0 + cc;
      const int n = c + 256*m;
      int lo, hi; float w;
      interp128(n, lo, hi, w);
      float rv = rp[lo]*(1.0f - w) + rp[hi]*w;
      float vx = rv * jax_noise((uint32_t)sig*32768u + (uint32_t)n);
      buf[cc][SK3(m)] = __floats2half2_rn(vx, 0.0f);
      buf[cc][SK3(m + 128)] = __floats2half2_rn(0.0f, 0.0f);
    }
  }
  __syncthreads();
  // pair-fused comb stages: sp covers (s, s+1) = (2sp, 2sp+1)
  const int row = t >> 6, q = t & 63;
  for (int sp = 0; sp < 4; sp++){
    const int s  = 2*sp;
    const int hh = 1 << (6 - 2*sp);    // 64,16,4,1
    const int hl = hh << 1;            // 128,32,8,2
    const int lj = 6 - 2*sp;
    const int j = q & (hh - 1), g = q >> lj;
    const int base = g*2*hl + j;
    const uint32_t e = (uint32_t)(c0 + row) + 256u*(uint32_t)j;
    __half2* B = buf[row];
    const int i0 = SK3(base), i1 = SK3(base+hh), i2 = SK3(base+hl), i3 = SK3(base+hl+hh);
    float2 u0 = __half22float2(B[i0]);
    float2 u1 = __half22float2(B[i1]);
    float2 u2 = __half22float2(B[i2]);
    float2 u3 = __half22float2(B[i3]);
    float2 wA0 = twid((e << s) & 0xFFFFu, UNIT64K, -1.0f);
    float2 wA1 = mulnegi(wA0);          // (e + 256*hh)<<s = arg + 2^14
    float2 wB  = cmul(wA0, wA0);        // e<<(s+1) = 2*arg (mod 2^16)
    bfly_fwd(u0, u2, wA0);
    bfly_fwd(u1, u3, wA1);
    bfly_fwd(u0, u1, wB);
    bfly_fwd(u2, u3, wB);
    B[i0] = __floats2half2_rn(u0.x, u0.y);
    B[i1] = __floats2half2_rn(u1.x, u1.y);
    B[i2] = __floats2half2_rn(u2.x, u2.y);
    B[i3] = __floats2half2_rn(u3.x, u3.y);
    __syncthreads();
  }
#pragma unroll
  for (int i = 0; i < 4; i++){
    const int cc = i, m = t;                  // contiguous 256B runs per row
    outh[(size_t)sig*65536 + (size_t)(c0+cc)*256 + m] = buf[cc][SK3(m)];
  }
}

// ------- forward block stages (s=8..15) for res spectra: in-place half2 ----
__global__ void k_fwdB(__half2* __restrict__ spech){
  const int wg = blockIdx.x;
  const int mq = wg & 15;
  const int sig = wg >> 4;
  const int m16 = mq*16;
  const int t = threadIdx.x;
  __shared__ __half2 buf[16][RPH];
  __half2* base = spech + (size_t)sig*65536;
#pragma unroll
  for (int i = 0; i < 16; i++){
    const int li = t + i*256;          // li = c*16 + mm
    const int mm = li & 15, c = li >> 4;
    buf[mm][SK3(c)] = base[(size_t)c*256 + m16 + mm];
  }
  __syncthreads();
  fwd_block_fft(buf, t);
#pragma unroll
  for (int i = 0; i < 16; i++){
    const int li = t + i*256;
    const int mm = li & 15, c = li >> 4;
    base[(size_t)c*256 + m16 + mm] = buf[mm][SK3(c)];
  }
}

// ---- FUSED: ru fwd block stages + product(p=0,1)*scale + inv block stages --
__global__ __launch_bounds__(256, 4)
void k_conv(const __half2* __restrict__ ruspec,
            const __half2* __restrict__ respspec,
            __half2* __restrict__ chunkbuf, const int gbase){
  const int wg = blockIdx.x;
  const int mq = wg & 15;
  const int gl = wg >> 4;
  const int g = gbase + gl;
  const int r = g & 31;
  const int m16 = mq*16;
  const int t = threadIdx.x;
  __shared__ __half2 buf[16][RPH];
  __shared__ __half2 Fh[4096];
  const __half2* A = ruspec + (size_t)g*65536;
#pragma unroll
  for (int i = 0; i < 16; i++){
    const int li = t + i*256;          // li = c*16 + mm
    const int mm = li & 15, c = li >> 4;
    buf[mm][SK3(c)] = A[(size_t)c*256 + m16 + mm];
  }
  __syncthreads();
  fwd_block_fft(buf, t);
  // snapshot fwd spectrum (per-thread-owned cells, no sync needed)
#pragma unroll
  for (int i = 0; i < 16; i++){
    const int li = t + i*256;
    const int mm = li & 15, c = li >> 4;
    Fh[li] = buf[mm][SK3(c)];
  }
#pragma unroll 1
  for (int p = 0; p < 2; p++){
    __syncthreads();                   // protect work LDS vs prior reads
    const __half2* B = respspec + (size_t)(r*2 + p)*65536;
#pragma unroll
    for (int i = 0; i < 16; i++){
      const int li = t + i*256;
      const int mm = li & 15, c = li >> 4;
      float2 b = __half22float2(B[(size_t)c*256 + m16 + mm]);
      float2 f = __half22float2(Fh[li]);
      buf[mm][SK3(c)] = __floats2half2_rn((f.x*b.x - f.y*b.y) * SCALE64K,
                                          (f.x*b.y + f.y*b.x) * SCALE64K);
    }
    __syncthreads();
    inv_block_fft(buf, t);
    __half2* O = chunkbuf + (size_t)(gl*2 + p)*65536;
#pragma unroll
    for (int i = 0; i < 16; i++){
      const int li = t + i*256;        // li = mm*256 + c -> contiguous rows
      const int mm = li >> 8, c = li & 255;
      O[(size_t)(m16+mm)*256 + c] = buf[mm][SK3(c)];
    }
  }
}

// -- inverse comb stages (s=7..0, fused pairs): 16 c x 2 p, fused epilogue --
// addresses it-invariant (q = t&63); 1 sincos per it (wA = wB0^2, wB1 = i*wB0)
__global__ __launch_bounds__(256, 4)
void k_invA_w(const __half2* __restrict__ chunkbuf, const int gbase,
              const float* __restrict__ w_sm, const float* __restrict__ gains,
              float* __restrict__ out0){
  const int wg = blockIdx.x;
  const int c16 = wg & 15;
  const int gl = wg >> 4;
  const int g = gbase + gl;
  const int r = g & 31, be = g >> 5;
  const int c0 = c16*16;
  const int t = threadIdx.x;
  __shared__ __half2 zz[2][16][RPH];
#pragma unroll
  for (int p = 0; p < 2; p++){
    const __half2* C = chunkbuf + (size_t)(gl*2 + p)*65536;
#pragma unroll
    for (int i = 0; i < 16; i++){
      const int li = t + i*256;        // li = m*16 + cc -> 64B clusters
      const int cc = li & 15, m = li >> 4;
      zz[p][cc][SK3(m)] = C[(size_t)m*256 + c0 + cc];
    }
  }
  __syncthreads();
  const int q = t & 63;
  const int row0 = t >> 6;
  for (int sp = 0; sp < 4; sp++){
    const int sB = 6 - 2*sp;
    const int hA = 1 << (2*sp);        // 1,4,16,64
    const int lA = 2*sp;
    const int j = q & (hA - 1), gq = q >> lA;
    const int base = gq*4*hA + j;
    const int i0 = SK3(base), i1 = SK3(base+hA), i2 = SK3(base+2*hA), i3 = SK3(base+3*hA);
#pragma unroll 1
    for (int it = 0; it < 8; it++){
      const int row = row0 + it*4;     // 32 rows: p(1) cc(4)
      const int p = row >> 4, cc = row & 15;
      __half2* Z = zz[p][cc];
      float2 u0 = __half22float2(Z[i0]);
      float2 u1 = __half22float2(Z[i1]);
      float2 u2 = __half22float2(Z[i2]);
      float2 u3 = __half22float2(Z[i3]);
      const uint32_t e = (uint32_t)(c0 + cc) + 256u*(uint32_t)j;
      float2 wB0 = twid((e << sB) & 0xFFFFu, UNIT64K, +1.0f);
      float2 wA  = cmul(wB0, wB0);     // e<<sA = 2*(e<<sB) (mod 2^16)
      float2 wB1 = mulposi(wB0);       // (e+256*hA)<<sB = arg + 2^14
      bfly_inv(u0, u1, wA);
      bfly_inv(u2, u3, wA);
      bfly_inv(u0, u2, wB0);
      bfly_inv(u1, u3, wB1);
      Z[i0] = __floats2half2_rn(u0.x, u0.y);
      Z[i1] = __floats2half2_rn(u1.x, u1.y);
      Z[i2] = __floats2half2_rn(u2.x, u2.y);
      Z[i3] = __floats2half2_rn(u3.x, u3.y);
    }
    __syncthreads();
  }
  const float gv = fabsf(gains[r]);
  const float* smb = w_sm + be*512;
#pragma unroll
  for (int it = 0; it < 8; it++){
    const int li = t + it*256;         // li = m*16 + cc, m < 128
    const int cc = li & 15, m = li >> 4;
    const int tt = c0 + cc + 256*m;
    int lo, hi; float w;
    interp128(tt, lo, hi, w);
    float2 z0 = __half22float2(zz[0][cc][SK3(m)]);
    float2 z1 = __half22float2(zz[1][cc][SK3(m)]);
    float dw0 = smb[0*128 + lo]*(1.0f - w) + smb[0*128 + hi]*w;
    float dw1 = smb[1*128 + lo]*(1.0f - w) + smb[1*128 + hi]*w;
    float dw2 = smb[2*128 + lo]*(1.0f - w) + smb[2*128 + hi]*w;
    float dw3 = smb[3*128 + lo]*(1.0f - w) + smb[3*128 + hi]*w;
    float val = dw0*z0.x + dw1*z0.y + dw2*z1.x + dw3*z1.y;  // scale pre-folded
    atomicAdd(&out0[(size_t)be*32768 + tt], tanhf(val*gv));
  }
}

extern "C" void kernel_launch(void* const* d_in, const int* in_sizes, int n_in,
                              void* d_out, int out_size, void* d_ws, size_t ws_size,
                              hipStream_t stream){
  const float* ctrl   = (const float*)d_in[0];
  const float* defm   = (const float*)d_in[1];
  const float* router = (const float*)d_in[2];
  const float* amp    = (const float*)d_in[3];
  const float* phase  = (const float*)d_in[4];
  const float* decay  = (const float*)d_in[5];
  const float* gains  = (const float*)d_in[6];
  float* out = (float*)d_out;
  float* ws  = (float*)d_ws;

  // ws layout (float offsets)
  float*   w_resT    = ws;                          // 4,194,304
  float*   w_routed  = ws + 4194304;                // 32,768
  float*   w_sm      = ws + 4227072;                // 4,096
  float*   w_invnorm = ws + 4231168;                // 128
  float*   w_sumsq   = ws + 4231296;                // 128
  __half2* ruspec_h  = (__half2*)(ws + 4231424);    // 256*65536 h2 = 16,777,216 f
  __half2* resp_h    = (__half2*)(ws + 21008640);   // 64*65536 h2  =  4,194,304 f
  __half2* chunk_h   = (__half2*)(ws + 25202944);   // 2G*65536 h2  = G*131,072 f
  const size_t base_f = 25202944;
  // frames scratch aliases ruspec_h region (ruspec written later by fwdA)
  float2* w_fr       = (float2*)ruspec_h;           // 2048*2048 c = 8,388,608 f

  int G = 0;
  for (int gg = 128; gg >= 1; gg >>= 1){
    size_t need = (base_f + (size_t)gg*131072) * sizeof(float);
    if (need <= ws_size){ G = gg; break; }
  }

  hipMemsetAsync(d_out, 0, 262144*sizeof(float), stream);  // out0 (atomicAdd)
  k_routed<<<132, 256, 0, stream>>>(ctrl, defm, router, w_routed, w_sm, out + 262144);
  if (G == 0) return;  // diagnostic: out1 ok, out0 stays 0 => ws too small

  hipMemsetAsync(w_sumsq, 0, 128*sizeof(float), stream);
  k_frames<<<2048, 256, 0, stream>>>(amp, phase, decay, w_fr);
  k_ola<<<512, 256, 0, stream>>>(w_fr, w_resT, w_sumsq);
  k_norm<<<1, 128, 0, stream>>>(w_sumsq, w_invnorm);
  k_fwdA<<<64*64, 256, 0, stream>>>(0, w_resT, w_invnorm, w_routed, resp_h);
  k_fwdB<<<64*16, 256, 0, stream>>>(resp_h);
  k_fwdA<<<256*64, 256, 0, stream>>>(1, w_resT, w_invnorm, w_routed, ruspec_h);
  for (int gb = 0; gb < 256; gb += G){
    k_conv<<<G*16, 256, 0, stream>>>(ruspec_h, resp_h, chunk_h, gb);
    k_invA_w<<<G*16, 256, 0, stream>>>(chunk_h, gb, w_sm, gains, out);
  }
}

// Round 12
// 398.076 us; speedup vs baseline: 2.0258x; 1.0022x over previous
//
#include <hip/hip_runtime.h>
#include <hip/hip_fp16.h>
#include <stdint.h>

// ResonanceLayer: routed einsum -> resonance irfft (x-pair packed, frames to
// scratch) -> OLA+transpose+norm -> upsample*threefry-noise -> 65536-pt FFT
// convolution with complex-packed res spectra -> softmax-deformation mix ->
// tanh(gain*x) summed over resonators.
//
// Round-12: fix round-11's k_conv spill. Hoisting twiddles AND the four LDS
// addresses across the it-loop stretched live ranges -> 32B/thread scratch
// (WRITE 65536->81920KB, VGPR 56->64, dur +1us despite VALU 65->47%). Now
// only the twiddles stay hoisted (1 sincos/pass, the expensive part);
// j/g/base/i0..i3 are recomputed per it (cheap int ops). invA/fwdA keep the
// round-11 form (they improved).

#define PI_F     3.14159265358979323846f
#define TWOPI_F  6.28318530717958647692f
#define UNIT64K  (TWOPI_F/65536.0f)
#define UNIT2K   (TWOPI_F/2048.0f)
#define SCALE64K (1.0f/65536.0f)
#define SK3(i)   ((i) + 3*((i) >> 4))    // per-16 pad: <=3-way on all strides
#define RPH 308                          // row pitch (>=301, ==4*5 mod 32)

__device__ __forceinline__ float2 cmul(float2 a, float2 b){
  return make_float2(a.x*b.x - a.y*b.y, a.x*b.y + a.y*b.x);
}

__device__ __forceinline__ float2 twid(uint32_t e, float unit, float sign){
  float ang = (float)e * unit;
  float sn, cn;
  __sincosf(ang, &sn, &cn);
  return make_float2(cn, sign*sn);
}

// quarter-turn helpers: mulnegi(w) = -i*w ; mulposi(w) = +i*w  (exact)
__device__ __forceinline__ float2 mulnegi(float2 w){ return make_float2(w.y, -w.x); }
__device__ __forceinline__ float2 mulposi(float2 w){ return make_float2(-w.y, w.x); }

// DIF butterfly: u' = u+v ; v' = (u-v)*w
__device__ __forceinline__ void bfly_fwd(float2& u, float2& v, float2 w){
  float2 d = make_float2(u.x - v.x, u.y - v.y);
  u = make_float2(u.x + v.x, u.y + v.y);
  v = cmul(d, w);
}
// DIT butterfly: t = v*w ; u' = u+t ; v' = u-t
__device__ __forceinline__ void bfly_inv(float2& u, float2& v, float2 w){
  float2 tv = cmul(v, w);
  v = make_float2(u.x - tv.x, u.y - tv.y);
  u = make_float2(u.x + tv.x, u.y + tv.y);
}

__device__ __forceinline__ uint32_t rotl32(uint32_t v, int r){
  return (v << r) | (v >> (32 - r));
}

// Threefry-2x32, key = (0, 123)
__device__ __forceinline__ void threefry2x32(uint32_t c0, uint32_t c1,
                                             uint32_t& o0, uint32_t& o1){
  const uint32_t k0 = 0u, k1 = 123u;
  const uint32_t k2 = 0x1BD11BDAu ^ k0 ^ k1;
  const uint32_t ks[3] = {k0, k1, k2};
  uint32_t x0 = c0 + k0, x1 = c1 + k1;
#pragma unroll
  for (int i = 0; i < 5; i++){
    if ((i & 1) == 0){
      x0 += x1; x1 = rotl32(x1,13); x1 ^= x0;
      x0 += x1; x1 = rotl32(x1,15); x1 ^= x0;
      x0 += x1; x1 = rotl32(x1,26); x1 ^= x0;
      x0 += x1; x1 = rotl32(x1, 6); x1 ^= x0;
    } else {
      x0 += x1; x1 = rotl32(x1,17); x1 ^= x0;
      x0 += x1; x1 = rotl32(x1,29); x1 ^= x0;
      x0 += x1; x1 = rotl32(x1,16); x1 ^= x0;
      x0 += x1; x1 = rotl32(x1,24); x1 ^= x0;
    }
    x0 += ks[(i+1)%3];
    x1 += ks[(i+2)%3] + (uint32_t)(i+1);
  }
  o0 = x0; o1 = x1;
}

__device__ __forceinline__ float jax_noise(uint32_t p){
  uint32_t b0, b1;
  threefry2x32(0u, p, b0, b1);
  uint32_t bits = b0 ^ b1;
  float u = __uint_as_float((bits >> 9) | 0x3f800000u) - 1.0f;
  return fmaxf(-1.0f, u*2.0f - 1.0f);
}

__device__ __forceinline__ void interp128(int t, int& lo, int& hi, float& w){
  float posf = ((float)t + 0.5f) * (1.0f/256.0f) - 0.5f;
  posf = fminf(fmaxf(posf, 0.0f), 127.0f);
  lo = (int)posf;
  hi = lo + 1; if (hi > 127) hi = 127;
  w = posf - (float)lo;
}

// ---- fused-pair forward block FFT (DIF, stages 8..15), half2 cells --------
// twiddles hoisted (1 sincos/pass); indices recomputed per it (spill fix)
__device__ __forceinline__ void fwd_block_fft(__half2 (*buf)[RPH], const int t){
  const int q = t & 63;
  const int row0 = t >> 6;
  for (int sp = 0; sp < 4; sp++){
    const int s  = 8 + 2*sp;
    const int hl = 1 << (7 - 2*sp);    // 128,32,8,2
    const int hh = hl >> 1;            // 64,16,4,1
    const int lj = 6 - 2*sp;
    const float2 wA0 = twid((uint32_t)((q & (hh - 1)) << s), UNIT64K, -1.0f);
    const float2 wA1 = mulnegi(wA0);          // w(arg+2^14)
    const float2 wB  = cmul(wA0, wA0);        // w(2*arg)
#pragma unroll 1
    for (int it = 0; it < 4; it++){
      const int j = q & (hh - 1), g = q >> lj;
      const int base = g*2*hl + j;
      const int i0 = SK3(base), i1 = SK3(base+hh), i2 = SK3(base+hl), i3 = SK3(base+hl+hh);
      __half2* B = buf[row0 + it*4];
      float2 u0 = __half22float2(B[i0]);
      float2 u1 = __half22float2(B[i1]);
      float2 u2 = __half22float2(B[i2]);
      float2 u3 = __half22float2(B[i3]);
      bfly_fwd(u0, u2, wA0);
      bfly_fwd(u1, u3, wA1);
      bfly_fwd(u0, u1, wB);
      bfly_fwd(u2, u3, wB);
      B[i0] = __floats2half2_rn(u0.x, u0.y);
      B[i1] = __floats2half2_rn(u1.x, u1.y);
      B[i2] = __floats2half2_rn(u2.x, u2.y);
      B[i3] = __floats2half2_rn(u3.x, u3.y);
    }
    __syncthreads();
  }
}

// ---- fused-pair inverse block FFT (DIT, stages 15..8), half2 cells --------
// twiddles hoisted (1 sincos/pass); indices recomputed per it (spill fix)
__device__ __forceinline__ void inv_block_fft(__half2 (*buf)[RPH], const int t){
  const int q = t & 63;
  const int row0 = t >> 6;
  for (int sp = 0; sp < 4; sp++){
    const int sB = 14 - 2*sp;
    const int hA = 1 << (2*sp);        // 1,4,16,64
    const int lA = 2*sp;
    const float2 wB0 = twid((uint32_t)((q & (hA - 1)) << sB), UNIT64K, +1.0f);
    const float2 wA  = cmul(wB0, wB0);        // w(2*argB)
    const float2 wB1 = mulposi(wB0);          // w(argB+2^14)
#pragma unroll 1
    for (int it = 0; it < 4; it++){
      const int j = q & (hA - 1), g = q >> lA;
      const int base = g*4*hA + j;
      const int i0 = SK3(base), i1 = SK3(base+hA), i2 = SK3(base+2*hA), i3 = SK3(base+3*hA);
      __half2* B = buf[row0 + it*4];
      float2 u0 = __half22float2(B[i0]);
      float2 u1 = __half22float2(B[i1]);
      float2 u2 = __half22float2(B[i2]);
      float2 u3 = __half22float2(B[i3]);
      bfly_inv(u0, u1, wA);
      bfly_inv(u2, u3, wA);
      bfly_inv(u0, u2, wB0);
      bfly_inv(u1, u3, wB1);
      B[i0] = __floats2half2_rn(u0.x, u0.y);
      B[i1] = __floats2half2_rn(u1.x, u1.y);
      B[i2] = __floats2half2_rn(u2.x, u2.y);
      B[i3] = __floats2half2_rn(u3.x, u3.y);
    }
    __syncthreads();
  }
}

// ---------------- routed einsum + output1 + softmax(deformations) ----------
__global__ void k_routed(const float* __restrict__ ctrl, const float* __restrict__ defm,
                         const float* __restrict__ router,
                         float* __restrict__ w_routed, float* __restrict__ w_sm,
                         float* __restrict__ out1){
  int idx = blockIdx.x*blockDim.x + threadIdx.x;
  if (idx < 32768){
    int f = idx & 127, r = (idx >> 7) & 31, be = idx >> 12;
    float acc = 0.0f;
#pragma unroll
    for (int c = 0; c < 16; c++)
      acc += ctrl[(be*16 + c)*128 + f] * router[c*32 + r];
    w_routed[idx] = acc;
    out1[idx] = acc;
  } else if (idx < 32768 + 1024){
    int j = idx - 32768;
    int f = j & 127, be = j >> 7;
    float v[4];
#pragma unroll
    for (int x = 0; x < 4; x++)
      v[x] = defm[(be*4 + x)*128 + f] + (x == 0 ? 1.0f : 0.0f);
    float mx = fmaxf(fmaxf(v[0], v[1]), fmaxf(v[2], v[3]));
    float s = 0.0f;
#pragma unroll
    for (int x = 0; x < 4; x++){ v[x] = expf(v[x] - mx); s += v[x]; }
#pragma unroll
    for (int x = 0; x < 4; x++) w_sm[(be*4 + x)*128 + f] = v[x]/s;
  }
}

// ---- resonance frames: packed complex irfft(2048) of x-pairs + hann -------
__global__ void k_frames(const float* __restrict__ amp, const float* __restrict__ phase,
                         const float* __restrict__ decay, float2* __restrict__ w_fr){
  const int wg = blockIdx.x;          // (r,p,f)
  const int f = wg & 31;
  const int rp = wg >> 5;             // r*2 + p
  const int p = rp & 1;
  const int r = rp >> 1;
  const int t = threadIdx.x;
  __shared__ float2 buf[2048];

  for (int k = t; k <= 1024; k += 256){
    float2 S[2];
#pragma unroll
    for (int d = 0; d < 2; d++){
      const int x = 2*p + d;
      const int base = (r*1025 + k)*4 + x;
      float a  = fabsf(amp[base]);
      float ph = tanhf(phase[base]) * PI_F;
      float sg = 1.0f / (1.0f + expf(-decay[base]));
      float dc = 0.5f + 0.45f * sg;
      float mag = expf(logf(dc + 1e-12f) * (float)(f+1)) * a;
      float snv, csv;
      sincosf(ph, &snv, &csv);
      float re = mag * csv, im = mag * snv;
      if (k == 0 || k == 1024) im = 0.0f;
      S[d] = make_float2(re, im);
    }
    buf[__brev((uint32_t)k) >> 21] =
        make_float2(S[0].x - S[1].y, S[0].y + S[1].x);
    if (k >= 1 && k <= 1023)
      buf[__brev((uint32_t)(2048 - k)) >> 21] =
          make_float2(S[0].x + S[1].y, -S[0].y + S[1].x);
  }
  __syncthreads();
  for (int s = 10; s >= 0; s--){
    const int ls = 10 - s;
    const int hl = 1 << ls;
    for (int bi = t; bi < 1024; bi += 256){
      const int g = bi >> ls, j = bi & (hl - 1);
      const int i0 = g*2*hl + j, i1 = i0 + hl;
      float2 pp = buf[i0], qq = buf[i1];
      float2 w = twid((uint32_t)(j << s), UNIT2K, +1.0f);
      float2 v = cmul(qq, w);
      buf[i0] = make_float2(pp.x+v.x, pp.y+v.y);
      buf[i1] = make_float2(pp.x-v.x, pp.y-v.y);
    }
    __syncthreads();
  }
  float2* O = w_fr + (size_t)wg*2048;
  for (int u = t; u < 2048; u += 256){
    float hann = 0.5f - 0.5f*cosf(TWOPI_F * (float)u / 2048.0f);
    float sc = (1.0f/2048.0f) * hann;
    O[u] = make_float2(buf[u].x*sc, buf[u].y*sc);
  }
}

// ---- OLA + transpose + sum-of-squares ------------------------------------
__global__ void k_ola(const float2* __restrict__ w_fr, float* __restrict__ w_resT,
                      float* __restrict__ w_sumsq){
  const int wg = blockIdx.x;           // rp*8 + cq
  const int cq = wg & 7;
  const int rp = wg >> 3;
  const int c0 = cq*32;
  const int r = rp >> 1, p = rp & 1;
  const int ch0 = r*4 + p*2;
  const int t = threadIdx.x;
  __shared__ float tx[32][129], ty[32][129];
  __shared__ float red[2][256];
  const float2* F = w_fr + (size_t)rp*32*2048;
  float acc0 = 0.0f, acc1 = 0.0f;
#pragma unroll
  for (int it = 0; it < 16; it++){
    const int idx = it*256 + t;        // m*32 + c'  (time-ordered reads)
    const int cp = idx & 31, m = idx >> 5;
    const int n = c0 + cp + 256*m;
    const int f = n >> 10, u = n & 1023;
    float2 a = F[(size_t)f*2048 + u];
    float vx = a.x, vy = a.y;
    if (f > 0){
      float2 b = F[(size_t)(f-1)*2048 + u + 1024];
      vx += b.x; vy += b.y;
    }
    tx[cp][m] = vx; ty[cp][m] = vy;
    acc0 += vx*vx; acc1 += vy*vy;
  }
  red[0][t] = acc0; red[1][t] = acc1;
  __syncthreads();
#pragma unroll
  for (int it = 0; it < 16; it++){
    const int idx = it*256 + t;        // c'*128 + m  (contiguous writes)
    const int m = idx & 127, cp = idx >> 7;
    w_resT[(size_t)ch0*32768 + (size_t)(c0+cp)*128 + m]     = tx[cp][m];
    w_resT[(size_t)(ch0+1)*32768 + (size_t)(c0+cp)*128 + m] = ty[cp][m];
  }
  for (int off = 128; off > 0; off >>= 1){
    __syncthreads();
    if (t < off){ red[0][t] += red[0][t+off]; red[1][t] += red[1][t+off]; }
  }
  if (t == 0){
    atomicAdd(&w_sumsq[ch0],     red[0][0]);
    atomicAdd(&w_sumsq[ch0 + 1], red[1][0]);
  }
}

// ---------------- invnorm from sumsq (1 tiny block) ------------------------
__global__ void k_norm(const float* __restrict__ w_sumsq, float* __restrict__ w_invnorm){
  const int s = threadIdx.x;
  if (s < 128) w_invnorm[s] = 1.0f/(sqrtf(w_sumsq[s]) + 1e-8f);
}

// --------- forward comb stages (s=0..7): 256-pt DIF over m, 4 combs/block --
// mode 0 (sig=r*2+p <64): packed res pair; mode 1 (sig<256): ru real+noise.
// Quad stages, 1 sincos per pass (wA1 = -i*wA0, wB = wA0^2), half2 LDS.
__global__ void k_fwdA(const int mode, const float* __restrict__ w_resT,
                       const float* __restrict__ w_invnorm,
                       const float* __restrict__ w_routed,
                       __half2* __restrict__ outh){
  const int wg = blockIdx.x;
  const int cq = wg & 63;
  const int sig = wg >> 6;
  const int c0 = cq*4;
  const int t = threadIdx.x;
  __shared__ __half2 buf[4][RPH];
  // staging: nonzero half m<128 spread over all lanes (2 per thread)
  if (mode == 0){
    const int rr = sig >> 1, pq = sig & 1;
    const int ch0 = rr*4 + pq*2;
    const float inv0 = w_invnorm[ch0], inv1 = w_invnorm[ch0+1];
#pragma unroll
    for (int i = 0; i < 2; i++){
      const int j = i*256 + t;
      const int cc = j & 3, m = j >> 2;        // m in [0,128)
      const int c = c0 + cc;
      float vx = w_resT[(size_t)ch0*32768 + c*128 + m] * inv0;
      float vy = w_resT[(size_t)(ch0+1)*32768 + c*128 + m] * inv1;
      buf[cc][SK3(m)] = __floats2half2_rn(vx, vy);
      buf[cc][SK3(m + 128)] = __floats2half2_rn(0.0f, 0.0f);
    }
  } else {
    const float* rp = w_routed + sig*128;
#pragma unroll
    for (int i = 0; i < 2; i++){
      const int j = i*256 + t;
      const int cc = j & 3, m = j >> 2;        // m in [0,128)
      const int c = c0 + cc;
      const int n = c + 256*m;
      int lo, hi; float w;
      interp128(n, lo, hi, w);
      float rv = rp[lo]*(1.0f - w) + rp[hi]*w;
      float vx = rv * jax_noise((uint32_t)sig*32768u + (uint32_t)n);
      buf[cc][SK3(m)] = __floats2half2_rn(vx, 0.0f);
      buf[cc][SK3(m + 128)] = __floats2half2_rn(0.0f, 0.0f);
    }
  }
  __syncthreads();
  // pair-fused comb stages: sp covers (s, s+1) = (2sp, 2sp+1)
  const int row = t >> 6, q = t & 63;
  for (int sp = 0; sp < 4; sp++){
    const int s  = 2*sp;
    const int hh = 1 << (6 - 2*sp);    // 64,16,4,1
    const int hl = hh << 1;            // 128,32,8,2
    const int lj = 6 - 2*sp;
    const int j = q & (hh - 1), g = q >> lj;
    const int base = g*2*hl + j;
    const uint32_t e = (uint32_t)(c0 + row) + 256u*(uint32_t)j;
    __half2* B = buf[row];
    const int i0 = SK3(base), i1 = SK3(base+hh), i2 = SK3(base+hl), i3 = SK3(base+hl+hh);
    float2 u0 = __half22float2(B[i0]);
    float2 u1 = __half22float2(B[i1]);
    float2 u2 = __half22float2(B[i2]);
    float2 u3 = __half22float2(B[i3]);
    float2 wA0 = twid((e << s) & 0xFFFFu, UNIT64K, -1.0f);
    float2 wA1 = mulnegi(wA0);          // (e + 256*hh)<<s = arg + 2^14
    float2 wB  = cmul(wA0, wA0);        // e<<(s+1) = 2*arg (mod 2^16)
    bfly_fwd(u0, u2, wA0);
    bfly_fwd(u1, u3, wA1);
    bfly_fwd(u0, u1, wB);
    bfly_fwd(u2, u3, wB);
    B[i0] = __floats2half2_rn(u0.x, u0.y);
    B[i1] = __floats2half2_rn(u1.x, u1.y);
    B[i2] = __floats2half2_rn(u2.x, u2.y);
    B[i3] = __floats2half2_rn(u3.x, u3.y);
    __syncthreads();
  }
#pragma unroll
  for (int i = 0; i < 4; i++){
    const int cc = i, m = t;                  // contiguous 256B runs per row
    outh[(size_t)sig*65536 + (size_t)(c0+cc)*256 + m] = buf[cc][SK3(m)];
  }
}

// ------- forward block stages (s=8..15) for res spectra: in-place half2 ----
__global__ void k_fwdB(__half2* __restrict__ spech){
  const int wg = blockIdx.x;
  const int mq = wg & 15;
  const int sig = wg >> 4;
  const int m16 = mq*16;
  const int t = threadIdx.x;
  __shared__ __half2 buf[16][RPH];
  __half2* base = spech + (size_t)sig*65536;
#pragma unroll
  for (int i = 0; i < 16; i++){
    const int li = t + i*256;          // li = c*16 + mm
    const int mm = li & 15, c = li >> 4;
    buf[mm][SK3(c)] = base[(size_t)c*256 + m16 + mm];
  }
  __syncthreads();
  fwd_block_fft(buf, t);
#pragma unroll
  for (int i = 0; i < 16; i++){
    const int li = t + i*256;
    const int mm = li & 15, c = li >> 4;
    base[(size_t)c*256 + m16 + mm] = buf[mm][SK3(c)];
  }
}

// ---- FUSED: ru fwd block stages + product(p=0,1)*scale + inv block stages --
__global__ __launch_bounds__(256, 4)
void k_conv(const __half2* __restrict__ ruspec,
            const __half2* __restrict__ respspec,
            __half2* __restrict__ chunkbuf, const int gbase){
  const int wg = blockIdx.x;
  const int mq = wg & 15;
  const int gl = wg >> 4;
  const int g = gbase + gl;
  const int r = g & 31;
  const int m16 = mq*16;
  const int t = threadIdx.x;
  __shared__ __half2 buf[16][RPH];
  __shared__ __half2 Fh[4096];
  const __half2* A = ruspec + (size_t)g*65536;
#pragma unroll
  for (int i = 0; i < 16; i++){
    const int li = t + i*256;          // li = c*16 + mm
    const int mm = li & 15, c = li >> 4;
    buf[mm][SK3(c)] = A[(size_t)c*256 + m16 + mm];
  }
  __syncthreads();
  fwd_block_fft(buf, t);
  // snapshot fwd spectrum (per-thread-owned cells, no sync needed)
#pragma unroll
  for (int i = 0; i < 16; i++){
    const int li = t + i*256;
    const int mm = li & 15, c = li >> 4;
    Fh[li] = buf[mm][SK3(c)];
  }
#pragma unroll 1
  for (int p = 0; p < 2; p++){
    __syncthreads();                   // protect work LDS vs prior reads
    const __half2* B = respspec + (size_t)(r*2 + p)*65536;
#pragma unroll
    for (int i = 0; i < 16; i++){
      const int li = t + i*256;
      const int mm = li & 15, c = li >> 4;
      float2 b = __half22float2(B[(size_t)c*256 + m16 + mm]);
      float2 f = __half22float2(Fh[li]);
      buf[mm][SK3(c)] = __floats2half2_rn((f.x*b.x - f.y*b.y) * SCALE64K,
                                          (f.x*b.y + f.y*b.x) * SCALE64K);
    }
    __syncthreads();
    inv_block_fft(buf, t);
    __half2* O = chunkbuf + (size_t)(gl*2 + p)*65536;
#pragma unroll
    for (int i = 0; i < 16; i++){
      const int li = t + i*256;        // li = mm*256 + c -> contiguous rows
      const int mm = li >> 8, c = li & 255;
      O[(size_t)(m16+mm)*256 + c] = buf[mm][SK3(c)];
    }
  }
}

// -- inverse comb stages (s=7..0, fused pairs): 16 c x 2 p, fused epilogue --
// addresses it-invariant (q = t&63); 1 sincos per it (wA = wB0^2, wB1 = i*wB0)
__global__ __launch_bounds__(256, 4)
void k_invA_w(const __half2* __restrict__ chunkbuf, const int gbase,
              const float* __restrict__ w_sm, const float* __restrict__ gains,
              float* __restrict__ out0){
  const int wg = blockIdx.x;
  const int c16 = wg & 15;
  const int gl = wg >> 4;
  const int g = gbase + gl;
  const int r = g & 31, be = g >> 5;
  const int c0 = c16*16;
  const int t = threadIdx.x;
  __shared__ __half2 zz[2][16][RPH];
#pragma unroll
  for (int p = 0; p < 2; p++){
    const __half2* C = chunkbuf + (size_t)(gl*2 + p)*65536;
#pragma unroll
    for (int i = 0; i < 16; i++){
      const int li = t + i*256;        // li = m*16 + cc -> 64B clusters
      const int cc = li & 15, m = li >> 4;
      zz[p][cc][SK3(m)] = C[(size_t)m*256 + c0 + cc];
    }
  }
  __syncthreads();
  const int q = t & 63;
  const int row0 = t >> 6;
  for (int sp = 0; sp < 4; sp++){
    const int sB = 6 - 2*sp;
    const int hA = 1 << (2*sp);        // 1,4,16,64
    const int lA = 2*sp;
    const int j = q & (hA - 1), gq = q >> lA;
    const int base = gq*4*hA + j;
    const int i0 = SK3(base), i1 = SK3(base+hA), i2 = SK3(base+2*hA), i3 = SK3(base+3*hA);
#pragma unroll 1
    for (int it = 0; it < 8; it++){
      const int row = row0 + it*4;     // 32 rows: p(1) cc(4)
      const int p = row >> 4, cc = row & 15;
      __half2* Z = zz[p][cc];
      float2 u0 = __half22float2(Z[i0]);
      float2 u1 = __half22float2(Z[i1]);
      float2 u2 = __half22float2(Z[i2]);
      float2 u3 = __half22float2(Z[i3]);
      const uint32_t e = (uint32_t)(c0 + cc) + 256u*(uint32_t)j;
      float2 wB0 = twid((e << sB) & 0xFFFFu, UNIT64K, +1.0f);
      float2 wA  = cmul(wB0, wB0);     // e<<sA = 2*(e<<sB) (mod 2^16)
      float2 wB1 = mulposi(wB0);       // (e+256*hA)<<sB = arg + 2^14
      bfly_inv(u0, u1, wA);
      bfly_inv(u2, u3, wA);
      bfly_inv(u0, u2, wB0);
      bfly_inv(u1, u3, wB1);
      Z[i0] = __floats2half2_rn(u0.x, u0.y);
      Z[i1] = __floats2half2_rn(u1.x, u1.y);
      Z[i2] = __floats2half2_rn(u2.x, u2.y);
      Z[i3] = __floats2half2_rn(u3.x, u3.y);
    }
    __syncthreads();
  }
  const float gv = fabsf(gains[r]);
  const float* smb = w_sm + be*512;
#pragma unroll
  for (int it = 0; it < 8; it++){
    const int li = t + it*256;         // li = m*16 + cc, m < 128
    const int cc = li & 15, m = li >> 4;
    const int tt = c0 + cc + 256*m;
    int lo, hi; float w;
    interp128(tt, lo, hi, w);
    float2 z0 = __half22float2(zz[0][cc][SK3(m)]);
    float2 z1 = __half22float2(zz[1][cc][SK3(m)]);
    float dw0 = smb[0*128 + lo]*(1.0f - w) + smb[0*128 + hi]*w;
    float dw1 = smb[1*128 + lo]*(1.0f - w) + smb[1*128 + hi]*w;
    float dw2 = smb[2*128 + lo]*(1.0f - w) + smb[2*128 + hi]*w;
    float dw3 = smb[3*128 + lo]*(1.0f - w) + smb[3*128 + hi]*w;
    float val = dw0*z0.x + dw1*z0.y + dw2*z1.x + dw3*z1.y;  // scale pre-folded
    atomicAdd(&out0[(size_t)be*32768 + tt], tanhf(val*gv));
  }
}

extern "C" void kernel_launch(void* const* d_in, const int* in_sizes, int n_in,
                              void* d_out, int out_size, void* d_ws, size_t ws_size,
                              hipStream_t stream){
  const float* ctrl   = (const float*)d_in[0];
  const float* defm   = (const float*)d_in[1];
  const float* router = (const float*)d_in[2];
  const float* amp    = (const float*)d_in[3];
  const float* phase  = (const float*)d_in[4];
  const float* decay  = (const float*)d_in[5];
  const float* gains  = (const float*)d_in[6];
  float* out = (float*)d_out;
  float* ws  = (float*)d_ws;

  // ws layout (float offsets)
  float*   w_resT    = ws;                          // 4,194,304
  float*   w_routed  = ws + 4194304;                // 32,768
  float*   w_sm      = ws + 4227072;                // 4,096
  float*   w_invnorm = ws + 4231168;                // 128
  float*   w_sumsq   = ws + 4231296;                // 128
  __half2* ruspec_h  = (__half2*)(ws + 4231424);    // 256*65536 h2 = 16,777,216 f
  __half2* resp_h    = (__half2*)(ws + 21008640);   // 64*65536 h2  =  4,194,304 f
  __half2* chunk_h   = (__half2*)(ws + 25202944);   // 2G*65536 h2  = G*131,072 f
  const size_t base_f = 25202944;
  // frames scratch aliases ruspec_h region (ruspec written later by fwdA)
  float2* w_fr       = (float2*)ruspec_h;           // 2048*2048 c = 8,388,608 f

  int G = 0;
  for (int gg = 128; gg >= 1; gg >>= 1){
    size_t need = (base_f + (size_t)gg*131072) * sizeof(float);
    if (need <= ws_size){ G = gg; break; }
  }

  hipMemsetAsync(d_out, 0, 262144*sizeof(float), stream);  // out0 (atomicAdd)
  k_routed<<<132, 256, 0, stream>>>(ctrl, defm, router, w_routed, w_sm, out + 262144);
  if (G == 0) return;  // diagnostic: out1 ok, out0 stays 0 => ws too small

  hipMemsetAsync(w_sumsq, 0, 128*sizeof(float), stream);
  k_frames<<<2048, 256, 0, stream>>>(amp, phase, decay, w_fr);
  k_ola<<<512, 256, 0, stream>>>(w_fr, w_resT, w_sumsq);
  k_norm<<<1, 128, 0, stream>>>(w_sumsq, w_invnorm);
  k_fwdA<<<64*64, 256, 0, stream>>>(0, w_resT, w_invnorm, w_routed, resp_h);
  k_fwdB<<<64*16, 256, 0, stream>>>(resp_h);
  k_fwdA<<<256*64, 256, 0, stream>>>(1, w_resT, w_invnorm, w_routed, ruspec_h);
  for (int gb = 0; gb < 256; gb += G){
    k_conv<<<G*16, 256, 0, stream>>>(ruspec_h, resp_h, chunk_h, gb);
    k_invA_w<<<G*16, 256, 0, stream>>>(chunk_h, gb, w_sm, gains, out);
  }
}